// Round 6
// baseline (634.170 us; speedup 1.0000x reference)
//
#include <hip/hip_runtime.h>
#include <hip/hip_bf16.h>
#include <math.h>

// Problem constants
#define BN   8
#define SN   2048
#define HN   1024
#define NTOK 16384   // B*S
#define NHD  16
#define HDD  64
#define NSD  64

typedef __attribute__((ext_vector_type(8))) short short8;
typedef __attribute__((ext_vector_type(4))) float f32x4;

__device__ __forceinline__ float fsig(float x)  { return 1.f / (1.f + __expf(-x)); }
__device__ __forceinline__ float fsilu(float x) { return x / (1.f + __expf(-x)); }
__device__ __forceinline__ float ftanh(float x) {
    const float t = __expf(-2.f * fabsf(x));
    const float r = (1.f - t) / (1.f + t);
    return x >= 0.f ? r : -r;
}
__device__ __forceinline__ void hilo(float v, __hip_bfloat16& h, __hip_bfloat16& l) {
    h = __float2bfloat16(v);
    l = __float2bfloat16(v - __bfloat162float(h));
}
__device__ __forceinline__ void gload_lds16(const void* g, void* l) {
    __builtin_amdgcn_global_load_lds(
        (const __attribute__((address_space(1))) unsigned int*)g,
        (__attribute__((address_space(3))) unsigned int*)l, 16, 0, 0);
}

// ---------------------------------------------------------------------------
// x (16384x1024 f32) -> A (16384x2048 bf16): [hi | lo] per row
// ---------------------------------------------------------------------------
__global__ __launch_bounds__(256)
void x_to_a(const float* __restrict__ X, __hip_bfloat16* __restrict__ A)
{
    const int idx = blockIdx.x * 256 + threadIdx.x;   // 4M float4s
    const int r  = idx >> 8;
    const int c4 = (idx & 255) * 4;
    const float4 v = *(const float4*)&X[(size_t)r * 1024 + c4];
    union { ushort4 u; __hip_bfloat16 b[4]; } H, L;
    hilo(v.x, H.b[0], L.b[0]);
    hilo(v.y, H.b[1], L.b[1]);
    hilo(v.z, H.b[2], L.b[2]);
    hilo(v.w, H.b[3], L.b[3]);
    *(ushort4*)&A[(size_t)r * 2048 + c4]        = H.u;
    *(ushort4*)&A[(size_t)r * 2048 + 1024 + c4] = L.u;
}

// ---------------------------------------------------------------------------
// W (1024 x N f32, (in,out)) -> BT (N x 2048 bf16): BT[n][k]=hi(W[k][n]),
// BT[n][1024+k]=lo(W[k][n]).  64x64 LDS-tiled transpose.
// ---------------------------------------------------------------------------
__global__ __launch_bounds__(256)
void w_to_bt(const float* __restrict__ W, __hip_bfloat16* __restrict__ BT, int N)
{
    __shared__ float t[64][65];
    const int k0 = blockIdx.x * 64;
    const int n0 = blockIdx.y * 64;
    const int c  = threadIdx.x & 63, r4 = threadIdx.x >> 6;
#pragma unroll
    for (int rr = 0; rr < 64; rr += 4)
        t[rr + r4][c] = W[(size_t)(k0 + rr + r4) * N + n0 + c];
    __syncthreads();
#pragma unroll
    for (int rr = 0; rr < 64; rr += 4) {
        const float v = t[c][rr + r4];
        __hip_bfloat16 h, l;
        hilo(v, h, l);
        const size_t o = (size_t)(n0 + rr + r4) * 2048 + k0 + c;
        BT[o]        = h;
        BT[o + 1024] = l;
    }
}

// ---------------------------------------------------------------------------
// 5 backbone weight mats (64x64 f32, (k,n)) -> WT5[mat][n][16 chunks x 8 bf16]
// hi octet o at chunk (o ^ (n&15)), lo at ((o|8) ^ (n&15)).  (pre-swizzled)
// ---------------------------------------------------------------------------
__global__ __launch_bounds__(256)
void w5_to_wt(const float* __restrict__ w0, const float* __restrict__ w1,
              const float* __restrict__ w2, const float* __restrict__ w3,
              const float* __restrict__ w4, __hip_bfloat16* __restrict__ WT5)
{
    const int idx = blockIdx.x * 256 + threadIdx.x;
    if (idx >= 2560) return;
    const int o = idx & 7, n = (idx >> 3) & 63, mat = idx >> 9;
    const float* W = mat == 0 ? w0 : mat == 1 ? w1 : mat == 2 ? w2 : mat == 3 ? w3 : w4;
    alignas(16) __hip_bfloat16 hb[8], lb[8];
#pragma unroll
    for (int j = 0; j < 8; ++j) {
        const float v = W[(o * 8 + j) * 64 + n];
        hilo(v, hb[j], lb[j]);
    }
    __hip_bfloat16* row = WT5 + (size_t)(mat * 64 + n) * 128;
    *(short8*)&row[((o     ) ^ (n & 15)) * 8] = *(const short8*)hb;
    *(short8*)&row[((o | 8) ^ (n & 15)) * 8] = *(const short8*)lb;
}

// ---------------------------------------------------------------------------
// MFMA GEMM (split bf16, 3 products): C = Ah*Bh + Ah*Bl + Al*Bh.
// 256x256 tile, BK=32, 8 waves (2Mx4N), double-buffered LDS (128 KB).
// STAGE-EARLY schedule (T3 minimum 2-phase): all 8 prefetch loads for tile
// t+1 issue at the TOP of tile t's body, so the tile-end barrier's vmcnt(0)
// drain finds them already landed (~3700 cy of MFMA cover vs ~900 before).
// ---------------------------------------------------------------------------
template<int NCT, int MODE>
__global__ __launch_bounds__(512, 2)
void mfma_gemm256(const __hip_bfloat16* __restrict__ A,
                  const __hip_bfloat16* __restrict__ BT,
                  float* __restrict__ out0, float* __restrict__ out1)
{
    // [buf][mat: Ah,Al,Bh,Bl][256 rows x 32 k]  = 128 KB
    __shared__ __hip_bfloat16 lds[2][4][8192];
    const int tid  = threadIdx.x;
    const int lane = tid & 63, wave = tid >> 6;
    const int wr   = wave >> 2, wc = wave & 3;     // 2 x 4 wave grid
    const int l15  = lane & 15, l4 = lane >> 4;

    // XCD-aware bijective swizzle (gridDim.x % 8 == 0 at both call sites)
    const int nwg = gridDim.x;
    const int cpx = nwg >> 3;
    const int swz = (blockIdx.x & 7) * cpx + (blockIdx.x >> 3);
    const int mt = swz / NCT, nt = swz % NCT;
    const int row0 = mt * 256, col0 = nt * 256;

    // staging thread map: issue i covers mat=i>>1, rows half*128..+127
    const int s_r = tid >> 2;          // 0..127 within half
    const int s_c = tid & 3;           // chunk
    const int s_sc = s_c ^ ((s_r >> 1) & 3);   // pre-swizzled source chunk

    f32x4 acc[8][4];
#pragma unroll
    for (int m = 0; m < 8; ++m)
#pragma unroll
        for (int n = 0; n < 4; ++n) acc[m][n] = (f32x4)0.f;

    const int rdsc = (l4 ^ ((l15 >> 1) & 3)) * 8;   // swizzled read chunk (elems)

    // ---- prologue: stage K-tile 0 into buf 0 ----
#pragma unroll
    for (int i = 0; i < 8; ++i) {
        const int mat = i >> 1, half = i & 1;
        const int r = half * 128 + s_r;
        const __hip_bfloat16* src = (mat < 2)
            ? &A [(size_t)(row0 + r) * 2048 + mat * 1024 + s_sc * 8]
            : &BT[(size_t)(col0 + r) * 2048 + (mat - 2) * 1024 + s_sc * 8];
        gload_lds16(src, &lds[0][mat][r * 32 + s_c * 8]);
    }
    __syncthreads();

#pragma unroll 2
    for (int t = 0; t < 32; ++t) {
        const int cur = t & 1, nxt = cur ^ 1;
        const int kk_next = (t + 1) << 5;

        // STAGE EARLY: all 8 prefetch loads for tile t+1, before any compute
        if (t < 31) {
#pragma unroll
            for (int i = 0; i < 8; ++i) {
                const int mat = i >> 1, half = i & 1;
                const int r = half * 128 + s_r;
                const __hip_bfloat16* src = (mat < 2)
                    ? &A [(size_t)(row0 + r) * 2048 + mat * 1024 + kk_next + s_sc * 8]
                    : &BT[(size_t)(col0 + r) * 2048 + (mat - 2) * 1024 + kk_next + s_sc * 8];
                gload_lds16(src, &lds[nxt][mat][r * 32 + s_c * 8]);
            }
        }

#pragma unroll
        for (int mh = 0; mh < 2; ++mh) {
            // A-frags for this mh: read once, reuse across both nh sub-phases
            short8 ah[4], al[4];
#pragma unroll
            for (int m = 0; m < 4; ++m) {
                const int off = (wr * 128 + mh * 64 + m * 16 + l15) * 32 + rdsc;
                ah[m] = *(const short8*)&lds[cur][0][off];
                al[m] = *(const short8*)&lds[cur][1][off];
            }

#pragma unroll
            for (int nh = 0; nh < 2; ++nh) {
                short8 bh2[2], bl2[2];
#pragma unroll
                for (int n = 0; n < 2; ++n) {
                    const int off = (wc * 64 + nh * 32 + n * 16 + l15) * 32 + rdsc;
                    bh2[n] = *(const short8*)&lds[cur][2][off];
                    bl2[n] = *(const short8*)&lds[cur][3][off];
                }

                __builtin_amdgcn_s_setprio(1);
#pragma unroll
                for (int m = 0; m < 4; ++m)
#pragma unroll
                    for (int n = 0; n < 2; ++n) {
                        f32x4 a = acc[mh * 4 + m][nh * 2 + n];
                        a = __builtin_amdgcn_mfma_f32_16x16x32_bf16(ah[m], bh2[n], a, 0, 0, 0);
                        a = __builtin_amdgcn_mfma_f32_16x16x32_bf16(ah[m], bl2[n], a, 0, 0, 0);
                        a = __builtin_amdgcn_mfma_f32_16x16x32_bf16(al[m], bh2[n], a, 0, 0, 0);
                        acc[mh * 4 + m][nh * 2 + n] = a;
                    }
                __builtin_amdgcn_s_setprio(0);
            }
        }
        __syncthreads();   // one drain per K-tile; prefetch landed under MFMA
    }

    // epilogue: C/D layout col=lane&15, row=(lane>>4)*4+q
    const int orow = l4 * 4, ocol = l15;
#pragma unroll
    for (int M = 0; M < 8; ++M)
#pragma unroll
        for (int N = 0; N < 4; ++N) {
            const int c = col0 + wc * 64 + N * 16 + ocol;
#pragma unroll
            for (int q = 0; q < 4; ++q) {
                const int r = row0 + wr * 128 + M * 16 + orow + q;
                const float v = acc[M][N][q];
                if (MODE == 0) {
                    out0[(size_t)r * (NCT * 256) + c] = v;
                } else {
                    if (c < 1024) out0[(size_t)r * 1024 + c] = v;
                    else          out1[(size_t)r * 1024 + (c - 1024)] = fsilu(v);
                }
            }
        }
}

// ---------------------------------------------------------------------------
// Depthwise causal conv (K=4) + bias + silu -> X as swizzled bf16 hi|lo rows.
// ---------------------------------------------------------------------------
__global__ __launch_bounds__(256)
void conv_silu_bf(const float* __restrict__ xp, const float* __restrict__ cw,
                  const float* __restrict__ cb, __hip_bfloat16* __restrict__ Xhl)
{
    const int idx = blockIdx.x * 256 + threadIdx.x;   // NTOK*128 octets
    const int g  = idx & 127;
    const int bt = idx >> 7;
    const int t  = bt & (SN - 1);
    const int c0 = g * 8;

    float acc[8];
#pragma unroll
    for (int j = 0; j < 8; ++j) acc[j] = cb[c0 + j];
    float4 cwv[8];
#pragma unroll
    for (int j = 0; j < 8; ++j) cwv[j] = *(const float4*)&cw[(c0 + j) * 4];
    const float* cwf = (const float*)cwv;

#pragma unroll
    for (int k = 0; k < 4; ++k) {
        const int tt = t - 3 + k;
        if (tt >= 0) {
            const float* xr = xp + (((size_t)(bt - 3 + k)) << 10) + c0;
            const float4 u0 = *(const float4*)&xr[0];
            const float4 u1 = *(const float4*)&xr[4];
            const float u[8] = {u0.x, u0.y, u0.z, u0.w, u1.x, u1.y, u1.z, u1.w};
#pragma unroll
            for (int j = 0; j < 8; ++j) acc[j] += cwf[j * 4 + k] * u[j];
        }
    }

    alignas(16) __hip_bfloat16 hb[8], lb[8];
#pragma unroll
    for (int j = 0; j < 8; ++j)
        hilo(fsilu(acc[j]), hb[j], lb[j]);

    const int head = c0 >> 6;
    const int o    = (c0 >> 3) & 7;
    __hip_bfloat16* row = Xhl + ((size_t)bt * 16 + head) * 128;
    *(short8*)&row[((o     ) ^ head) * 8] = *(const short8*)hb;
    *(short8*)&row[((o | 8) ^ head) * 8] = *(const short8*)lb;
}

// ---------------------------------------------------------------------------
// Fused MFMA backbone (unchanged).
// ---------------------------------------------------------------------------
__global__ __launch_bounds__(256, 1)
void backbone_mfma(const __hip_bfloat16* __restrict__ Xhl,
                   const __hip_bfloat16* __restrict__ WT5,
                   const float* __restrict__ bbb,
                   const float* __restrict__ f1b, const float* __restrict__ f2b,
                   const float* __restrict__ taub, const float* __restrict__ taub2,
                   const float* __restrict__ decb,
                   float* __restrict__ cand, float* __restrict__ decay)
{
    __shared__ __hip_bfloat16 Wl[5 * 64 * 128];   // 80 KB
    __shared__ __hip_bfloat16 Xl[128 * 128];      // 32 KB
    __shared__ __hip_bfloat16 Bb[128 * 128];      // 32 KB
    const int tid  = threadIdx.x;
    const int lane = tid & 63, wave = tid >> 6;
    const int l15  = lane & 15, l4 = lane >> 4;

#pragma unroll
    for (int r = 0; r < 20; ++r) {
        const int blk = r * 4 + wave;
        gload_lds16(WT5 + blk * 512 + lane * 8, Wl + blk * 512);
    }
    const __hip_bfloat16* xsrc = Xhl + (size_t)blockIdx.x * 16384;
#pragma unroll
    for (int r = 0; r < 8; ++r) {
        const int blk = r * 4 + wave;
        gload_lds16(xsrc + blk * 512 + lane * 8, Xl + blk * 512);
    }
    __syncthreads();

    // ---- stage 1 ----
    short8 xa[2][2][2];
#pragma unroll
    for (int mt2 = 0; mt2 < 2; ++mt2)
#pragma unroll
        for (int s = 0; s < 2; ++s)
#pragma unroll
            for (int p = 0; p < 2; ++p) {
                const int ch = ((s * 4 + l4) | (p << 3)) ^ l15;
                xa[mt2][s][p] = *(const short8*)&Xl[(wave * 32 + mt2 * 16 + l15) * 128 + ch * 8];
            }

#pragma unroll
    for (int nt = 0; nt < 4; ++nt) {
        short8 wb[2][2];
#pragma unroll
        for (int s = 0; s < 2; ++s)
#pragma unroll
            for (int p = 0; p < 2; ++p) {
                const int ch = ((s * 4 + l4) | (p << 3)) ^ l15;
                wb[s][p] = *(const short8*)&Wl[(nt * 16 + l15) * 128 + ch * 8];
            }
        f32x4 ac[2] = {(f32x4)0.f, (f32x4)0.f};
#pragma unroll
        for (int mt2 = 0; mt2 < 2; ++mt2)
#pragma unroll
            for (int s = 0; s < 2; ++s) {
                ac[mt2] = __builtin_amdgcn_mfma_f32_16x16x32_bf16(xa[mt2][s][0], wb[s][0], ac[mt2], 0, 0, 0);
                ac[mt2] = __builtin_amdgcn_mfma_f32_16x16x32_bf16(xa[mt2][s][0], wb[s][1], ac[mt2], 0, 0, 0);
                ac[mt2] = __builtin_amdgcn_mfma_f32_16x16x32_bf16(xa[mt2][s][1], wb[s][0], ac[mt2], 0, 0, 0);
            }
        const int col = nt * 16 + l15;
        const float bc = bbb[col];
#pragma unroll
        for (int mt2 = 0; mt2 < 2; ++mt2)
#pragma unroll
            for (int q = 0; q < 4; ++q) {
                const int r15 = l4 * 4 + q;
                const int lr  = wave * 32 + mt2 * 16 + r15;
                const float v = fsilu(ac[mt2][q] + bc);
                __hip_bfloat16 h, l;
                hilo(v, h, l);
                Bb[lr * 128 + (((col >> 3)     ) ^ r15) * 8 + (col & 7)] = h;
                Bb[lr * 128 + (((col >> 3) | 8) ^ r15) * 8 + (col & 7)] = l;
            }
    }
    __syncthreads();

    // ---- stage 2 ----
    short8 ba[2][2][2];
#pragma unroll
    for (int mt2 = 0; mt2 < 2; ++mt2)
#pragma unroll
        for (int s = 0; s < 2; ++s)
#pragma unroll
            for (int p = 0; p < 2; ++p) {
                const int ch = ((s * 4 + l4) | (p << 3)) ^ l15;
                ba[mt2][s][p] = *(const short8*)&Bb[(wave * 32 + mt2 * 16 + l15) * 128 + ch * 8];
            }

#pragma unroll
    for (int nt = 0; nt < 4; ++nt) {
        f32x4 a2[4][2];
#pragma unroll
        for (int m = 0; m < 4; ++m)
#pragma unroll
            for (int mt2 = 0; mt2 < 2; ++mt2) a2[m][mt2] = (f32x4)0.f;

#pragma unroll
        for (int mat = 0; mat < 4; ++mat) {
            short8 w2[2][2];
#pragma unroll
            for (int s = 0; s < 2; ++s)
#pragma unroll
                for (int p = 0; p < 2; ++p) {
                    const int ch = ((s * 4 + l4) | (p << 3)) ^ l15;
                    w2[s][p] = *(const short8*)&Wl[((mat + 1) * 64 + nt * 16 + l15) * 128 + ch * 8];
                }
#pragma unroll
            for (int mt2 = 0; mt2 < 2; ++mt2)
#pragma unroll
                for (int s = 0; s < 2; ++s) {
                    a2[mat][mt2] = __builtin_amdgcn_mfma_f32_16x16x32_bf16(ba[mt2][s][0], w2[s][0], a2[mat][mt2], 0, 0, 0);
                    a2[mat][mt2] = __builtin_amdgcn_mfma_f32_16x16x32_bf16(ba[mt2][s][0], w2[s][1], a2[mat][mt2], 0, 0, 0);
                    a2[mat][mt2] = __builtin_amdgcn_mfma_f32_16x16x32_bf16(ba[mt2][s][1], w2[s][0], a2[mat][mt2], 0, 0, 0);
                }
        }

        const int col = nt * 16 + l15;
        const float b1 = f1b[col], b2 = f2b[col];
        const float b3 = taub[col] + taub2[col], b4 = decb[col];
        const size_t Rbase = (size_t)blockIdx.x * 128 + wave * 32;
#pragma unroll
        for (int mt2 = 0; mt2 < 2; ++mt2)
#pragma unroll
            for (int q = 0; q < 4; ++q) {
                const size_t R = Rbase + mt2 * 16 + l4 * 4 + q;
                const float f1v = ftanh(a2[0][mt2][q] + b1);
                const float f2v = ftanh(a2[1][mt2][q] + b2);
                const float tv  = fsig (a2[2][mt2][q] + b3);
                const float dv  = fsig (a2[3][mt2][q] + b4);
                cand [R * 64 + col] = f1v * (1.f - tv) + f2v * tv;
                decay[R * 64 + col] = dv;
            }
    }
}

// ---------------------------------------------------------------------------
// Chunked scan passes 1+2 (unchanged).
// ---------------------------------------------------------------------------
__global__ __launch_bounds__(256)
void scan_compose(const float* __restrict__ decay, const float* __restrict__ cand,
                  float* __restrict__ Ach, float* __restrict__ Bch)
{
    const int idx = blockIdx.x * 256 + threadIdx.x;
    const int p  = idx & 1023;
    const int rest = idx >> 10;
    const int ch = rest & 63, b = rest >> 6;
    float A = 1.f, Bv = 0.f;
    const size_t base = ((size_t)(b * SN + ch * 32) << 10) + p;
    for (int t = 0; t < 32; ++t) {
        const float d = decay[base + ((size_t)t << 10)];
        const float c = cand [base + ((size_t)t << 10)];
        A  *= d;
        Bv  = d * Bv + (1.f - d) * c;
    }
    Ach[(ch << 13) + (b << 10) + p] = A;
    Bch[(ch << 13) + (b << 10) + p] = Bv;
}

__global__ __launch_bounds__(256)
void scan_chunks(const float* __restrict__ Ach, const float* __restrict__ Bch,
                 float* __restrict__ hstart)
{
    const int q = blockIdx.x * 256 + threadIdx.x;
    float h = 0.f;
    for (int ch = 0; ch < 64; ++ch) {
        hstart[(ch << 13) + q] = h;
        h = Ach[(ch << 13) + q] * h + Bch[(ch << 13) + q];
    }
}

// ---------------------------------------------------------------------------
// FUSED scan_apply + state_out + gate.  One block = (b, 32-token chunk).
// Phase 1 (scan): 512 threads own 2 chains each; h written as swizzled
// hi|lo bf16 straight into LDS (512 rows x 256B = 128 KB).
// Phase 2 (MFMA): 8 waves x 64 rows, out = H @ sow + sob, gated by silu(z),
// emitted as bf16 hi|lo rows for out_proj.  Saves the 128 MB Hhl round-trip.
// ---------------------------------------------------------------------------
__global__ __launch_bounds__(512, 2)
void scanout_fused(const float* __restrict__ decay, const float* __restrict__ cand,
                   const float* __restrict__ hstart,
                   const float* __restrict__ sow, const float* __restrict__ sob,
                   const float* __restrict__ zs, __hip_bfloat16* __restrict__ gA)
{
    __shared__ __hip_bfloat16 Wl[64 * 128];    // 16 KB
    __shared__ __hip_bfloat16 Hl[512 * 128];   // 128 KB
    const int tid  = threadIdx.x;
    const int lane = tid & 63, wave = tid >> 6;
    const int l15  = lane & 15, l4 = lane >> 4;
    const int b  = blockIdx.x >> 6;
    const int ch = blockIdx.x & 63;

    // sow (64x64 f32, (k,n)) -> Wl hi|lo, chunk-XOR swizzled. thread=(o,n).
    {
        const int n = tid & 63;
        const int o = tid >> 6;   // 0..7
        alignas(16) __hip_bfloat16 hb[8], lb[8];
#pragma unroll
        for (int j = 0; j < 8; ++j)
            hilo(sow[(o * 8 + j) * 64 + n], hb[j], lb[j]);
        *(short8*)&Wl[n * 128 + ((o       ^ (n & 15)) * 8)] = *(const short8*)hb;
        *(short8*)&Wl[n * 128 + (((o | 8) ^ (n & 15)) * 8)] = *(const short8*)lb;
    }

    // ---- phase 1: scan 32 steps, 2 chains per thread ----
    const float* hs0 = hstart + (ch << 13) + (b << 10);
#pragma unroll
    for (int cp = 0; cp < 2; ++cp) {
        const int p = tid + cp * 512;
        const int head = p >> 6, ns = p & 63;
        const int hoff = (((ns >> 3)    ) ^ head) * 8 + (ns & 7);
        const int loff = (((ns >> 3) | 8) ^ head) * 8 + (ns & 7);
        float h = hs0[p];
        const size_t base = ((size_t)(b * SN + ch * 32) << 10) + p;
        for (int t = 0; t < 32; ++t) {
            const size_t o = base + ((size_t)t << 10);
            const float d = decay[o];
            const float c = cand[o];
            h = d * h + (1.f - d) * c;
            __hip_bfloat16 hb, lb;
            hilo(h, hb, lb);
            const int lr = t * 16 + head;
            Hl[lr * 128 + hoff] = hb;
            Hl[lr * 128 + loff] = lb;
        }
    }
    __syncthreads();

    // ---- phase 2: MFMA state_out; wave owns rows [wave*64, +64) ----
    short8 ha[4][2][2];
#pragma unroll
    for (int mt = 0; mt < 4; ++mt)
#pragma unroll
        for (int s = 0; s < 2; ++s)
#pragma unroll
            for (int pp = 0; pp < 2; ++pp) {
                const int chk = ((s * 4 + l4) | (pp << 3)) ^ l15;
                ha[mt][s][pp] = *(const short8*)&Hl[(wave * 64 + mt * 16 + l15) * 128 + chk * 8];
            }

    const int T0 = b * SN + ch * 32;
#pragma unroll
    for (int nt = 0; nt < 4; ++nt) {
        short8 wb[2][2];
#pragma unroll
        for (int s = 0; s < 2; ++s)
#pragma unroll
            for (int pp = 0; pp < 2; ++pp) {
                const int chk = ((s * 4 + l4) | (pp << 3)) ^ l15;
                wb[s][pp] = *(const short8*)&Wl[(nt * 16 + l15) * 128 + chk * 8];
            }
        f32x4 ac[4];
#pragma unroll
        for (int mt = 0; mt < 4; ++mt) ac[mt] = (f32x4)0.f;
#pragma unroll
        for (int mt = 0; mt < 4; ++mt)
#pragma unroll
            for (int s = 0; s < 2; ++s) {
                ac[mt] = __builtin_amdgcn_mfma_f32_16x16x32_bf16(ha[mt][s][0], wb[s][0], ac[mt], 0, 0, 0);
                ac[mt] = __builtin_amdgcn_mfma_f32_16x16x32_bf16(ha[mt][s][0], wb[s][1], ac[mt], 0, 0, 0);
                ac[mt] = __builtin_amdgcn_mfma_f32_16x16x32_bf16(ha[mt][s][1], wb[s][0], ac[mt], 0, 0, 0);
            }

        const int col = nt * 16 + l15;
        const float bj = sob[col];
#pragma unroll
        for (int mt = 0; mt < 4; ++mt) {
            const int token = T0 + wave * 4 + mt;
#pragma unroll
            for (int q = 0; q < 4; ++q) {
                const int head = l4 * 4 + q;
                const float v = (ac[mt][q] + bj) * zs[(size_t)token * 1024 + head * 64 + col];
                __hip_bfloat16 hb, lb;
                hilo(v, hb, lb);
                const int colg = head * 64 + col;
                gA[(size_t)token * 2048 + colg]        = hb;
                gA[(size_t)token * 2048 + 1024 + colg] = lb;
            }
        }
    }
}

// ---------------------------------------------------------------------------
extern "C" void kernel_launch(void* const* d_in, const int* in_sizes, int n_in,
                              void* d_out, int out_size, void* d_ws, size_t ws_size,
                              hipStream_t stream)
{
    const float* x     = (const float*)d_in[0];
    const float* ipw   = (const float*)d_in[1];
    const float* cw    = (const float*)d_in[2];
    const float* cb    = (const float*)d_in[3];
    const float* bbw   = (const float*)d_in[4];
    const float* bbb   = (const float*)d_in[5];
    const float* f1w   = (const float*)d_in[6];
    const float* f1b   = (const float*)d_in[7];
    const float* f2w   = (const float*)d_in[8];
    const float* f2b   = (const float*)d_in[9];
    const float* tauw  = (const float*)d_in[10];
    const float* taub  = (const float*)d_in[11];
    const float* taub2 = (const float*)d_in[12];
    const float* decw  = (const float*)d_in[13];
    const float* decb  = (const float*)d_in[14];
    const float* sow   = (const float*)d_in[15];
    const float* sob   = (const float*)d_in[16];
    const float* opw   = (const float*)d_in[17];

    float* out = (float*)d_out;
    char*  ws  = (char*)d_ws;
    const size_t MB = 1024 * 1024;

    // Workspace map (198 MiB):
    //  @0Mi   (64Mi): Ahl (bf16) -> Xhl (bf16, conv out) -> gA (bf16)
    //  @64Mi  (64Mi): xpath (f32) -> decay (f32)
    //  @128Mi (64Mi): BTin (8Mi, dead before cand) -> cand (f32)
    //  @192Mi (6Mi) : WT5 (80KB, dead before scan) -> Ach|Bch (4Mi) | hst (2Mi)
    //                 BTout (4Mi) overwrites Ach|Bch after scan_chunks
    __hip_bfloat16* Ahl   = (__hip_bfloat16*)(ws);
    float*          xpath = (float*)(ws + 64 * MB);
    __hip_bfloat16* BTin  = (__hip_bfloat16*)(ws + 128 * MB);
    float*          cand  = (float*)(ws + 128 * MB);
    __hip_bfloat16* WT5   = (__hip_bfloat16*)(ws + 192 * MB);
    float*          Ach   = (float*)(ws + 192 * MB);
    float*          Bch   = Ach + 524288;
    float*          hst   = Bch + 524288;
    __hip_bfloat16* BTout = (__hip_bfloat16*)(ws + 192 * MB);
    __hip_bfloat16* Xhl   = (__hip_bfloat16*)(ws);
    __hip_bfloat16* gA    = (__hip_bfloat16*)(ws);
    float*          decay = xpath;
    float*          zsilu = out;   // d_out as scratch until final GEMM

    // 1) conversions
    x_to_a<<<16384, 256, 0, stream>>>(x, Ahl);
    w_to_bt<<<dim3(16, 32), 256, 0, stream>>>(ipw, BTin, 2048);
    w5_to_wt<<<10, 256, 0, stream>>>(bbw, f1w, f2w, tauw, decw, WT5);
    // 2) in_proj GEMM (split-bf16 MFMA, stage-early) + silu(z)
    mfma_gemm256<8, 1><<<512, 512, 0, stream>>>(Ahl, BTin, xpath, zsilu);
    // 3) conv + silu -> swizzled bf16 hi|lo X
    conv_silu_bf<<<8192, 256, 0, stream>>>(xpath, cw, cb, Xhl);
    // 4) fused MFMA backbone -> cand, decay
    backbone_mfma<<<2048, 256, 0, stream>>>(Xhl, WT5, bbb, f1b, f2b,
                                            taub, taub2, decb, cand, decay);
    // 5) chunked scan levels 1+2
    scan_compose<<<2048, 256, 0, stream>>>(decay, cand, Ach, Bch);
    scan_chunks<<<32, 256, 0, stream>>>(Ach, Bch, hst);
    // 6) fused scan_apply + state_out + gate -> gA (bf16 hi|lo)
    scanout_fused<<<512, 512, 0, stream>>>(decay, cand, hst, sow, sob, zsilu, gA);
    // 7) out_proj weight conversion (Ach/Bch dead; hst untouched)
    w_to_bt<<<dim3(16, 16), 256, 0, stream>>>(opw, BTout, 1024);
    // 8) out_proj GEMM
    mfma_gemm256<4, 0><<<256, 512, 0, stream>>>(gA, BTout, out, nullptr);
}

// Round 7
// 602.810 us; speedup vs baseline: 1.0520x; 1.0520x over previous
//
#include <hip/hip_runtime.h>
#include <hip/hip_bf16.h>
#include <math.h>

// Problem constants
#define BN   8
#define SN   2048
#define HN   1024
#define NTOK 16384   // B*S
#define NHD  16
#define HDD  64
#define NSD  64

typedef __attribute__((ext_vector_type(8))) short short8;
typedef __attribute__((ext_vector_type(4))) float f32x4;

__device__ __forceinline__ float fsig(float x)  { return 1.f / (1.f + __expf(-x)); }
__device__ __forceinline__ float fsilu(float x) { return x / (1.f + __expf(-x)); }
__device__ __forceinline__ float ftanh(float x) {
    const float t = __expf(-2.f * fabsf(x));
    const float r = (1.f - t) / (1.f + t);
    return x >= 0.f ? r : -r;
}
__device__ __forceinline__ void hilo(float v, __hip_bfloat16& h, __hip_bfloat16& l) {
    h = __float2bfloat16(v);
    l = __float2bfloat16(v - __bfloat162float(h));
}
__device__ __forceinline__ void gload_lds16(const void* g, void* l) {
    __builtin_amdgcn_global_load_lds(
        (const __attribute__((address_space(1))) unsigned int*)g,
        (__attribute__((address_space(3))) unsigned int*)l, 16, 0, 0);
}

// ---------------------------------------------------------------------------
// x (16384x1024 f32) -> A (16384x2048 bf16): [hi | lo] per row
// ---------------------------------------------------------------------------
__global__ __launch_bounds__(256)
void x_to_a(const float* __restrict__ X, __hip_bfloat16* __restrict__ A)
{
    const int idx = blockIdx.x * 256 + threadIdx.x;   // 4M float4s
    const int r  = idx >> 8;
    const int c4 = (idx & 255) * 4;
    const float4 v = *(const float4*)&X[(size_t)r * 1024 + c4];
    union { ushort4 u; __hip_bfloat16 b[4]; } H, L;
    hilo(v.x, H.b[0], L.b[0]);
    hilo(v.y, H.b[1], L.b[1]);
    hilo(v.z, H.b[2], L.b[2]);
    hilo(v.w, H.b[3], L.b[3]);
    *(ushort4*)&A[(size_t)r * 2048 + c4]        = H.u;
    *(ushort4*)&A[(size_t)r * 2048 + 1024 + c4] = L.u;
}

// ---------------------------------------------------------------------------
// W (1024 x N f32, (in,out)) -> BT (N x 2048 bf16): BT[n][k]=hi(W[k][n]),
// BT[n][1024+k]=lo(W[k][n]).  64x64 LDS-tiled transpose.
// ---------------------------------------------------------------------------
__global__ __launch_bounds__(256)
void w_to_bt(const float* __restrict__ W, __hip_bfloat16* __restrict__ BT, int N)
{
    __shared__ float t[64][65];
    const int k0 = blockIdx.x * 64;
    const int n0 = blockIdx.y * 64;
    const int c  = threadIdx.x & 63, r4 = threadIdx.x >> 6;
#pragma unroll
    for (int rr = 0; rr < 64; rr += 4)
        t[rr + r4][c] = W[(size_t)(k0 + rr + r4) * N + n0 + c];
    __syncthreads();
#pragma unroll
    for (int rr = 0; rr < 64; rr += 4) {
        const float v = t[c][rr + r4];
        __hip_bfloat16 h, l;
        hilo(v, h, l);
        const size_t o = (size_t)(n0 + rr + r4) * 2048 + k0 + c;
        BT[o]        = h;
        BT[o + 1024] = l;
    }
}

// ---------------------------------------------------------------------------
// 5 backbone weight mats (64x64 f32, (k,n)) -> WT5[mat][n][16 chunks x 8 bf16]
// hi octet o at chunk (o ^ (n&15)), lo at ((o|8) ^ (n&15)).  (pre-swizzled)
// ---------------------------------------------------------------------------
__global__ __launch_bounds__(256)
void w5_to_wt(const float* __restrict__ w0, const float* __restrict__ w1,
              const float* __restrict__ w2, const float* __restrict__ w3,
              const float* __restrict__ w4, __hip_bfloat16* __restrict__ WT5)
{
    const int idx = blockIdx.x * 256 + threadIdx.x;
    if (idx >= 2560) return;
    const int o = idx & 7, n = (idx >> 3) & 63, mat = idx >> 9;
    const float* W = mat == 0 ? w0 : mat == 1 ? w1 : mat == 2 ? w2 : mat == 3 ? w3 : w4;
    alignas(16) __hip_bfloat16 hb[8], lb[8];
#pragma unroll
    for (int j = 0; j < 8; ++j) {
        const float v = W[(o * 8 + j) * 64 + n];
        hilo(v, hb[j], lb[j]);
    }
    __hip_bfloat16* row = WT5 + (size_t)(mat * 64 + n) * 128;
    *(short8*)&row[((o     ) ^ (n & 15)) * 8] = *(const short8*)hb;
    *(short8*)&row[((o | 8) ^ (n & 15)) * 8] = *(const short8*)lb;
}

// ---------------------------------------------------------------------------
// MFMA GEMM (split bf16, 3 products): C = Ah*Bh + Ah*Bl + Al*Bh.
// 256x256 tile, BK=32, 8 waves (2Mx4N), double-buffered LDS (128 KB).
// COUNTED-VMCNT schedule (T3+T4): raw s_barrier + s_waitcnt vmcnt(8) —
// no vmcnt(0) drain in the main loop; tile t+1's loads land under tile t's
// MFMA.  Per K-tile: compute(buf) | barrier(release) | stage t+2 -> buf |
// vmcnt(8) | barrier(acquire).
// ---------------------------------------------------------------------------
template<int NCT, int MODE>
__global__ __launch_bounds__(512, 2)
void mfma_gemm256(const __hip_bfloat16* __restrict__ A,
                  const __hip_bfloat16* __restrict__ BT,
                  float* __restrict__ out0, float* __restrict__ out1)
{
    // [buf][mat: Ah,Al,Bh,Bl][256 rows x 32 k]  = 128 KB
    __shared__ __hip_bfloat16 lds[2][4][8192];
    const int tid  = threadIdx.x;
    const int lane = tid & 63, wave = tid >> 6;
    const int wr   = wave >> 2, wc = wave & 3;     // 2 x 4 wave grid
    const int l15  = lane & 15, l4 = lane >> 4;

    // XCD-aware bijective swizzle (gridDim.x % 8 == 0 at both call sites)
    const int nwg = gridDim.x;
    const int cpx = nwg >> 3;
    const int swz = (blockIdx.x & 7) * cpx + (blockIdx.x >> 3);
    const int mt = swz / NCT, nt = swz % NCT;
    const int row0 = mt * 256, col0 = nt * 256;

    // staging thread map: issue i covers mat=i>>1, rows half*128..+127
    const int s_r = tid >> 2;          // 0..127 within half
    const int s_c = tid & 3;           // chunk
    const int s_sc = s_c ^ ((s_r >> 1) & 3);   // pre-swizzled source chunk

    f32x4 acc[8][4];
#pragma unroll
    for (int m = 0; m < 8; ++m)
#pragma unroll
        for (int n = 0; n < 4; ++n) acc[m][n] = (f32x4)0.f;

    const int rdsc = (l4 ^ ((l15 >> 1) & 3)) * 8;   // swizzled read chunk (elems)

#define STAGE(TT, BUF)                                                         \
    {                                                                          \
        const int kk_ = (TT) << 5;                                             \
        _Pragma("unroll")                                                      \
        for (int i_ = 0; i_ < 8; ++i_) {                                       \
            const int mat_ = i_ >> 1, half_ = i_ & 1;                          \
            const int r_ = half_ * 128 + s_r;                                  \
            const __hip_bfloat16* src_ = (mat_ < 2)                            \
                ? &A [(size_t)(row0 + r_) * 2048 + mat_ * 1024 + kk_ + s_sc * 8]          \
                : &BT[(size_t)(col0 + r_) * 2048 + (mat_ - 2) * 1024 + kk_ + s_sc * 8];   \
            gload_lds16(src_, &lds[BUF][mat_][r_ * 32 + s_c * 8]);             \
        }                                                                      \
    }

    // ---- prologue: stage tiles 0 and 1 (16 loads/wave in flight) ----
    STAGE(0, 0);
    STAGE(1, 1);
    asm volatile("s_waitcnt vmcnt(8)" ::: "memory");   // own tile-0 loads landed
    __builtin_amdgcn_s_barrier();                      // all waves' tile-0 landed
    __builtin_amdgcn_sched_barrier(0);

    for (int t = 0; t < 32; ++t) {
        const int cur = t & 1;

        // ---- compute tile t from buf[cur] ----
#pragma unroll
        for (int mh = 0; mh < 2; ++mh) {
            short8 ah[4], al[4];
#pragma unroll
            for (int m = 0; m < 4; ++m) {
                const int off = (wr * 128 + mh * 64 + m * 16 + l15) * 32 + rdsc;
                ah[m] = *(const short8*)&lds[cur][0][off];
                al[m] = *(const short8*)&lds[cur][1][off];
            }
#pragma unroll
            for (int nh = 0; nh < 2; ++nh) {
                short8 bh2[2], bl2[2];
#pragma unroll
                for (int n = 0; n < 2; ++n) {
                    const int off = (wc * 64 + nh * 32 + n * 16 + l15) * 32 + rdsc;
                    bh2[n] = *(const short8*)&lds[cur][2][off];
                    bl2[n] = *(const short8*)&lds[cur][3][off];
                }
                __builtin_amdgcn_s_setprio(1);
#pragma unroll
                for (int m = 0; m < 4; ++m)
#pragma unroll
                    for (int n = 0; n < 2; ++n) {
                        f32x4 a = acc[mh * 4 + m][nh * 2 + n];
                        a = __builtin_amdgcn_mfma_f32_16x16x32_bf16(ah[m], bh2[n], a, 0, 0, 0);
                        a = __builtin_amdgcn_mfma_f32_16x16x32_bf16(ah[m], bl2[n], a, 0, 0, 0);
                        a = __builtin_amdgcn_mfma_f32_16x16x32_bf16(al[m], bh2[n], a, 0, 0, 0);
                        acc[mh * 4 + m][nh * 2 + n] = a;
                    }
                __builtin_amdgcn_s_setprio(0);
            }
        }

        if (t == 31) break;

        __builtin_amdgcn_s_barrier();          // release: all waves done reading buf[cur]
        if (t < 30) {
            STAGE(t + 2, cur);                 // overwrite buf[cur] with tile t+2
            asm volatile("s_waitcnt vmcnt(8)" ::: "memory");  // own tile t+1 landed
        } else {
            asm volatile("s_waitcnt vmcnt(0)" ::: "memory");  // last tile: drain
        }
        __builtin_amdgcn_s_barrier();          // acquire: all waves' tile t+1 landed
        __builtin_amdgcn_sched_barrier(0);     // no ds_read hoisting above this point
    }
#undef STAGE

    // epilogue: C/D layout col=lane&15, row=(lane>>4)*4+q
    const int orow = l4 * 4, ocol = l15;
#pragma unroll
    for (int M = 0; M < 8; ++M)
#pragma unroll
        for (int N = 0; N < 4; ++N) {
            const int c = col0 + wc * 64 + N * 16 + ocol;
#pragma unroll
            for (int q = 0; q < 4; ++q) {
                const int r = row0 + wr * 128 + M * 16 + orow + q;
                const float v = acc[M][N][q];
                if (MODE == 0) {
                    out0[(size_t)r * (NCT * 256) + c] = v;
                } else {
                    if (c < 1024) out0[(size_t)r * 1024 + c] = v;
                    else          out1[(size_t)r * 1024 + (c - 1024)] = fsilu(v);
                }
            }
        }
}

// ---------------------------------------------------------------------------
// Depthwise causal conv (K=4) + bias + silu -> X as swizzled bf16 hi|lo rows.
// ---------------------------------------------------------------------------
__global__ __launch_bounds__(256)
void conv_silu_bf(const float* __restrict__ xp, const float* __restrict__ cw,
                  const float* __restrict__ cb, __hip_bfloat16* __restrict__ Xhl)
{
    const int idx = blockIdx.x * 256 + threadIdx.x;   // NTOK*128 octets
    const int g  = idx & 127;
    const int bt = idx >> 7;
    const int t  = bt & (SN - 1);
    const int c0 = g * 8;

    float acc[8];
#pragma unroll
    for (int j = 0; j < 8; ++j) acc[j] = cb[c0 + j];
    float4 cwv[8];
#pragma unroll
    for (int j = 0; j < 8; ++j) cwv[j] = *(const float4*)&cw[(c0 + j) * 4];
    const float* cwf = (const float*)cwv;

#pragma unroll
    for (int k = 0; k < 4; ++k) {
        const int tt = t - 3 + k;
        if (tt >= 0) {
            const float* xr = xp + (((size_t)(bt - 3 + k)) << 10) + c0;
            const float4 u0 = *(const float4*)&xr[0];
            const float4 u1 = *(const float4*)&xr[4];
            const float u[8] = {u0.x, u0.y, u0.z, u0.w, u1.x, u1.y, u1.z, u1.w};
#pragma unroll
            for (int j = 0; j < 8; ++j) acc[j] += cwf[j * 4 + k] * u[j];
        }
    }

    alignas(16) __hip_bfloat16 hb[8], lb[8];
#pragma unroll
    for (int j = 0; j < 8; ++j)
        hilo(fsilu(acc[j]), hb[j], lb[j]);

    const int head = c0 >> 6;
    const int o    = (c0 >> 3) & 7;
    __hip_bfloat16* row = Xhl + ((size_t)bt * 16 + head) * 128;
    *(short8*)&row[((o     ) ^ head) * 8] = *(const short8*)hb;
    *(short8*)&row[((o | 8) ^ head) * 8] = *(const short8*)lb;
}

// ---------------------------------------------------------------------------
// Fused MFMA backbone (unchanged).
// ---------------------------------------------------------------------------
__global__ __launch_bounds__(256, 1)
void backbone_mfma(const __hip_bfloat16* __restrict__ Xhl,
                   const __hip_bfloat16* __restrict__ WT5,
                   const float* __restrict__ bbb,
                   const float* __restrict__ f1b, const float* __restrict__ f2b,
                   const float* __restrict__ taub, const float* __restrict__ taub2,
                   const float* __restrict__ decb,
                   float* __restrict__ cand, float* __restrict__ decay)
{
    __shared__ __hip_bfloat16 Wl[5 * 64 * 128];   // 80 KB
    __shared__ __hip_bfloat16 Xl[128 * 128];      // 32 KB
    __shared__ __hip_bfloat16 Bb[128 * 128];      // 32 KB
    const int tid  = threadIdx.x;
    const int lane = tid & 63, wave = tid >> 6;
    const int l15  = lane & 15, l4 = lane >> 4;

#pragma unroll
    for (int r = 0; r < 20; ++r) {
        const int blk = r * 4 + wave;
        gload_lds16(WT5 + blk * 512 + lane * 8, Wl + blk * 512);
    }
    const __hip_bfloat16* xsrc = Xhl + (size_t)blockIdx.x * 16384;
#pragma unroll
    for (int r = 0; r < 8; ++r) {
        const int blk = r * 4 + wave;
        gload_lds16(xsrc + blk * 512 + lane * 8, Xl + blk * 512);
    }
    __syncthreads();

    // ---- stage 1 ----
    short8 xa[2][2][2];
#pragma unroll
    for (int mt2 = 0; mt2 < 2; ++mt2)
#pragma unroll
        for (int s = 0; s < 2; ++s)
#pragma unroll
            for (int p = 0; p < 2; ++p) {
                const int ch = ((s * 4 + l4) | (p << 3)) ^ l15;
                xa[mt2][s][p] = *(const short8*)&Xl[(wave * 32 + mt2 * 16 + l15) * 128 + ch * 8];
            }

#pragma unroll
    for (int nt = 0; nt < 4; ++nt) {
        short8 wb[2][2];
#pragma unroll
        for (int s = 0; s < 2; ++s)
#pragma unroll
            for (int p = 0; p < 2; ++p) {
                const int ch = ((s * 4 + l4) | (p << 3)) ^ l15;
                wb[s][p] = *(const short8*)&Wl[(nt * 16 + l15) * 128 + ch * 8];
            }
        f32x4 ac[2] = {(f32x4)0.f, (f32x4)0.f};
#pragma unroll
        for (int mt2 = 0; mt2 < 2; ++mt2)
#pragma unroll
            for (int s = 0; s < 2; ++s) {
                ac[mt2] = __builtin_amdgcn_mfma_f32_16x16x32_bf16(xa[mt2][s][0], wb[s][0], ac[mt2], 0, 0, 0);
                ac[mt2] = __builtin_amdgcn_mfma_f32_16x16x32_bf16(xa[mt2][s][0], wb[s][1], ac[mt2], 0, 0, 0);
                ac[mt2] = __builtin_amdgcn_mfma_f32_16x16x32_bf16(xa[mt2][s][1], wb[s][0], ac[mt2], 0, 0, 0);
            }
        const int col = nt * 16 + l15;
        const float bc = bbb[col];
#pragma unroll
        for (int mt2 = 0; mt2 < 2; ++mt2)
#pragma unroll
            for (int q = 0; q < 4; ++q) {
                const int r15 = l4 * 4 + q;
                const int lr  = wave * 32 + mt2 * 16 + r15;
                const float v = fsilu(ac[mt2][q] + bc);
                __hip_bfloat16 h, l;
                hilo(v, h, l);
                Bb[lr * 128 + (((col >> 3)     ) ^ r15) * 8 + (col & 7)] = h;
                Bb[lr * 128 + (((col >> 3) | 8) ^ r15) * 8 + (col & 7)] = l;
            }
    }
    __syncthreads();

    // ---- stage 2 ----
    short8 ba[2][2][2];
#pragma unroll
    for (int mt2 = 0; mt2 < 2; ++mt2)
#pragma unroll
        for (int s = 0; s < 2; ++s)
#pragma unroll
            for (int p = 0; p < 2; ++p) {
                const int ch = ((s * 4 + l4) | (p << 3)) ^ l15;
                ba[mt2][s][p] = *(const short8*)&Bb[(wave * 32 + mt2 * 16 + l15) * 128 + ch * 8];
            }

#pragma unroll
    for (int nt = 0; nt < 4; ++nt) {
        f32x4 a2[4][2];
#pragma unroll
        for (int m = 0; m < 4; ++m)
#pragma unroll
            for (int mt2 = 0; mt2 < 2; ++mt2) a2[m][mt2] = (f32x4)0.f;

#pragma unroll
        for (int mat = 0; mat < 4; ++mat) {
            short8 w2[2][2];
#pragma unroll
            for (int s = 0; s < 2; ++s)
#pragma unroll
                for (int p = 0; p < 2; ++p) {
                    const int ch = ((s * 4 + l4) | (p << 3)) ^ l15;
                    w2[s][p] = *(const short8*)&Wl[((mat + 1) * 64 + nt * 16 + l15) * 128 + ch * 8];
                }
#pragma unroll
            for (int mt2 = 0; mt2 < 2; ++mt2)
#pragma unroll
                for (int s = 0; s < 2; ++s) {
                    a2[mat][mt2] = __builtin_amdgcn_mfma_f32_16x16x32_bf16(ba[mt2][s][0], w2[s][0], a2[mat][mt2], 0, 0, 0);
                    a2[mat][mt2] = __builtin_amdgcn_mfma_f32_16x16x32_bf16(ba[mt2][s][0], w2[s][1], a2[mat][mt2], 0, 0, 0);
                    a2[mat][mt2] = __builtin_amdgcn_mfma_f32_16x16x32_bf16(ba[mt2][s][1], w2[s][0], a2[mat][mt2], 0, 0, 0);
                }
        }

        const int col = nt * 16 + l15;
        const float b1 = f1b[col], b2 = f2b[col];
        const float b3 = taub[col] + taub2[col], b4 = decb[col];
        const size_t Rbase = (size_t)blockIdx.x * 128 + wave * 32;
#pragma unroll
        for (int mt2 = 0; mt2 < 2; ++mt2)
#pragma unroll
            for (int q = 0; q < 4; ++q) {
                const size_t R = Rbase + mt2 * 16 + l4 * 4 + q;
                const float f1v = ftanh(a2[0][mt2][q] + b1);
                const float f2v = ftanh(a2[1][mt2][q] + b2);
                const float tv  = fsig (a2[2][mt2][q] + b3);
                const float dv  = fsig (a2[3][mt2][q] + b4);
                cand [R * 64 + col] = f1v * (1.f - tv) + f2v * tv;
                decay[R * 64 + col] = dv;
            }
    }
}

// ---------------------------------------------------------------------------
// Chunked scan passes 1+2 (unchanged).
// ---------------------------------------------------------------------------
__global__ __launch_bounds__(256)
void scan_compose(const float* __restrict__ decay, const float* __restrict__ cand,
                  float* __restrict__ Ach, float* __restrict__ Bch)
{
    const int idx = blockIdx.x * 256 + threadIdx.x;
    const int p  = idx & 1023;
    const int rest = idx >> 10;
    const int ch = rest & 63, b = rest >> 6;
    float A = 1.f, Bv = 0.f;
    const size_t base = ((size_t)(b * SN + ch * 32) << 10) + p;
    for (int t = 0; t < 32; ++t) {
        const float d = decay[base + ((size_t)t << 10)];
        const float c = cand [base + ((size_t)t << 10)];
        A  *= d;
        Bv  = d * Bv + (1.f - d) * c;
    }
    Ach[(ch << 13) + (b << 10) + p] = A;
    Bch[(ch << 13) + (b << 10) + p] = Bv;
}

__global__ __launch_bounds__(256)
void scan_chunks(const float* __restrict__ Ach, const float* __restrict__ Bch,
                 float* __restrict__ hstart)
{
    const int q = blockIdx.x * 256 + threadIdx.x;
    float h = 0.f;
    for (int ch = 0; ch < 64; ++ch) {
        hstart[(ch << 13) + q] = h;
        h = Ach[(ch << 13) + q] * h + Bch[(ch << 13) + q];
    }
}

// ---------------------------------------------------------------------------
// scan_apply: final h per timestep, emitted directly as swizzled bf16 hi|lo
// rows (same format as Xhl) for the MFMA state_out kernel.  Hhl ALIASES the
// decay buffer (read-then-write, each window owned by one thread).
// ---------------------------------------------------------------------------
__global__ __launch_bounds__(256)
void scan_apply(const float* decay, const float* __restrict__ cand,
                const float* __restrict__ hstart, __hip_bfloat16* Hhl)
{
    const int idx = blockIdx.x * 256 + threadIdx.x;
    const int p  = idx & 1023;
    const int rest = idx >> 10;
    const int ch = rest & 63, b = rest >> 6;
    const int nh = p >> 6, ns = p & 63;
    const int hoff = (((ns >> 3)    ) ^ nh) * 8 + (ns & 7);
    const int loff = (((ns >> 3) | 8) ^ nh) * 8 + (ns & 7);
    float h = hstart[(ch << 13) + (b << 10) + p];
    const int t0 = b * SN + ch * 32;
    const size_t base = ((size_t)t0 << 10) + p;
    for (int t = 0; t < 32; ++t) {
        const size_t o = base + ((size_t)t << 10);
        const float d = decay[o];
        const float c = cand[o];
        h = d * h + (1.f - d) * c;
        __hip_bfloat16 hb, lb;
        hilo(h, hb, lb);
        const size_t row = ((size_t)(t0 + t) * 16 + nh) * 128;
        Hhl[row + hoff] = hb;
        Hhl[row + loff] = lb;
    }
}

// ---------------------------------------------------------------------------
// MFMA state_out: out = H @ sow + sob, gated by silu(z), emitted as bf16
// hi|lo rows for out_proj.  (round-5 version, proven)
// ---------------------------------------------------------------------------
__global__ __launch_bounds__(256)
void stateout_mfma(const __hip_bfloat16* __restrict__ Hhl,
                   const float* __restrict__ sow, const float* __restrict__ sob,
                   const float* __restrict__ zs, __hip_bfloat16* __restrict__ gA)
{
    __shared__ __hip_bfloat16 Wl[64 * 128];   // 16 KB
    __shared__ __hip_bfloat16 Hl[128 * 128];  // 32 KB
    const int tid  = threadIdx.x;
    const int lane = tid & 63, wave = tid >> 6;
    const int l15  = lane & 15, l4 = lane >> 4;

    {
        const int n = tid & 63;
        const int ob = (tid >> 6) * 2;
#pragma unroll
        for (int oo = 0; oo < 2; ++oo) {
            const int o = ob + oo;
#pragma unroll
            for (int j = 0; j < 8; ++j) {
                const float v = sow[(o * 8 + j) * 64 + n];
                __hip_bfloat16 hb, lb;
                hilo(v, hb, lb);
                Wl[n * 128 + ((o       ^ (n & 15)) * 8 + j)] = hb;
                Wl[n * 128 + (((o | 8) ^ (n & 15)) * 8 + j)] = lb;
            }
        }
    }
    const __hip_bfloat16* hsrc = Hhl + (size_t)blockIdx.x * 16384;
#pragma unroll
    for (int r = 0; r < 8; ++r) {
        const int blk = r * 4 + wave;
        gload_lds16(hsrc + blk * 512 + lane * 8, Hl + blk * 512);
    }
    __syncthreads();

    short8 ha[2][2][2];
#pragma unroll
    for (int mt2 = 0; mt2 < 2; ++mt2)
#pragma unroll
        for (int s = 0; s < 2; ++s)
#pragma unroll
            for (int p = 0; p < 2; ++p) {
                const int ch = ((s * 4 + l4) | (p << 3)) ^ l15;
                ha[mt2][s][p] = *(const short8*)&Hl[(wave * 32 + mt2 * 16 + l15) * 128 + ch * 8];
            }

#pragma unroll
    for (int nt = 0; nt < 4; ++nt) {
        short8 wb[2][2];
#pragma unroll
        for (int s = 0; s < 2; ++s)
#pragma unroll
            for (int p = 0; p < 2; ++p) {
                const int ch = ((s * 4 + l4) | (p << 3)) ^ l15;
                wb[s][p] = *(const short8*)&Wl[(nt * 16 + l15) * 128 + ch * 8];
            }
        f32x4 ac[2] = {(f32x4)0.f, (f32x4)0.f};
#pragma unroll
        for (int mt2 = 0; mt2 < 2; ++mt2)
#pragma unroll
            for (int s = 0; s < 2; ++s) {
                ac[mt2] = __builtin_amdgcn_mfma_f32_16x16x32_bf16(ha[mt2][s][0], wb[s][0], ac[mt2], 0, 0, 0);
                ac[mt2] = __builtin_amdgcn_mfma_f32_16x16x32_bf16(ha[mt2][s][0], wb[s][1], ac[mt2], 0, 0, 0);
                ac[mt2] = __builtin_amdgcn_mfma_f32_16x16x32_bf16(ha[mt2][s][1], wb[s][0], ac[mt2], 0, 0, 0);
            }
        const int col = nt * 16 + l15;
        const float bj = sob[col];
#pragma unroll
        for (int mt2 = 0; mt2 < 2; ++mt2)
#pragma unroll
            for (int q = 0; q < 4; ++q) {
                const size_t th = (size_t)blockIdx.x * 128 + wave * 32 + mt2 * 16 + l4 * 4 + q;
                const float v = (ac[mt2][q] + bj) * zs[th * 64 + col];
                __hip_bfloat16 hb, lb;
                hilo(v, hb, lb);
                const size_t token = th >> 4;
                const int colg = (int)(th & 15) * 64 + col;
                gA[token * 2048 + colg]        = hb;
                gA[token * 2048 + 1024 + colg] = lb;
            }
    }
}

// ---------------------------------------------------------------------------
extern "C" void kernel_launch(void* const* d_in, const int* in_sizes, int n_in,
                              void* d_out, int out_size, void* d_ws, size_t ws_size,
                              hipStream_t stream)
{
    const float* x     = (const float*)d_in[0];
    const float* ipw   = (const float*)d_in[1];
    const float* cw    = (const float*)d_in[2];
    const float* cb    = (const float*)d_in[3];
    const float* bbw   = (const float*)d_in[4];
    const float* bbb   = (const float*)d_in[5];
    const float* f1w   = (const float*)d_in[6];
    const float* f1b   = (const float*)d_in[7];
    const float* f2w   = (const float*)d_in[8];
    const float* f2b   = (const float*)d_in[9];
    const float* tauw  = (const float*)d_in[10];
    const float* taub  = (const float*)d_in[11];
    const float* taub2 = (const float*)d_in[12];
    const float* decw  = (const float*)d_in[13];
    const float* decb  = (const float*)d_in[14];
    const float* sow   = (const float*)d_in[15];
    const float* sob   = (const float*)d_in[16];
    const float* opw   = (const float*)d_in[17];

    float* out = (float*)d_out;
    char*  ws  = (char*)d_ws;
    const size_t MB = 1024 * 1024;

    // Workspace map (198 MiB):
    //  @0Mi   (64Mi): Ahl (bf16) -> Xhl (bf16, conv out) -> gA (bf16)
    //  @64Mi  (64Mi): xpath (f32) -> decay (f32) -> Hhl (bf16, in place)
    //  @128Mi (64Mi): BTin (8Mi, dead before cand) -> cand (f32)
    //  @192Mi (6Mi) : WT5 (80KB, dead before scan) -> Ach|Bch|hst -> BTout
    __hip_bfloat16* Ahl   = (__hip_bfloat16*)(ws);
    float*          xpath = (float*)(ws + 64 * MB);
    __hip_bfloat16* BTin  = (__hip_bfloat16*)(ws + 128 * MB);
    float*          cand  = (float*)(ws + 128 * MB);
    __hip_bfloat16* WT5   = (__hip_bfloat16*)(ws + 192 * MB);
    float*          Ach   = (float*)(ws + 192 * MB);
    float*          Bch   = Ach + 524288;
    float*          hst   = Bch + 524288;
    __hip_bfloat16* BTout = (__hip_bfloat16*)(ws + 192 * MB);
    __hip_bfloat16* Xhl   = (__hip_bfloat16*)(ws);
    __hip_bfloat16* gA    = (__hip_bfloat16*)(ws);
    float*          decay = xpath;
    __hip_bfloat16* Hhl   = (__hip_bfloat16*)(ws + 64 * MB);   // aliases decay
    float*          zsilu = out;   // d_out as scratch until final GEMM

    // 1) conversions
    x_to_a<<<16384, 256, 0, stream>>>(x, Ahl);
    w_to_bt<<<dim3(16, 32), 256, 0, stream>>>(ipw, BTin, 2048);
    w5_to_wt<<<10, 256, 0, stream>>>(bbw, f1w, f2w, tauw, decw, WT5);
    // 2) in_proj GEMM (split-bf16 MFMA, counted-vmcnt) + silu(z)
    mfma_gemm256<8, 1><<<512, 512, 0, stream>>>(Ahl, BTin, xpath, zsilu);
    // 3) conv + silu -> swizzled bf16 hi|lo X
    conv_silu_bf<<<8192, 256, 0, stream>>>(xpath, cw, cb, Xhl);
    // 4) fused MFMA backbone -> cand, decay
    backbone_mfma<<<2048, 256, 0, stream>>>(Xhl, WT5, bbb, f1b, f2b,
                                            taub, taub2, decb, cand, decay);
    // 5) chunked scan -> Hhl (bf16 hi|lo, in decay's storage)
    scan_compose<<<2048, 256, 0, stream>>>(decay, cand, Ach, Bch);
    scan_chunks<<<32, 256, 0, stream>>>(Ach, Bch, hst);
    scan_apply<<<2048, 256, 0, stream>>>(decay, cand, hst, Hhl);
    // 6) out_proj weight conversion (scan scratch dead)
    w_to_bt<<<dim3(16, 16), 256, 0, stream>>>(opw, BTout, 1024);
    // 7) state_out + gate (MFMA) -> bf16 hi|lo
    stateout_mfma<<<2048, 256, 0, stream>>>(Hhl, sow, sob, zsilu, gA);
    // 8) out_proj GEMM
    mfma_gemm256<4, 0><<<256, 512, 0, stream>>>(gA, BTout, out, nullptr);
}

// Round 9
// 422.161 us; speedup vs baseline: 1.5022x; 1.4279x over previous
//
#include <hip/hip_runtime.h>
#include <hip/hip_bf16.h>
#include <math.h>

// Problem constants
#define BN   8
#define SN   2048
#define HN   1024
#define NTOK 16384   // B*S
#define NHD  16
#define HDD  64
#define NSD  64

typedef __attribute__((ext_vector_type(8))) short short8;
typedef __attribute__((ext_vector_type(4))) float f32x4;

__device__ __forceinline__ float fsig(float x)  { return 1.f / (1.f + __expf(-x)); }
__device__ __forceinline__ float fsilu(float x) { return x / (1.f + __expf(-x)); }
__device__ __forceinline__ float ftanh(float x) {
    const float t = __expf(-2.f * fabsf(x));
    const float r = (1.f - t) / (1.f + t);
    return x >= 0.f ? r : -r;
}
__device__ __forceinline__ void hilo(float v, __hip_bfloat16& h, __hip_bfloat16& l) {
    h = __float2bfloat16(v);
    l = __float2bfloat16(v - __bfloat162float(h));
}
__device__ __forceinline__ void gload_lds16(const void* g, void* l) {
    __builtin_amdgcn_global_load_lds(
        (const __attribute__((address_space(1))) unsigned int*)g,
        (__attribute__((address_space(3))) unsigned int*)l, 16, 0, 0);
}

// ---------------------------------------------------------------------------
// x (16384x1024 f32) -> A (16384x1024 bf16), pre-swizzled rows for the GEMM:
// logical octet c of row r stored at chunk (c&120)|((c&7)^(r&7)).
// ---------------------------------------------------------------------------
__global__ __launch_bounds__(256)
void x_to_a_bf(const float* __restrict__ X, __hip_bfloat16* __restrict__ A)
{
    const int idx = blockIdx.x * 256 + threadIdx.x;   // 2M octets
    const int r = idx >> 7;
    const int c = idx & 127;                          // logical octet
    const float* src = &X[(size_t)r * 1024 + c * 8];
    alignas(16) __hip_bfloat16 b[8];
#pragma unroll
    for (int j = 0; j < 8; ++j) b[j] = __float2bfloat16(src[j]);
    const int cs = (c & 120) | ((c & 7) ^ (r & 7));   // swizzle within 8-chunk group
    *(short8*)&A[(size_t)r * 1024 + cs * 8] = *(const short8*)b;
}

// ---------------------------------------------------------------------------
// W (1024 x N f32, (in,out)) -> BT (N x 1024 bf16), same pre-swizzle:
// logical octet (k>>3) of row n at chunk XOR (n&7).  64x64 LDS-tiled.
// ---------------------------------------------------------------------------
__global__ __launch_bounds__(256)
void w_to_bt_bf(const float* __restrict__ W, __hip_bfloat16* __restrict__ BT, int N)
{
    __shared__ float t[64][65];
    const int k0 = blockIdx.x * 64;
    const int n0 = blockIdx.y * 64;
    const int c  = threadIdx.x & 63, r4 = threadIdx.x >> 6;
#pragma unroll
    for (int rr = 0; rr < 64; rr += 4)
        t[rr + r4][c] = W[(size_t)(k0 + rr + r4) * N + n0 + c];
    __syncthreads();
#pragma unroll
    for (int oo = 0; oo < 2; ++oo) {
        const int o = r4 * 2 + oo;                 // octet within 64-k tile
        alignas(16) __hip_bfloat16 b[8];
#pragma unroll
        for (int j = 0; j < 8; ++j)
            b[j] = __float2bfloat16(t[o * 8 + j][c]);
        const int n = n0 + c;
        const int cglob = (k0 >> 3) + o;           // global octet index
        const int cs = (cglob & 120) | ((cglob & 7) ^ (n & 7));
        *(short8*)&BT[(size_t)n * 1024 + cs * 8] = *(const short8*)b;
    }
}

// ---------------------------------------------------------------------------
// 5 backbone weight mats (64x64 f32, (k,n)) -> WT5[mat][n][16 chunks x 8 bf16]
// hi octet o at chunk (o ^ (n&15)), lo at ((o|8) ^ (n&15)).  (pre-swizzled)
// ---------------------------------------------------------------------------
__global__ __launch_bounds__(256)
void w5_to_wt(const float* __restrict__ w0, const float* __restrict__ w1,
              const float* __restrict__ w2, const float* __restrict__ w3,
              const float* __restrict__ w4, __hip_bfloat16* __restrict__ WT5)
{
    const int idx = blockIdx.x * 256 + threadIdx.x;
    if (idx >= 2560) return;
    const int o = idx & 7, n = (idx >> 3) & 63, mat = idx >> 9;
    const float* W = mat == 0 ? w0 : mat == 1 ? w1 : mat == 2 ? w2 : mat == 3 ? w3 : w4;
    alignas(16) __hip_bfloat16 hb[8], lb[8];
#pragma unroll
    for (int j = 0; j < 8; ++j) {
        const float v = W[(o * 8 + j) * 64 + n];
        hilo(v, hb[j], lb[j]);
    }
    __hip_bfloat16* row = WT5 + (size_t)(mat * 64 + n) * 128;
    *(short8*)&row[((o     ) ^ (n & 15)) * 8] = *(const short8*)hb;
    *(short8*)&row[((o | 8) ^ (n & 15)) * 8] = *(const short8*)lb;
}

// ---------------------------------------------------------------------------
// Pure-bf16 MFMA GEMM: C = A*B, A[16384][1024] bf16, BT[N][1024] bf16, both
// pre-swizzled (chunk ^= row&7).  256x256 tile, BK=64, 8 waves (2Mx4N),
// double-buffered LDS (128 KB), round-5 schedule: one __syncthreads per
// K-tile, prefetch spread through compute, setprio.
// FIX vs round 8: stage verbatim from pre-swizzled global (no XOR at stage);
// LDS holds the swizzled layout; only the ds_read applies the XOR.
// ---------------------------------------------------------------------------
template<int NCT, int MODE>
__global__ __launch_bounds__(512, 2)
void mfma_gemm256(const __hip_bfloat16* __restrict__ A,
                  const __hip_bfloat16* __restrict__ BT,
                  float* __restrict__ out0, float* __restrict__ out1)
{
    __shared__ __hip_bfloat16 lds[2][2][16384];   // [buf][A/B][256 rows x 64 k]
    const int tid  = threadIdx.x;
    const int lane = tid & 63, wave = tid >> 6;
    const int wr   = wave >> 2, wc = wave & 3;     // 2 x 4 wave grid
    const int l15  = lane & 15, l4 = lane >> 4;

    // XCD-aware bijective swizzle (gridDim.x % 8 == 0 at both call sites)
    const int nwg = gridDim.x;
    const int cpx = nwg >> 3;
    const int swz = (blockIdx.x & 7) * cpx + (blockIdx.x >> 3);
    const int mt = swz / NCT, nt = swz % NCT;
    const int row0 = mt * 256, col0 = nt * 256;

    // staging map: tid -> (s_c chunk 0..7, s_r row 0..63); issue i covers
    // mat = i>>2, row-group (i&3)*64.  Dest = uniform + lane*16 (verified).
    const int s_c = tid & 7;
    const int s_r = (tid >> 3) & 63;

    f32x4 acc[8][4];
#pragma unroll
    for (int m = 0; m < 8; ++m)
#pragma unroll
        for (int n = 0; n < 4; ++n) acc[m][n] = (f32x4)0.f;

#define STAGE_I(I, TT, BUF)                                                    \
    {                                                                          \
        const int mat_ = (I) >> 2;                                             \
        const int row_ = ((I) & 3) * 64 + s_r;                                 \
        const __hip_bfloat16* src_ = (mat_ == 0)                               \
            ? &A [(size_t)(row0 + row_) * 1024 + ((TT) << 6) + s_c * 8]        \
            : &BT[(size_t)(col0 + row_) * 1024 + ((TT) << 6) + s_c * 8];       \
        gload_lds16(src_, &lds[BUF][mat_][row_ * 64 + s_c * 8]);               \
    }

    // ---- prologue: stage K-tile 0 into buf 0 ----
#pragma unroll
    for (int i = 0; i < 8; ++i) STAGE_I(i, 0, 0)
    __syncthreads();

    for (int t = 0; t < 16; ++t) {
        const int cur = t & 1, nxt = cur ^ 1;
        const bool pf = (t < 15);

#pragma unroll
        for (int ks = 0; ks < 2; ++ks) {
            // prefetch 4 of 8 loads for tile t+1
            if (pf) {
#pragma unroll
                for (int i = ks * 4; i < ks * 4 + 4; ++i) STAGE_I(i, t + 1, nxt)
            }

            // ds_read fragments (swizzled chunk): uniform 8-lanes/slot = floor
            short8 af[8], bf[4];
#pragma unroll
            for (int m = 0; m < 8; ++m) {
                const int row = wr * 128 + m * 16 + l15;
                const int ch = (ks * 4 + l4) ^ (l15 & 7);
                af[m] = *(const short8*)&lds[cur][0][row * 64 + ch * 8];
            }
#pragma unroll
            for (int n = 0; n < 4; ++n) {
                const int row = wc * 64 + n * 16 + l15;
                const int ch = (ks * 4 + l4) ^ (l15 & 7);
                bf[n] = *(const short8*)&lds[cur][1][row * 64 + ch * 8];
            }

            __builtin_amdgcn_s_setprio(1);
#pragma unroll
            for (int m = 0; m < 8; ++m)
#pragma unroll
                for (int n = 0; n < 4; ++n)
                    acc[m][n] = __builtin_amdgcn_mfma_f32_16x16x32_bf16(af[m], bf[n], acc[m][n], 0, 0, 0);
            __builtin_amdgcn_s_setprio(0);
        }
        __syncthreads();   // reads of buf[cur] done + prefetch into buf[nxt] landed
    }
#undef STAGE_I

    // epilogue: C/D layout col=lane&15, row=(lane>>4)*4+q
    const int orow = l4 * 4, ocol = l15;
#pragma unroll
    for (int M = 0; M < 8; ++M)
#pragma unroll
        for (int N = 0; N < 4; ++N) {
            const int c = col0 + wc * 64 + N * 16 + ocol;
#pragma unroll
            for (int q = 0; q < 4; ++q) {
                const int r = row0 + wr * 128 + M * 16 + orow + q;
                const float v = acc[M][N][q];
                if (MODE == 0) {
                    out0[(size_t)r * (NCT * 256) + c] = v;
                } else {
                    if (c < 1024) out0[(size_t)r * 1024 + c] = v;
                    else          out1[(size_t)r * 1024 + (c - 1024)] = fsilu(v);
                }
            }
        }
}

// ---------------------------------------------------------------------------
// Depthwise causal conv (K=4) + bias + silu -> X as swizzled bf16 hi|lo rows.
// ---------------------------------------------------------------------------
__global__ __launch_bounds__(256)
void conv_silu_bf(const float* __restrict__ xp, const float* __restrict__ cw,
                  const float* __restrict__ cb, __hip_bfloat16* __restrict__ Xhl)
{
    const int idx = blockIdx.x * 256 + threadIdx.x;   // NTOK*128 octets
    const int g  = idx & 127;
    const int bt = idx >> 7;
    const int t  = bt & (SN - 1);
    const int c0 = g * 8;

    float acc[8];
#pragma unroll
    for (int j = 0; j < 8; ++j) acc[j] = cb[c0 + j];
    float4 cwv[8];
#pragma unroll
    for (int j = 0; j < 8; ++j) cwv[j] = *(const float4*)&cw[(c0 + j) * 4];
    const float* cwf = (const float*)cwv;

#pragma unroll
    for (int k = 0; k < 4; ++k) {
        const int tt = t - 3 + k;
        if (tt >= 0) {
            const float* xr = xp + (((size_t)(bt - 3 + k)) << 10) + c0;
            const float4 u0 = *(const float4*)&xr[0];
            const float4 u1 = *(const float4*)&xr[4];
            const float u[8] = {u0.x, u0.y, u0.z, u0.w, u1.x, u1.y, u1.z, u1.w};
#pragma unroll
            for (int j = 0; j < 8; ++j) acc[j] += cwf[j * 4 + k] * u[j];
        }
    }

    alignas(16) __hip_bfloat16 hb[8], lb[8];
#pragma unroll
    for (int j = 0; j < 8; ++j)
        hilo(fsilu(acc[j]), hb[j], lb[j]);

    const int head = c0 >> 6;
    const int o    = (c0 >> 3) & 7;
    __hip_bfloat16* row = Xhl + ((size_t)bt * 16 + head) * 128;
    *(short8*)&row[((o     ) ^ head) * 8] = *(const short8*)hb;
    *(short8*)&row[((o | 8) ^ head) * 8] = *(const short8*)lb;
}

// ---------------------------------------------------------------------------
// Fused MFMA backbone (unchanged, hi|lo 3-product).
// ---------------------------------------------------------------------------
__global__ __launch_bounds__(256, 1)
void backbone_mfma(const __hip_bfloat16* __restrict__ Xhl,
                   const __hip_bfloat16* __restrict__ WT5,
                   const float* __restrict__ bbb,
                   const float* __restrict__ f1b, const float* __restrict__ f2b,
                   const float* __restrict__ taub, const float* __restrict__ taub2,
                   const float* __restrict__ decb,
                   float* __restrict__ cand, float* __restrict__ decay)
{
    __shared__ __hip_bfloat16 Wl[5 * 64 * 128];   // 80 KB
    __shared__ __hip_bfloat16 Xl[128 * 128];      // 32 KB
    __shared__ __hip_bfloat16 Bb[128 * 128];      // 32 KB
    const int tid  = threadIdx.x;
    const int lane = tid & 63, wave = tid >> 6;
    const int l15  = lane & 15, l4 = lane >> 4;

#pragma unroll
    for (int r = 0; r < 20; ++r) {
        const int blk = r * 4 + wave;
        gload_lds16(WT5 + blk * 512 + lane * 8, Wl + blk * 512);
    }
    const __hip_bfloat16* xsrc = Xhl + (size_t)blockIdx.x * 16384;
#pragma unroll
    for (int r = 0; r < 8; ++r) {
        const int blk = r * 4 + wave;
        gload_lds16(xsrc + blk * 512 + lane * 8, Xl + blk * 512);
    }
    __syncthreads();

    // ---- stage 1 ----
    short8 xa[2][2][2];
#pragma unroll
    for (int mt2 = 0; mt2 < 2; ++mt2)
#pragma unroll
        for (int s = 0; s < 2; ++s)
#pragma unroll
            for (int p = 0; p < 2; ++p) {
                const int ch = ((s * 4 + l4) | (p << 3)) ^ l15;
                xa[mt2][s][p] = *(const short8*)&Xl[(wave * 32 + mt2 * 16 + l15) * 128 + ch * 8];
            }

#pragma unroll
    for (int nt = 0; nt < 4; ++nt) {
        short8 wb[2][2];
#pragma unroll
        for (int s = 0; s < 2; ++s)
#pragma unroll
            for (int p = 0; p < 2; ++p) {
                const int ch = ((s * 4 + l4) | (p << 3)) ^ l15;
                wb[s][p] = *(const short8*)&Wl[(nt * 16 + l15) * 128 + ch * 8];
            }
        f32x4 ac[2] = {(f32x4)0.f, (f32x4)0.f};
#pragma unroll
        for (int mt2 = 0; mt2 < 2; ++mt2)
#pragma unroll
            for (int s = 0; s < 2; ++s) {
                ac[mt2] = __builtin_amdgcn_mfma_f32_16x16x32_bf16(xa[mt2][s][0], wb[s][0], ac[mt2], 0, 0, 0);
                ac[mt2] = __builtin_amdgcn_mfma_f32_16x16x32_bf16(xa[mt2][s][0], wb[s][1], ac[mt2], 0, 0, 0);
                ac[mt2] = __builtin_amdgcn_mfma_f32_16x16x32_bf16(xa[mt2][s][1], wb[s][0], ac[mt2], 0, 0, 0);
            }
        const int col = nt * 16 + l15;
        const float bc = bbb[col];
#pragma unroll
        for (int mt2 = 0; mt2 < 2; ++mt2)
#pragma unroll
            for (int q = 0; q < 4; ++q) {
                const int r15 = l4 * 4 + q;
                const int lr  = wave * 32 + mt2 * 16 + r15;
                const float v = fsilu(ac[mt2][q] + bc);
                __hip_bfloat16 h, l;
                hilo(v, h, l);
                Bb[lr * 128 + (((col >> 3)     ) ^ r15) * 8 + (col & 7)] = h;
                Bb[lr * 128 + (((col >> 3) | 8) ^ r15) * 8 + (col & 7)] = l;
            }
    }
    __syncthreads();

    // ---- stage 2 ----
    short8 ba[2][2][2];
#pragma unroll
    for (int mt2 = 0; mt2 < 2; ++mt2)
#pragma unroll
        for (int s = 0; s < 2; ++s)
#pragma unroll
            for (int p = 0; p < 2; ++p) {
                const int ch = ((s * 4 + l4) | (p << 3)) ^ l15;
                ba[mt2][s][p] = *(const short8*)&Bb[(wave * 32 + mt2 * 16 + l15) * 128 + ch * 8];
            }

#pragma unroll
    for (int nt = 0; nt < 4; ++nt) {
        f32x4 a2[4][2];
#pragma unroll
        for (int m = 0; m < 4; ++m)
#pragma unroll
            for (int mt2 = 0; mt2 < 2; ++mt2) a2[m][mt2] = (f32x4)0.f;

#pragma unroll
        for (int mat = 0; mat < 4; ++mat) {
            short8 w2[2][2];
#pragma unroll
            for (int s = 0; s < 2; ++s)
#pragma unroll
                for (int p = 0; p < 2; ++p) {
                    const int ch = ((s * 4 + l4) | (p << 3)) ^ l15;
                    w2[s][p] = *(const short8*)&Wl[((mat + 1) * 64 + nt * 16 + l15) * 128 + ch * 8];
                }
#pragma unroll
            for (int mt2 = 0; mt2 < 2; ++mt2)
#pragma unroll
                for (int s = 0; s < 2; ++s) {
                    a2[mat][mt2] = __builtin_amdgcn_mfma_f32_16x16x32_bf16(ba[mt2][s][0], w2[s][0], a2[mat][mt2], 0, 0, 0);
                    a2[mat][mt2] = __builtin_amdgcn_mfma_f32_16x16x32_bf16(ba[mt2][s][0], w2[s][1], a2[mat][mt2], 0, 0, 0);
                    a2[mat][mt2] = __builtin_amdgcn_mfma_f32_16x16x32_bf16(ba[mt2][s][1], w2[s][0], a2[mat][mt2], 0, 0, 0);
                }
        }

        const int col = nt * 16 + l15;
        const float b1 = f1b[col], b2 = f2b[col];
        const float b3 = taub[col] + taub2[col], b4 = decb[col];
        const size_t Rbase = (size_t)blockIdx.x * 128 + wave * 32;
#pragma unroll
        for (int mt2 = 0; mt2 < 2; ++mt2)
#pragma unroll
            for (int q = 0; q < 4; ++q) {
                const size_t R = Rbase + mt2 * 16 + l4 * 4 + q;
                const float f1v = ftanh(a2[0][mt2][q] + b1);
                const float f2v = ftanh(a2[1][mt2][q] + b2);
                const float tv  = fsig (a2[2][mt2][q] + b3);
                const float dv  = fsig (a2[3][mt2][q] + b4);
                cand [R * 64 + col] = f1v * (1.f - tv) + f2v * tv;
                decay[R * 64 + col] = dv;
            }
    }
}

// ---------------------------------------------------------------------------
// Chunked scan passes 1+2 (unchanged).
// ---------------------------------------------------------------------------
__global__ __launch_bounds__(256)
void scan_compose(const float* __restrict__ decay, const float* __restrict__ cand,
                  float* __restrict__ Ach, float* __restrict__ Bch)
{
    const int idx = blockIdx.x * 256 + threadIdx.x;
    const int p  = idx & 1023;
    const int rest = idx >> 10;
    const int ch = rest & 63, b = rest >> 6;
    float A = 1.f, Bv = 0.f;
    const size_t base = ((size_t)(b * SN + ch * 32) << 10) + p;
    for (int t = 0; t < 32; ++t) {
        const float d = decay[base + ((size_t)t << 10)];
        const float c = cand [base + ((size_t)t << 10)];
        A  *= d;
        Bv  = d * Bv + (1.f - d) * c;
    }
    Ach[(ch << 13) + (b << 10) + p] = A;
    Bch[(ch << 13) + (b << 10) + p] = Bv;
}

__global__ __launch_bounds__(256)
void scan_chunks(const float* __restrict__ Ach, const float* __restrict__ Bch,
                 float* __restrict__ hstart)
{
    const int q = blockIdx.x * 256 + threadIdx.x;
    float h = 0.f;
    for (int ch = 0; ch < 64; ++ch) {
        hstart[(ch << 13) + q] = h;
        h = Ach[(ch << 13) + q] * h + Bch[(ch << 13) + q];
    }
}

// ---------------------------------------------------------------------------
// scan_apply: final h per timestep as swizzled bf16 hi|lo rows (Xhl format).
// Hhl aliases decay (read-then-write, each window owned by one thread).
// ---------------------------------------------------------------------------
__global__ __launch_bounds__(256)
void scan_apply(const float* decay, const float* __restrict__ cand,
                const float* __restrict__ hstart, __hip_bfloat16* Hhl)
{
    const int idx = blockIdx.x * 256 + threadIdx.x;
    const int p  = idx & 1023;
    const int rest = idx >> 10;
    const int ch = rest & 63, b = rest >> 6;
    const int nh = p >> 6, ns = p & 63;
    const int hoff = (((ns >> 3)    ) ^ nh) * 8 + (ns & 7);
    const int loff = (((ns >> 3) | 8) ^ nh) * 8 + (ns & 7);
    float h = hstart[(ch << 13) + (b << 10) + p];
    const int t0 = b * SN + ch * 32;
    const size_t base = ((size_t)t0 << 10) + p;
    for (int t = 0; t < 32; ++t) {
        const size_t o = base + ((size_t)t << 10);
        const float d = decay[o];
        const float c = cand[o];
        h = d * h + (1.f - d) * c;
        __hip_bfloat16 hb, lb;
        hilo(h, hb, lb);
        const size_t row = ((size_t)(t0 + t) * 16 + nh) * 128;
        Hhl[row + hoff] = hb;
        Hhl[row + loff] = lb;
    }
}

// ---------------------------------------------------------------------------
// MFMA state_out: out = H @ sow + sob, gated by silu(z); emits PURE bf16
// rows for the bf16 out_proj GEMM, pre-swizzled (chunk ^= row&7).
// ---------------------------------------------------------------------------
__global__ __launch_bounds__(256)
void stateout_mfma(const __hip_bfloat16* __restrict__ Hhl,
                   const float* __restrict__ sow, const float* __restrict__ sob,
                   const float* __restrict__ zs, __hip_bfloat16* __restrict__ gA)
{
    __shared__ __hip_bfloat16 Wl[64 * 128];   // 16 KB
    __shared__ __hip_bfloat16 Hl[128 * 128];  // 32 KB
    const int tid  = threadIdx.x;
    const int lane = tid & 63, wave = tid >> 6;
    const int l15  = lane & 15, l4 = lane >> 4;

    {
        const int n = tid & 63;
        const int ob = (tid >> 6) * 2;
#pragma unroll
        for (int oo = 0; oo < 2; ++oo) {
            const int o = ob + oo;
#pragma unroll
            for (int j = 0; j < 8; ++j) {
                const float v = sow[(o * 8 + j) * 64 + n];
                __hip_bfloat16 hb, lb;
                hilo(v, hb, lb);
                Wl[n * 128 + ((o       ^ (n & 15)) * 8 + j)] = hb;
                Wl[n * 128 + (((o | 8) ^ (n & 15)) * 8 + j)] = lb;
            }
        }
    }
    const __hip_bfloat16* hsrc = Hhl + (size_t)blockIdx.x * 16384;
#pragma unroll
    for (int r = 0; r < 8; ++r) {
        const int blk = r * 4 + wave;
        gload_lds16(hsrc + blk * 512 + lane * 8, Hl + blk * 512);
    }
    __syncthreads();

    short8 ha[2][2][2];
#pragma unroll
    for (int mt2 = 0; mt2 < 2; ++mt2)
#pragma unroll
        for (int s = 0; s < 2; ++s)
#pragma unroll
            for (int p = 0; p < 2; ++p) {
                const int ch = ((s * 4 + l4) | (p << 3)) ^ l15;
                ha[mt2][s][p] = *(const short8*)&Hl[(wave * 32 + mt2 * 16 + l15) * 128 + ch * 8];
            }

#pragma unroll
    for (int nt = 0; nt < 4; ++nt) {
        short8 wb[2][2];
#pragma unroll
        for (int s = 0; s < 2; ++s)
#pragma unroll
            for (int p = 0; p < 2; ++p) {
                const int ch = ((s * 4 + l4) | (p << 3)) ^ l15;
                wb[s][p] = *(const short8*)&Wl[(nt * 16 + l15) * 128 + ch * 8];
            }
        f32x4 ac[2] = {(f32x4)0.f, (f32x4)0.f};
#pragma unroll
        for (int mt2 = 0; mt2 < 2; ++mt2)
#pragma unroll
            for (int s = 0; s < 2; ++s) {
                ac[mt2] = __builtin_amdgcn_mfma_f32_16x16x32_bf16(ha[mt2][s][0], wb[s][0], ac[mt2], 0, 0, 0);
                ac[mt2] = __builtin_amdgcn_mfma_f32_16x16x32_bf16(ha[mt2][s][0], wb[s][1], ac[mt2], 0, 0, 0);
                ac[mt2] = __builtin_amdgcn_mfma_f32_16x16x32_bf16(ha[mt2][s][1], wb[s][0], ac[mt2], 0, 0, 0);
            }
        const int col = nt * 16 + l15;
        const float bj = sob[col];
#pragma unroll
        for (int mt2 = 0; mt2 < 2; ++mt2)
#pragma unroll
            for (int q = 0; q < 4; ++q) {
                const size_t th = (size_t)blockIdx.x * 128 + wave * 32 + mt2 * 16 + l4 * 4 + q;
                const float v = (ac[mt2][q] + bj) * zs[th * 64 + col];
                const size_t token = th >> 4;
                const int colg = (int)(th & 15) * 64 + col;   // 0..1023
                const int cg = colg >> 3, jg = colg & 7;      // octet, elem
                const int cs = (cg & 120) | ((cg & 7) ^ ((int)(token & 7)));
                gA[token * 1024 + cs * 8 + jg] = __float2bfloat16(v);
            }
    }
}

// ---------------------------------------------------------------------------
extern "C" void kernel_launch(void* const* d_in, const int* in_sizes, int n_in,
                              void* d_out, int out_size, void* d_ws, size_t ws_size,
                              hipStream_t stream)
{
    const float* x     = (const float*)d_in[0];
    const float* ipw   = (const float*)d_in[1];
    const float* cw    = (const float*)d_in[2];
    const float* cb    = (const float*)d_in[3];
    const float* bbw   = (const float*)d_in[4];
    const float* bbb   = (const float*)d_in[5];
    const float* f1w   = (const float*)d_in[6];
    const float* f1b   = (const float*)d_in[7];
    const float* f2w   = (const float*)d_in[8];
    const float* f2b   = (const float*)d_in[9];
    const float* tauw  = (const float*)d_in[10];
    const float* taub  = (const float*)d_in[11];
    const float* taub2 = (const float*)d_in[12];
    const float* decw  = (const float*)d_in[13];
    const float* decb  = (const float*)d_in[14];
    const float* sow   = (const float*)d_in[15];
    const float* sob   = (const float*)d_in[16];
    const float* opw   = (const float*)d_in[17];

    float* out = (float*)d_out;
    char*  ws  = (char*)d_ws;
    const size_t MB = 1024 * 1024;

    // Workspace map (198 MiB):
    //  @0Mi   (64Mi): Abf (bf16 32Mi) -> Xhl (bf16 64Mi, conv out) -> gA (bf16 32Mi)
    //  @64Mi  (64Mi): xpath (f32) -> decay (f32) -> Hhl (bf16, in place)
    //  @128Mi (64Mi): BTin_bf (4Mi, dead before cand) -> cand (f32)
    //  @192Mi (6Mi) : WT5 (80KB, dead before scan) -> Ach|Bch|hst -> BTout (2Mi)
    __hip_bfloat16* Abf   = (__hip_bfloat16*)(ws);
    float*          xpath = (float*)(ws + 64 * MB);
    __hip_bfloat16* BTin  = (__hip_bfloat16*)(ws + 128 * MB);
    float*          cand  = (float*)(ws + 128 * MB);
    __hip_bfloat16* WT5   = (__hip_bfloat16*)(ws + 192 * MB);
    float*          Ach   = (float*)(ws + 192 * MB);
    float*          Bch   = Ach + 524288;
    float*          hst   = Bch + 524288;
    __hip_bfloat16* BTout = (__hip_bfloat16*)(ws + 192 * MB);
    __hip_bfloat16* Xhl   = (__hip_bfloat16*)(ws);
    __hip_bfloat16* gA    = (__hip_bfloat16*)(ws);
    float*          decay = xpath;
    __hip_bfloat16* Hhl   = (__hip_bfloat16*)(ws + 64 * MB);   // aliases decay
    float*          zsilu = out;   // d_out as scratch until final GEMM

    // 1) conversions (pure bf16 for GEMM operands)
    x_to_a_bf<<<8192, 256, 0, stream>>>(x, Abf);
    w_to_bt_bf<<<dim3(16, 32), 256, 0, stream>>>(ipw, BTin, 2048);
    w5_to_wt<<<10, 256, 0, stream>>>(bbw, f1w, f2w, tauw, decw, WT5);
    // 2) in_proj GEMM (pure bf16 MFMA) + silu(z)
    mfma_gemm256<8, 1><<<512, 512, 0, stream>>>(Abf, BTin, xpath, zsilu);
    // 3) conv + silu -> swizzled bf16 hi|lo X
    conv_silu_bf<<<8192, 256, 0, stream>>>(xpath, cw, cb, Xhl);
    // 4) fused MFMA backbone -> cand, decay
    backbone_mfma<<<2048, 256, 0, stream>>>(Xhl, WT5, bbb, f1b, f2b,
                                            taub, taub2, decb, cand, decay);
    // 5) chunked scan -> Hhl (bf16 hi|lo, in decay's storage)
    scan_compose<<<2048, 256, 0, stream>>>(decay, cand, Ach, Bch);
    scan_chunks<<<32, 256, 0, stream>>>(Ach, Bch, hst);
    scan_apply<<<2048, 256, 0, stream>>>(decay, cand, hst, Hhl);
    // 6) out_proj weight conversion (scan scratch dead)
    w_to_bt_bf<<<dim3(16, 16), 256, 0, stream>>>(opw, BTout, 1024);
    // 7) state_out + gate (MFMA) -> pure bf16 gA
    stateout_mfma<<<2048, 256, 0, stream>>>(Hhl, sow, sob, zsilu, gA);
    // 8) out_proj GEMM (pure bf16)
    mfma_gemm256<4, 0><<<256, 512, 0, stream>>>(gA, BTout, out, nullptr);
}

// Round 11
// 358.762 us; speedup vs baseline: 1.7677x; 1.1767x over previous
//
#include <hip/hip_runtime.h>
#include <hip/hip_bf16.h>
#include <math.h>

// Problem constants
#define BN   8
#define SN   2048
#define HN   1024
#define NTOK 16384   // B*S
#define NHD  16
#define HDD  64
#define NSD  64

typedef __attribute__((ext_vector_type(8))) short short8;
typedef __attribute__((ext_vector_type(4))) float f32x4;

__device__ __forceinline__ float fsig(float x)  { return 1.f / (1.f + __expf(-x)); }
__device__ __forceinline__ float fsilu(float x) { return x / (1.f + __expf(-x)); }
__device__ __forceinline__ float ftanh(float x) {
    const float t = __expf(-2.f * fabsf(x));
    const float r = (1.f - t) / (1.f + t);
    return x >= 0.f ? r : -r;
}
__device__ __forceinline__ void hilo(float v, __hip_bfloat16& h, __hip_bfloat16& l) {
    h = __float2bfloat16(v);
    l = __float2bfloat16(v - __bfloat162float(h));
}
__device__ __forceinline__ unsigned pack_cd(float cand, float dec) {
    __hip_bfloat16 cb_ = __float2bfloat16(cand);
    __hip_bfloat16 db_ = __float2bfloat16(dec);
    return (unsigned)*(unsigned short*)&cb_ | ((unsigned)*(unsigned short*)&db_ << 16);
}
__device__ __forceinline__ void gload_lds16(const void* g, void* l) {
    __builtin_amdgcn_global_load_lds(
        (const __attribute__((address_space(1))) unsigned int*)g,
        (__attribute__((address_space(3))) unsigned int*)l, 16, 0, 0);
}

// ---------------------------------------------------------------------------
// x (16384x1024 f32) -> A (16384x1024 bf16), pre-swizzled rows for the GEMM:
// logical octet c of row r stored at chunk (c&120)|((c&7)^(r&7)).
// ---------------------------------------------------------------------------
__global__ __launch_bounds__(256)
void x_to_a_bf(const float* __restrict__ X, __hip_bfloat16* __restrict__ A)
{
    const int idx = blockIdx.x * 256 + threadIdx.x;   // 2M octets
    const int r = idx >> 7;
    const int c = idx & 127;                          // logical octet
    const float* src = &X[(size_t)r * 1024 + c * 8];
    alignas(16) __hip_bfloat16 b[8];
#pragma unroll
    for (int j = 0; j < 8; ++j) b[j] = __float2bfloat16(src[j]);
    const int cs = (c & 120) | ((c & 7) ^ (r & 7));   // swizzle within 8-chunk group
    *(short8*)&A[(size_t)r * 1024 + cs * 8] = *(const short8*)b;
}

// ---------------------------------------------------------------------------
// W (1024 x N f32, (in,out)) -> BT (N x 1024 bf16), same pre-swizzle.
// ---------------------------------------------------------------------------
__global__ __launch_bounds__(256)
void w_to_bt_bf(const float* __restrict__ W, __hip_bfloat16* __restrict__ BT, int N)
{
    __shared__ float t[64][65];
    const int k0 = blockIdx.x * 64;
    const int n0 = blockIdx.y * 64;
    const int c  = threadIdx.x & 63, r4 = threadIdx.x >> 6;
#pragma unroll
    for (int rr = 0; rr < 64; rr += 4)
        t[rr + r4][c] = W[(size_t)(k0 + rr + r4) * N + n0 + c];
    __syncthreads();
#pragma unroll
    for (int oo = 0; oo < 2; ++oo) {
        const int o = r4 * 2 + oo;                 // octet within 64-k tile
        alignas(16) __hip_bfloat16 b[8];
#pragma unroll
        for (int j = 0; j < 8; ++j)
            b[j] = __float2bfloat16(t[o * 8 + j][c]);
        const int n = n0 + c;
        const int cglob = (k0 >> 3) + o;           // global octet index
        const int cs = (cglob & 120) | ((cglob & 7) ^ (n & 7));
        *(short8*)&BT[(size_t)n * 1024 + cs * 8] = *(const short8*)b;
    }
}

// ---------------------------------------------------------------------------
// 5 backbone weight mats (64x64 f32, (k,n)) -> WT5[mat][n][16 chunks x 8 bf16]
// hi octet o at chunk (o ^ (n&15)), lo at ((o|8) ^ (n&15)).  (pre-swizzled)
// ---------------------------------------------------------------------------
__global__ __launch_bounds__(256)
void w5_to_wt(const float* __restrict__ w0, const float* __restrict__ w1,
              const float* __restrict__ w2, const float* __restrict__ w3,
              const float* __restrict__ w4, __hip_bfloat16* __restrict__ WT5)
{
    const int idx = blockIdx.x * 256 + threadIdx.x;
    if (idx >= 2560) return;
    const int o = idx & 7, n = (idx >> 3) & 63, mat = idx >> 9;
    const float* W = mat == 0 ? w0 : mat == 1 ? w1 : mat == 2 ? w2 : mat == 3 ? w3 : w4;
    alignas(16) __hip_bfloat16 hb[8], lb[8];
#pragma unroll
    for (int j = 0; j < 8; ++j) {
        const float v = W[(o * 8 + j) * 64 + n];
        hilo(v, hb[j], lb[j]);
    }
    __hip_bfloat16* row = WT5 + (size_t)(mat * 64 + n) * 128;
    *(short8*)&row[((o     ) ^ (n & 15)) * 8] = *(const short8*)hb;
    *(short8*)&row[((o | 8) ^ (n & 15)) * 8] = *(const short8*)lb;
}

// ---------------------------------------------------------------------------
// Pure-bf16 MFMA GEMM (unchanged from round 9 — proven).
// ---------------------------------------------------------------------------
template<int NCT, int MODE>
__global__ __launch_bounds__(512, 2)
void mfma_gemm256(const __hip_bfloat16* __restrict__ A,
                  const __hip_bfloat16* __restrict__ BT,
                  float* __restrict__ out0, float* __restrict__ out1)
{
    __shared__ __hip_bfloat16 lds[2][2][16384];   // [buf][A/B][256 rows x 64 k]
    const int tid  = threadIdx.x;
    const int lane = tid & 63, wave = tid >> 6;
    const int wr   = wave >> 2, wc = wave & 3;     // 2 x 4 wave grid
    const int l15  = lane & 15, l4 = lane >> 4;

    const int nwg = gridDim.x;
    const int cpx = nwg >> 3;
    const int swz = (blockIdx.x & 7) * cpx + (blockIdx.x >> 3);
    const int mt = swz / NCT, nt = swz % NCT;
    const int row0 = mt * 256, col0 = nt * 256;

    const int s_c = tid & 7;
    const int s_r = (tid >> 3) & 63;

    f32x4 acc[8][4];
#pragma unroll
    for (int m = 0; m < 8; ++m)
#pragma unroll
        for (int n = 0; n < 4; ++n) acc[m][n] = (f32x4)0.f;

#define STAGE_I(I, TT, BUF)                                                    \
    {                                                                          \
        const int mat_ = (I) >> 2;                                             \
        const int row_ = ((I) & 3) * 64 + s_r;                                 \
        const __hip_bfloat16* src_ = (mat_ == 0)                               \
            ? &A [(size_t)(row0 + row_) * 1024 + ((TT) << 6) + s_c * 8]        \
            : &BT[(size_t)(col0 + row_) * 1024 + ((TT) << 6) + s_c * 8];       \
        gload_lds16(src_, &lds[BUF][mat_][row_ * 64 + s_c * 8]);               \
    }

#pragma unroll
    for (int i = 0; i < 8; ++i) STAGE_I(i, 0, 0)
    __syncthreads();

    for (int t = 0; t < 16; ++t) {
        const int cur = t & 1, nxt = cur ^ 1;
        const bool pf = (t < 15);

#pragma unroll
        for (int ks = 0; ks < 2; ++ks) {
            if (pf) {
#pragma unroll
                for (int i = ks * 4; i < ks * 4 + 4; ++i) STAGE_I(i, t + 1, nxt)
            }

            short8 af[8], bf[4];
#pragma unroll
            for (int m = 0; m < 8; ++m) {
                const int row = wr * 128 + m * 16 + l15;
                const int ch = (ks * 4 + l4) ^ (l15 & 7);
                af[m] = *(const short8*)&lds[cur][0][row * 64 + ch * 8];
            }
#pragma unroll
            for (int n = 0; n < 4; ++n) {
                const int row = wc * 64 + n * 16 + l15;
                const int ch = (ks * 4 + l4) ^ (l15 & 7);
                bf[n] = *(const short8*)&lds[cur][1][row * 64 + ch * 8];
            }

            __builtin_amdgcn_s_setprio(1);
#pragma unroll
            for (int m = 0; m < 8; ++m)
#pragma unroll
                for (int n = 0; n < 4; ++n)
                    acc[m][n] = __builtin_amdgcn_mfma_f32_16x16x32_bf16(af[m], bf[n], acc[m][n], 0, 0, 0);
            __builtin_amdgcn_s_setprio(0);
        }
        __syncthreads();
    }
#undef STAGE_I

    const int orow = l4 * 4, ocol = l15;
#pragma unroll
    for (int M = 0; M < 8; ++M)
#pragma unroll
        for (int N = 0; N < 4; ++N) {
            const int c = col0 + wc * 64 + N * 16 + ocol;
#pragma unroll
            for (int q = 0; q < 4; ++q) {
                const int r = row0 + wr * 128 + M * 16 + orow + q;
                const float v = acc[M][N][q];
                if (MODE == 0) {
                    out0[(size_t)r * (NCT * 256) + c] = v;
                } else {
                    if (c < 1024) out0[(size_t)r * 1024 + c] = v;
                    else          out1[(size_t)r * 1024 + (c - 1024)] = fsilu(v);
                }
            }
        }
}

// ---------------------------------------------------------------------------
// FUSED conv + backbone, 512 threads (8 waves), one barrier.
// Block = 8 tokens x 16 heads = 128 rows; wave owns 16-row slab (1 token).
// Phase 0: stage Wl (async) || depthwise conv+silu -> Xl (wave-private,
//          swizzled hi|lo).  Phase 1: bb = silu(X@W0+b) -> Bb (wave-private).
// Phase 2: f1,f2,tau,dec -> cand,decay packed bf16 pairs (uint).
// ---------------------------------------------------------------------------
__global__ __launch_bounds__(512, 1)
void backbone_mfma(const float* __restrict__ xpath,
                   const float* __restrict__ cw, const float* __restrict__ cb,
                   const __hip_bfloat16* __restrict__ WT5,
                   const float* __restrict__ bbb,
                   const float* __restrict__ f1b, const float* __restrict__ f2b,
                   const float* __restrict__ taub, const float* __restrict__ taub2,
                   const float* __restrict__ decb,
                   unsigned* __restrict__ cd)
{
    __shared__ __hip_bfloat16 Wl[5 * 64 * 128];   // 80 KB
    __shared__ __hip_bfloat16 Xl[128 * 128];      // 32 KB
    __shared__ __hip_bfloat16 Bb[128 * 128];      // 32 KB
    const int tid  = threadIdx.x;
    const int lane = tid & 63, wave = tid >> 6;
    const int l15  = lane & 15, l4 = lane >> 4;

    // stage all 5 weight matrices: 5120 16B-chunks over 512 threads
#pragma unroll
    for (int r = 0; r < 10; ++r) {
        const int blk = r * 8 + wave;
        gload_lds16(WT5 + blk * 512 + lane * 8, Wl + blk * 512);
    }

    // fused depthwise conv (K=4) + bias + silu -> Xl (wave-private slab)
    {
        const int bt = blockIdx.x * 8 + wave;     // global token
        const int t  = bt & (SN - 1);
#pragma unroll
        for (int gg = 0; gg < 2; ++gg) {
            const int g  = lane + gg * 64;        // octet 0..127
            const int c0 = g * 8;
            float acc[8];
#pragma unroll
            for (int j = 0; j < 8; ++j) acc[j] = cb[c0 + j];
            float4 cwv[8];
#pragma unroll
            for (int j = 0; j < 8; ++j) cwv[j] = *(const float4*)&cw[(c0 + j) * 4];
            const float* cwf = (const float*)cwv;
#pragma unroll
            for (int k = 0; k < 4; ++k) {
                if (t - 3 + k >= 0) {
                    const float* xr = xpath + (((size_t)(bt - 3 + k)) << 10) + c0;
                    const float4 u0 = *(const float4*)&xr[0];
                    const float4 u1 = *(const float4*)&xr[4];
                    const float u[8] = {u0.x, u0.y, u0.z, u0.w, u1.x, u1.y, u1.z, u1.w};
#pragma unroll
                    for (int j = 0; j < 8; ++j) acc[j] += cwf[j * 4 + k] * u[j];
                }
            }
            alignas(16) __hip_bfloat16 hb[8], lb[8];
#pragma unroll
            for (int j = 0; j < 8; ++j) hilo(fsilu(acc[j]), hb[j], lb[j]);
            const int head = c0 >> 6;
            const int o    = (c0 >> 3) & 7;
            __hip_bfloat16* row = Xl + (wave * 16 + head) * 128;
            *(short8*)&row[((o     ) ^ head) * 8] = *(const short8*)hb;
            *(short8*)&row[((o | 8) ^ head) * 8] = *(const short8*)lb;
        }
    }
    __syncthreads();   // Wl staged (vmcnt drained) + all Xl writes visible

    // ---- stage 1: bb = silu(X @ W0 + bbb) -> Bb (wave-private slab) ----
    short8 xa[2][2];
#pragma unroll
    for (int s = 0; s < 2; ++s)
#pragma unroll
        for (int p = 0; p < 2; ++p) {
            const int ch = ((s * 4 + l4) | (p << 3)) ^ l15;
            xa[s][p] = *(const short8*)&Xl[(wave * 16 + l15) * 128 + ch * 8];
        }

#pragma unroll
    for (int nt = 0; nt < 4; ++nt) {
        short8 wb[2][2];
#pragma unroll
        for (int s = 0; s < 2; ++s)
#pragma unroll
            for (int p = 0; p < 2; ++p) {
                const int ch = ((s * 4 + l4) | (p << 3)) ^ l15;
                wb[s][p] = *(const short8*)&Wl[(nt * 16 + l15) * 128 + ch * 8];
            }
        f32x4 ac = (f32x4)0.f;
        __builtin_amdgcn_s_setprio(1);
#pragma unroll
        for (int s = 0; s < 2; ++s) {
            ac = __builtin_amdgcn_mfma_f32_16x16x32_bf16(xa[s][0], wb[s][0], ac, 0, 0, 0);
            ac = __builtin_amdgcn_mfma_f32_16x16x32_bf16(xa[s][0], wb[s][1], ac, 0, 0, 0);
            ac = __builtin_amdgcn_mfma_f32_16x16x32_bf16(xa[s][1], wb[s][0], ac, 0, 0, 0);
        }
        __builtin_amdgcn_s_setprio(0);
        const int col = nt * 16 + l15;
        const float bc = bbb[col];
#pragma unroll
        for (int q = 0; q < 4; ++q) {
            const int r15 = l4 * 4 + q;
            const float v = fsilu(ac[q] + bc);
            __hip_bfloat16 h, l;
            hilo(v, h, l);
            Bb[(wave * 16 + r15) * 128 + (((col >> 3)     ) ^ r15) * 8 + (col & 7)] = h;
            Bb[(wave * 16 + r15) * 128 + (((col >> 3) | 8) ^ r15) * 8 + (col & 7)] = l;
        }
    }
    // no barrier: Bb slab is written and read by the same wave

    // ---- stage 2: f1,f2,tau,dec = bb @ W[1..4] ----
    short8 ba[2][2];
#pragma unroll
    for (int s = 0; s < 2; ++s)
#pragma unroll
        for (int p = 0; p < 2; ++p) {
            const int ch = ((s * 4 + l4) | (p << 3)) ^ l15;
            ba[s][p] = *(const short8*)&Bb[(wave * 16 + l15) * 128 + ch * 8];
        }

#pragma unroll
    for (int nt = 0; nt < 4; ++nt) {
        f32x4 a2[4];
#pragma unroll
        for (int m = 0; m < 4; ++m) a2[m] = (f32x4)0.f;

#pragma unroll
        for (int mat = 0; mat < 4; ++mat) {
            short8 w2[2][2];
#pragma unroll
            for (int s = 0; s < 2; ++s)
#pragma unroll
                for (int p = 0; p < 2; ++p) {
                    const int ch = ((s * 4 + l4) | (p << 3)) ^ l15;
                    w2[s][p] = *(const short8*)&Wl[((mat + 1) * 64 + nt * 16 + l15) * 128 + ch * 8];
                }
            __builtin_amdgcn_s_setprio(1);
#pragma unroll
            for (int s = 0; s < 2; ++s) {
                a2[mat] = __builtin_amdgcn_mfma_f32_16x16x32_bf16(ba[s][0], w2[s][0], a2[mat], 0, 0, 0);
                a2[mat] = __builtin_amdgcn_mfma_f32_16x16x32_bf16(ba[s][0], w2[s][1], a2[mat], 0, 0, 0);
                a2[mat] = __builtin_amdgcn_mfma_f32_16x16x32_bf16(ba[s][1], w2[s][0], a2[mat], 0, 0, 0);
            }
            __builtin_amdgcn_s_setprio(0);
        }

        const int col = nt * 16 + l15;
        const float b1 = f1b[col], b2 = f2b[col];
        const float b3 = taub[col] + taub2[col], b4 = decb[col];
        const size_t Rbase = (size_t)blockIdx.x * 128 + wave * 16;
#pragma unroll
        for (int q = 0; q < 4; ++q) {
            const size_t R = Rbase + l4 * 4 + q;
            const float f1v = ftanh(a2[0][q] + b1);
            const float f2v = ftanh(a2[1][q] + b2);
            const float tv  = fsig (a2[2][q] + b3);
            const float dv  = fsig (a2[3][q] + b4);
            cd[R * 64 + col] = pack_cd(f1v * (1.f - tv) + f2v * tv, dv);
        }
    }
}

// ---------------------------------------------------------------------------
// Chunked scan passes 1+2 (packed cd input).
// ---------------------------------------------------------------------------
__global__ __launch_bounds__(256)
void scan_compose(const unsigned* __restrict__ cd,
                  float* __restrict__ Ach, float* __restrict__ Bch)
{
    const int idx = blockIdx.x * 256 + threadIdx.x;
    const int p  = idx & 1023;
    const int rest = idx >> 10;
    const int ch = rest & 63, b = rest >> 6;
    float A = 1.f, Bv = 0.f;
    const size_t base = ((size_t)(b * SN + ch * 32) << 10) + p;
    for (int t = 0; t < 32; ++t) {
        const unsigned u = cd[base + ((size_t)t << 10)];
        const float c = __uint_as_float(u << 16);
        const float d = __uint_as_float(u & 0xffff0000u);
        A  *= d;
        Bv  = d * Bv + (1.f - d) * c;
    }
    Ach[(ch << 13) + (b << 10) + p] = A;
    Bch[(ch << 13) + (b << 10) + p] = Bv;
}

__global__ __launch_bounds__(256)
void scan_chunks(const float* __restrict__ Ach, const float* __restrict__ Bch,
                 float* __restrict__ hstart)
{
    const int q = blockIdx.x * 256 + threadIdx.x;
    float h = 0.f;
    for (int ch = 0; ch < 64; ++ch) {
        hstart[(ch << 13) + q] = h;
        h = Ach[(ch << 13) + q] * h + Bch[(ch << 13) + q];
    }
}

// ---------------------------------------------------------------------------
// scan_apply: final h per timestep as swizzled bf16 hi|lo rows (no aliasing:
// Hhl lives in a dead region).
// ---------------------------------------------------------------------------
__global__ __launch_bounds__(256)
void scan_apply(const unsigned* __restrict__ cd,
                const float* __restrict__ hstart, __hip_bfloat16* __restrict__ Hhl)
{
    const int idx = blockIdx.x * 256 + threadIdx.x;
    const int p  = idx & 1023;
    const int rest = idx >> 10;
    const int ch = rest & 63, b = rest >> 6;
    const int nh = p >> 6, ns = p & 63;
    const int hoff = (((ns >> 3)    ) ^ nh) * 8 + (ns & 7);
    const int loff = (((ns >> 3) | 8) ^ nh) * 8 + (ns & 7);
    float h = hstart[(ch << 13) + (b << 10) + p];
    const int t0 = b * SN + ch * 32;
    const size_t base = ((size_t)t0 << 10) + p;
    for (int t = 0; t < 32; ++t) {
        const unsigned u = cd[base + ((size_t)t << 10)];
        const float c = __uint_as_float(u << 16);
        const float d = __uint_as_float(u & 0xffff0000u);
        h = d * h + (1.f - d) * c;
        __hip_bfloat16 hb, lb;
        hilo(h, hb, lb);
        const size_t row = ((size_t)(t0 + t) * 16 + nh) * 128;
        Hhl[row + hoff] = hb;
        Hhl[row + loff] = lb;
    }
}

// ---------------------------------------------------------------------------
// MFMA state_out: out = H @ sow + sob, gated by silu(z); emits PURE bf16
// rows for the bf16 out_proj GEMM, pre-swizzled (chunk ^= row&7).
// ---------------------------------------------------------------------------
__global__ __launch_bounds__(256)
void stateout_mfma(const __hip_bfloat16* __restrict__ Hhl,
                   const float* __restrict__ sow, const float* __restrict__ sob,
                   const float* __restrict__ zs, __hip_bfloat16* __restrict__ gA)
{
    __shared__ __hip_bfloat16 Wl[64 * 128];   // 16 KB
    __shared__ __hip_bfloat16 Hl[128 * 128];  // 32 KB
    const int tid  = threadIdx.x;
    const int lane = tid & 63, wave = tid >> 6;
    const int l15  = lane & 15, l4 = lane >> 4;

    {
        const int n = tid & 63;
        const int ob = (tid >> 6) * 2;
#pragma unroll
        for (int oo = 0; oo < 2; ++oo) {
            const int o = ob + oo;
#pragma unroll
            for (int j = 0; j < 8; ++j) {
                const float v = sow[(o * 8 + j) * 64 + n];
                __hip_bfloat16 hb, lb;
                hilo(v, hb, lb);
                Wl[n * 128 + ((o       ^ (n & 15)) * 8 + j)] = hb;
                Wl[n * 128 + (((o | 8) ^ (n & 15)) * 8 + j)] = lb;
            }
        }
    }
    const __hip_bfloat16* hsrc = Hhl + (size_t)blockIdx.x * 16384;
#pragma unroll
    for (int r = 0; r < 8; ++r) {
        const int blk = r * 4 + wave;
        gload_lds16(hsrc + blk * 512 + lane * 8, Hl + blk * 512);
    }
    __syncthreads();

    short8 ha[2][2][2];
#pragma unroll
    for (int mt2 = 0; mt2 < 2; ++mt2)
#pragma unroll
        for (int s = 0; s < 2; ++s)
#pragma unroll
            for (int p = 0; p < 2; ++p) {
                const int ch = ((s * 4 + l4) | (p << 3)) ^ l15;
                ha[mt2][s][p] = *(const short8*)&Hl[(wave * 32 + mt2 * 16 + l15) * 128 + ch * 8];
            }

#pragma unroll
    for (int nt = 0; nt < 4; ++nt) {
        short8 wb[2][2];
#pragma unroll
        for (int s = 0; s < 2; ++s)
#pragma unroll
            for (int p = 0; p < 2; ++p) {
                const int ch = ((s * 4 + l4) | (p << 3)) ^ l15;
                wb[s][p] = *(const short8*)&Wl[(nt * 16 + l15) * 128 + ch * 8];
            }
        f32x4 ac[2] = {(f32x4)0.f, (f32x4)0.f};
#pragma unroll
        for (int mt2 = 0; mt2 < 2; ++mt2)
#pragma unroll
            for (int s = 0; s < 2; ++s) {
                ac[mt2] = __builtin_amdgcn_mfma_f32_16x16x32_bf16(ha[mt2][s][0], wb[s][0], ac[mt2], 0, 0, 0);
                ac[mt2] = __builtin_amdgcn_mfma_f32_16x16x32_bf16(ha[mt2][s][0], wb[s][1], ac[mt2], 0, 0, 0);
                ac[mt2] = __builtin_amdgcn_mfma_f32_16x16x32_bf16(ha[mt2][s][1], wb[s][0], ac[mt2], 0, 0, 0);
            }
        const int col = nt * 16 + l15;
        const float bj = sob[col];
#pragma unroll
        for (int mt2 = 0; mt2 < 2; ++mt2)
#pragma unroll
            for (int q = 0; q < 4; ++q) {
                const size_t th = (size_t)blockIdx.x * 128 + wave * 32 + mt2 * 16 + l4 * 4 + q;
                const float v = (ac[mt2][q] + bj) * zs[th * 64 + col];
                const size_t token = th >> 4;
                const int colg = (int)(th & 15) * 64 + col;   // 0..1023
                const int cg = colg >> 3, jg = colg & 7;      // octet, elem
                const int cs = (cg & 120) | ((cg & 7) ^ ((int)(token & 7)));
                gA[token * 1024 + cs * 8 + jg] = __float2bfloat16(v);
            }
    }
}

// ---------------------------------------------------------------------------
extern "C" void kernel_launch(void* const* d_in, const int* in_sizes, int n_in,
                              void* d_out, int out_size, void* d_ws, size_t ws_size,
                              hipStream_t stream)
{
    const float* x     = (const float*)d_in[0];
    const float* ipw   = (const float*)d_in[1];
    const float* cw    = (const float*)d_in[2];
    const float* cb    = (const float*)d_in[3];
    const float* bbw   = (const float*)d_in[4];
    const float* bbb   = (const float*)d_in[5];
    const float* f1w   = (const float*)d_in[6];
    const float* f1b   = (const float*)d_in[7];
    const float* f2w   = (const float*)d_in[8];
    const float* f2b   = (const float*)d_in[9];
    const float* tauw  = (const float*)d_in[10];
    const float* taub  = (const float*)d_in[11];
    const float* taub2 = (const float*)d_in[12];
    const float* decw  = (const float*)d_in[13];
    const float* decb  = (const float*)d_in[14];
    const float* sow   = (const float*)d_in[15];
    const float* sob   = (const float*)d_in[16];
    const float* opw   = (const float*)d_in[17];

    float* out = (float*)d_out;
    char*  ws  = (char*)d_ws;
    const size_t MB = 1024 * 1024;

    // Workspace map (198 MiB), no aliasing hazards:
    //  @0Mi   (64Mi): Abf (bf16 32Mi, dead after GEMM-in) -> Hhl (bf16 64Mi)
    //  @64Mi  (64Mi): xpath (f32 64Mi, dead after backbone) -> gA (bf16 32Mi)
    //  @128Mi (64Mi): BTin (2Mi, dead after GEMM-in) -> cd (packed uint 64Mi)
    //  @192Mi (6Mi) : WT5 (80KB, dead after backbone) -> Ach|Bch|hst;
    //                 BTout (2Mi) overwrites Ach after scan_chunks (hst @+4Mi safe)
    __hip_bfloat16* Abf   = (__hip_bfloat16*)(ws);
    float*          xpath = (float*)(ws + 64 * MB);
    __hip_bfloat16* BTin  = (__hip_bfloat16*)(ws + 128 * MB);
    unsigned*       cd    = (unsigned*)(ws + 128 * MB);
    __hip_bfloat16* WT5   = (__hip_bfloat16*)(ws + 192 * MB);
    float*          Ach   = (float*)(ws + 192 * MB);
    float*          Bch   = Ach + 524288;
    float*          hst   = Bch + 524288;
    __hip_bfloat16* BTout = (__hip_bfloat16*)(ws + 192 * MB);
    __hip_bfloat16* Hhl   = (__hip_bfloat16*)(ws);
    __hip_bfloat16* gA    = (__hip_bfloat16*)(ws + 64 * MB);
    float*          zsilu = out;   // d_out as scratch until final GEMM

    // 1) conversions (pure bf16 for GEMM operands)
    x_to_a_bf<<<8192, 256, 0, stream>>>(x, Abf);
    w_to_bt_bf<<<dim3(16, 32), 256, 0, stream>>>(ipw, BTin, 2048);
    w5_to_wt<<<10, 256, 0, stream>>>(bbw, f1w, f2w, tauw, decw, WT5);
    // 2) in_proj GEMM (pure bf16 MFMA) + silu(z)
    mfma_gemm256<8, 1><<<512, 512, 0, stream>>>(Abf, BTin, xpath, zsilu);
    // 3) fused conv + backbone -> packed cand|decay
    backbone_mfma<<<2048, 512, 0, stream>>>(xpath, cw, cb, WT5, bbb, f1b, f2b,
                                            taub, taub2, decb, cd);
    // 4) chunked scan -> Hhl (bf16 hi|lo)
    scan_compose<<<2048, 256, 0, stream>>>(cd, Ach, Bch);
    scan_chunks<<<32, 256, 0, stream>>>(Ach, Bch, hst);
    scan_apply<<<2048, 256, 0, stream>>>(cd, hst, Hhl);
    // 5) out_proj weight conversion (Ach/Bch dead; hst untouched)
    w_to_bt_bf<<<dim3(16, 16), 256, 0, stream>>>(opw, BTout, 1024);
    // 6) state_out + gate (MFMA) -> pure bf16 gA
    stateout_mfma<<<2048, 256, 0, stream>>>(Hhl, sow, sob, zsilu, gA);
    // 7) out_proj GEMM (pure bf16)
    mfma_gemm256<4, 0><<<256, 512, 0, stream>>>(gA, BTout, out, nullptr);
}

// Round 12
// 320.840 us; speedup vs baseline: 1.9766x; 1.1182x over previous
//
#include <hip/hip_runtime.h>
#include <hip/hip_bf16.h>
#include <math.h>

// Problem constants
#define BN   8
#define SN   2048
#define HN   1024
#define NTOK 16384   // B*S
#define NHD  16
#define HDD  64
#define NSD  64

typedef __attribute__((ext_vector_type(8))) short short8;
typedef __attribute__((ext_vector_type(4))) float f32x4;

__device__ __forceinline__ float fsig(float x)  { return 1.f / (1.f + __expf(-x)); }
__device__ __forceinline__ float fsilu(float x) { return x / (1.f + __expf(-x)); }
__device__ __forceinline__ float ftanh(float x) {
    const float t = __expf(-2.f * fabsf(x));
    const float r = (1.f - t) / (1.f + t);
    return x >= 0.f ? r : -r;
}
__device__ __forceinline__ unsigned pack_cd(float cand, float dec) {
    __hip_bfloat16 cb_ = __float2bfloat16(cand);
    __hip_bfloat16 db_ = __float2bfloat16(dec);
    return (unsigned)*(unsigned short*)&cb_ | ((unsigned)*(unsigned short*)&db_ << 16);
}
__device__ __forceinline__ void gload_lds16(const void* g, void* l) {
    __builtin_amdgcn_global_load_lds(
        (const __attribute__((address_space(1))) unsigned int*)g,
        (__attribute__((address_space(3))) unsigned int*)l, 16, 0, 0);
}

// ---------------------------------------------------------------------------
// x (16384x1024 f32) -> A (16384x1024 bf16), pre-swizzled rows for the GEMM:
// logical octet c of row r stored at chunk (c&120)|((c&7)^(r&7)).
// ---------------------------------------------------------------------------
__global__ __launch_bounds__(256)
void x_to_a_bf(const float* __restrict__ X, __hip_bfloat16* __restrict__ A)
{
    const int idx = blockIdx.x * 256 + threadIdx.x;   // 2M octets
    const int r = idx >> 7;
    const int c = idx & 127;                          // logical octet
    const float* src = &X[(size_t)r * 1024 + c * 8];
    alignas(16) __hip_bfloat16 b[8];
#pragma unroll
    for (int j = 0; j < 8; ++j) b[j] = __float2bfloat16(src[j]);
    const int cs = (c & 120) | ((c & 7) ^ (r & 7));   // swizzle within 8-chunk group
    *(short8*)&A[(size_t)r * 1024 + cs * 8] = *(const short8*)b;
}

// ---------------------------------------------------------------------------
// W (1024 x N f32, (in,out)) -> BT (N x 1024 bf16), same pre-swizzle.
// ---------------------------------------------------------------------------
__global__ __launch_bounds__(256)
void w_to_bt_bf(const float* __restrict__ W, __hip_bfloat16* __restrict__ BT, int N)
{
    __shared__ float t[64][65];
    const int k0 = blockIdx.x * 64;
    const int n0 = blockIdx.y * 64;
    const int c  = threadIdx.x & 63, r4 = threadIdx.x >> 6;
#pragma unroll
    for (int rr = 0; rr < 64; rr += 4)
        t[rr + r4][c] = W[(size_t)(k0 + rr + r4) * N + n0 + c];
    __syncthreads();
#pragma unroll
    for (int oo = 0; oo < 2; ++oo) {
        const int o = r4 * 2 + oo;                 // octet within 64-k tile
        alignas(16) __hip_bfloat16 b[8];
#pragma unroll
        for (int j = 0; j < 8; ++j)
            b[j] = __float2bfloat16(t[o * 8 + j][c]);
        const int n = n0 + c;
        const int cglob = (k0 >> 3) + o;           // global octet index
        const int cs = (cglob & 120) | ((cglob & 7) ^ (n & 7));
        *(short8*)&BT[(size_t)n * 1024 + cs * 8] = *(const short8*)b;
    }
}

// ---------------------------------------------------------------------------
// 5 backbone weight mats (64x64 f32, (k,n)) -> WT5[mat][n][8 octets x 8 bf16]
// pure bf16, octet o stored at (o ^ (n&7)).
// ---------------------------------------------------------------------------
__global__ __launch_bounds__(256)
void w5_to_wt(const float* __restrict__ w0, const float* __restrict__ w1,
              const float* __restrict__ w2, const float* __restrict__ w3,
              const float* __restrict__ w4, __hip_bfloat16* __restrict__ WT5)
{
    const int idx = blockIdx.x * 256 + threadIdx.x;
    if (idx >= 2560) return;
    const int o = idx & 7, n = (idx >> 3) & 63, mat = idx >> 9;
    const float* W = mat == 0 ? w0 : mat == 1 ? w1 : mat == 2 ? w2 : mat == 3 ? w3 : w4;
    alignas(16) __hip_bfloat16 b[8];
#pragma unroll
    for (int j = 0; j < 8; ++j)
        b[j] = __float2bfloat16(W[(o * 8 + j) * 64 + n]);
    *(short8*)&WT5[(size_t)(mat * 64 + n) * 64 + ((o ^ (n & 7)) * 8)] = *(const short8*)b;
}

// ---------------------------------------------------------------------------
// Pure-bf16 MFMA GEMM (unchanged — proven at 422µs round).
// ---------------------------------------------------------------------------
template<int NCT, int MODE>
__global__ __launch_bounds__(512, 2)
void mfma_gemm256(const __hip_bfloat16* __restrict__ A,
                  const __hip_bfloat16* __restrict__ BT,
                  float* __restrict__ out0, float* __restrict__ out1)
{
    __shared__ __hip_bfloat16 lds[2][2][16384];   // [buf][A/B][256 rows x 64 k]
    const int tid  = threadIdx.x;
    const int lane = tid & 63, wave = tid >> 6;
    const int wr   = wave >> 2, wc = wave & 3;     // 2 x 4 wave grid
    const int l15  = lane & 15, l4 = lane >> 4;

    const int nwg = gridDim.x;
    const int cpx = nwg >> 3;
    const int swz = (blockIdx.x & 7) * cpx + (blockIdx.x >> 3);
    const int mt = swz / NCT, nt = swz % NCT;
    const int row0 = mt * 256, col0 = nt * 256;

    const int s_c = tid & 7;
    const int s_r = (tid >> 3) & 63;

    f32x4 acc[8][4];
#pragma unroll
    for (int m = 0; m < 8; ++m)
#pragma unroll
        for (int n = 0; n < 4; ++n) acc[m][n] = (f32x4)0.f;

#define STAGE_I(I, TT, BUF)                                                    \
    {                                                                          \
        const int mat_ = (I) >> 2;                                             \
        const int row_ = ((I) & 3) * 64 + s_r;                                 \
        const __hip_bfloat16* src_ = (mat_ == 0)                               \
            ? &A [(size_t)(row0 + row_) * 1024 + ((TT) << 6) + s_c * 8]        \
            : &BT[(size_t)(col0 + row_) * 1024 + ((TT) << 6) + s_c * 8];       \
        gload_lds16(src_, &lds[BUF][mat_][row_ * 64 + s_c * 8]);               \
    }

#pragma unroll
    for (int i = 0; i < 8; ++i) STAGE_I(i, 0, 0)
    __syncthreads();

    for (int t = 0; t < 16; ++t) {
        const int cur = t & 1, nxt = cur ^ 1;
        const bool pf = (t < 15);

#pragma unroll
        for (int ks = 0; ks < 2; ++ks) {
            if (pf) {
#pragma unroll
                for (int i = ks * 4; i < ks * 4 + 4; ++i) STAGE_I(i, t + 1, nxt)
            }

            short8 af[8], bf[4];
#pragma unroll
            for (int m = 0; m < 8; ++m) {
                const int row = wr * 128 + m * 16 + l15;
                const int ch = (ks * 4 + l4) ^ (l15 & 7);
                af[m] = *(const short8*)&lds[cur][0][row * 64 + ch * 8];
            }
#pragma unroll
            for (int n = 0; n < 4; ++n) {
                const int row = wc * 64 + n * 16 + l15;
                const int ch = (ks * 4 + l4) ^ (l15 & 7);
                bf[n] = *(const short8*)&lds[cur][1][row * 64 + ch * 8];
            }

            __builtin_amdgcn_s_setprio(1);
#pragma unroll
            for (int m = 0; m < 8; ++m)
#pragma unroll
                for (int n = 0; n < 4; ++n)
                    acc[m][n] = __builtin_amdgcn_mfma_f32_16x16x32_bf16(af[m], bf[n], acc[m][n], 0, 0, 0);
            __builtin_amdgcn_s_setprio(0);
        }
        __syncthreads();
    }
#undef STAGE_I

    const int orow = l4 * 4, ocol = l15;
#pragma unroll
    for (int M = 0; M < 8; ++M)
#pragma unroll
        for (int N = 0; N < 4; ++N) {
            const int c = col0 + wc * 64 + N * 16 + ocol;
#pragma unroll
            for (int q = 0; q < 4; ++q) {
                const int r = row0 + wr * 128 + M * 16 + orow + q;
                const float v = acc[M][N][q];
                if (MODE == 0) {
                    out0[(size_t)r * (NCT * 256) + c] = v;
                } else {
                    if (c < 1024) out0[(size_t)r * 1024 + c] = v;
                    else          out1[(size_t)r * 1024 + (c - 1024)] = fsilu(v);
                }
            }
        }
}

// ---------------------------------------------------------------------------
// Depthwise causal conv (K=4) + bias + silu -> Xbf: pure bf16 rows of 64
// (token-head), octet o stored at (o ^ (head&7)).  Streaming, high occupancy.
// ---------------------------------------------------------------------------
__global__ __launch_bounds__(256)
void conv_silu_bf(const float* __restrict__ xp, const float* __restrict__ cw,
                  const float* __restrict__ cb, __hip_bfloat16* __restrict__ Xbf)
{
    const int idx = blockIdx.x * 256 + threadIdx.x;   // NTOK*128 octets
    const int g  = idx & 127;
    const int bt = idx >> 7;
    const int t  = bt & (SN - 1);
    const int c0 = g * 8;

    float acc[8];
#pragma unroll
    for (int j = 0; j < 8; ++j) acc[j] = cb[c0 + j];
    float4 cwv[8];
#pragma unroll
    for (int j = 0; j < 8; ++j) cwv[j] = *(const float4*)&cw[(c0 + j) * 4];
    const float* cwf = (const float*)cwv;

#pragma unroll
    for (int k = 0; k < 4; ++k) {
        if (t - 3 + k >= 0) {
            const float* xr = xp + (((size_t)(bt - 3 + k)) << 10) + c0;
            const float4 u0 = *(const float4*)&xr[0];
            const float4 u1 = *(const float4*)&xr[4];
            const float u[8] = {u0.x, u0.y, u0.z, u0.w, u1.x, u1.y, u1.z, u1.w};
#pragma unroll
            for (int j = 0; j < 8; ++j) acc[j] += cwf[j * 4 + k] * u[j];
        }
    }

    alignas(16) __hip_bfloat16 b[8];
#pragma unroll
    for (int j = 0; j < 8; ++j) b[j] = __float2bfloat16(fsilu(acc[j]));

    const int head = g >> 3;      // 0..15
    const int o    = g & 7;
    const size_t row = (size_t)bt * 16 + head;
    *(short8*)&Xbf[row * 64 + ((o ^ (head & 7)) * 8)] = *(const short8*)b;
}

// ---------------------------------------------------------------------------
// Pure-bf16 backbone, 512 threads (8 waves), 56 KB LDS -> 2 blocks/CU.
// Wave = 1 token (16 head-rows).  X A-frags direct from global (coalesced).
// Stage 1: bb = silu(X@W0+b) -> Bb (wave-private).  Stage 2: 4 matmuls ->
// nonlinearities -> packed bf16 cand|decay.
// ---------------------------------------------------------------------------
__global__ __launch_bounds__(512, 4)
void backbone_mfma(const __hip_bfloat16* __restrict__ Xbf,
                   const __hip_bfloat16* __restrict__ WT5,
                   const float* __restrict__ bbb,
                   const float* __restrict__ f1b, const float* __restrict__ f2b,
                   const float* __restrict__ taub, const float* __restrict__ taub2,
                   const float* __restrict__ decb,
                   unsigned* __restrict__ cd)
{
    __shared__ __hip_bfloat16 Wl[5 * 64 * 64];   // 40 KB
    __shared__ __hip_bfloat16 Bb[128 * 64];      // 16 KB
    const int tid  = threadIdx.x;
    const int lane = tid & 63, wave = tid >> 6;
    const int l15  = lane & 15, l4 = lane >> 4;
    const int e7   = l15 & 7;

    // stage all 5 weight matrices: 2560 16B-chunks over 512 threads
#pragma unroll
    for (int r = 0; r < 5; ++r) {
        const int blk = r * 8 + wave;
        gload_lds16(WT5 + blk * 512 + lane * 8, Wl + blk * 512);
    }

    // X A-frags direct from global: wave's token = 16 rows x 64 (2 KB)
    const __hip_bfloat16* xrow = Xbf + ((size_t)(blockIdx.x * 8 + wave) * 16) * 64;
    short8 xa[2];
#pragma unroll
    for (int s = 0; s < 2; ++s)
        xa[s] = *(const short8*)&xrow[l15 * 64 + (((s * 4 + l4) ^ e7) * 8)];

    __syncthreads();   // Wl staged (vmcnt drained)

    // ---- stage 1: bb = silu(X @ W0 + bbb) -> Bb (wave-private rows) ----
#pragma unroll
    for (int nt = 0; nt < 4; ++nt) {
        short8 wb[2];
#pragma unroll
        for (int s = 0; s < 2; ++s)
            wb[s] = *(const short8*)&Wl[(nt * 16 + l15) * 64 + (((s * 4 + l4) ^ e7) * 8)];
        f32x4 ac = (f32x4)0.f;
        ac = __builtin_amdgcn_mfma_f32_16x16x32_bf16(xa[0], wb[0], ac, 0, 0, 0);
        ac = __builtin_amdgcn_mfma_f32_16x16x32_bf16(xa[1], wb[1], ac, 0, 0, 0);
        const int col = nt * 16 + l15;
        const float bc = bbb[col];
#pragma unroll
        for (int q = 0; q < 4; ++q) {
            const int r15 = l4 * 4 + q;
            Bb[(wave * 16 + r15) * 64 + ((col >> 3) ^ (r15 & 7)) * 8 + (col & 7)] =
                __float2bfloat16(fsilu(ac[q] + bc));
        }
    }
    // wave-private slab: LDS ops from one wave execute in order, no barrier

    // ---- stage 2: f1,f2,tau,dec = bb @ W[1..4] ----
    short8 ba[2];
#pragma unroll
    for (int s = 0; s < 2; ++s)
        ba[s] = *(const short8*)&Bb[(wave * 16 + l15) * 64 + (((s * 4 + l4) ^ e7) * 8)];

#pragma unroll
    for (int nt = 0; nt < 4; ++nt) {
        f32x4 a2[4];
#pragma unroll
        for (int m = 0; m < 4; ++m) a2[m] = (f32x4)0.f;

#pragma unroll
        for (int mat = 0; mat < 4; ++mat) {
            short8 w2[2];
#pragma unroll
            for (int s = 0; s < 2; ++s)
                w2[s] = *(const short8*)&Wl[((mat + 1) * 64 + nt * 16 + l15) * 64 + (((s * 4 + l4) ^ e7) * 8)];
            a2[mat] = __builtin_amdgcn_mfma_f32_16x16x32_bf16(ba[0], w2[0], a2[mat], 0, 0, 0);
            a2[mat] = __builtin_amdgcn_mfma_f32_16x16x32_bf16(ba[1], w2[1], a2[mat], 0, 0, 0);
        }

        const int col = nt * 16 + l15;
        const float b1 = f1b[col], b2 = f2b[col];
        const float b3 = taub[col] + taub2[col], b4 = decb[col];
        const size_t Rbase = (size_t)blockIdx.x * 128 + wave * 16;
#pragma unroll
        for (int q = 0; q < 4; ++q) {
            const size_t R = Rbase + l4 * 4 + q;
            const float f1v = ftanh(a2[0][q] + b1);
            const float f2v = ftanh(a2[1][q] + b2);
            const float tv  = fsig (a2[2][q] + b3);
            const float dv  = fsig (a2[3][q] + b4);
            cd[R * 64 + col] = pack_cd(f1v * (1.f - tv) + f2v * tv, dv);
        }
    }
}

// ---------------------------------------------------------------------------
// Chunked scan passes 1+2 (packed cd input).
// ---------------------------------------------------------------------------
__global__ __launch_bounds__(256)
void scan_compose(const unsigned* __restrict__ cd,
                  float* __restrict__ Ach, float* __restrict__ Bch)
{
    const int idx = blockIdx.x * 256 + threadIdx.x;
    const int p  = idx & 1023;
    const int rest = idx >> 10;
    const int ch = rest & 63, b = rest >> 6;
    float A = 1.f, Bv = 0.f;
    const size_t base = ((size_t)(b * SN + ch * 32) << 10) + p;
    for (int t = 0; t < 32; ++t) {
        const unsigned u = cd[base + ((size_t)t << 10)];
        const float c = __uint_as_float(u << 16);
        const float d = __uint_as_float(u & 0xffff0000u);
        A  *= d;
        Bv  = d * Bv + (1.f - d) * c;
    }
    Ach[(ch << 13) + (b << 10) + p] = A;
    Bch[(ch << 13) + (b << 10) + p] = Bv;
}

__global__ __launch_bounds__(256)
void scan_chunks(const float* __restrict__ Ach, const float* __restrict__ Bch,
                 float* __restrict__ hstart)
{
    const int q = blockIdx.x * 256 + threadIdx.x;
    float h = 0.f;
    for (int ch = 0; ch < 64; ++ch) {
        hstart[(ch << 13) + q] = h;
        h = Ach[(ch << 13) + q] * h + Bch[(ch << 13) + q];
    }
}

// ---------------------------------------------------------------------------
// scan_apply: final h per timestep as PURE bf16 swizzled rows (Xbf format).
// ---------------------------------------------------------------------------
__global__ __launch_bounds__(256)
void scan_apply(const unsigned* __restrict__ cd,
                const float* __restrict__ hstart, __hip_bfloat16* __restrict__ Hhl)
{
    const int idx = blockIdx.x * 256 + threadIdx.x;
    const int p  = idx & 1023;
    const int rest = idx >> 10;
    const int ch = rest & 63, b = rest >> 6;
    const int nh = p >> 6, ns = p & 63;
    const int hpos = ((ns >> 3) ^ (nh & 7)) * 8 + (ns & 7);
    float h = hstart[(ch << 13) + (b << 10) + p];
    const int t0 = b * SN + ch * 32;
    const size_t base = ((size_t)t0 << 10) + p;
    for (int t = 0; t < 32; ++t) {
        const unsigned u = cd[base + ((size_t)t << 10)];
        const float c = __uint_as_float(u << 16);
        const float d = __uint_as_float(u & 0xffff0000u);
        h = d * h + (1.f - d) * c;
        Hhl[((size_t)(t0 + t) * 16 + nh) * 64 + hpos] = __float2bfloat16(h);
    }
}

// ---------------------------------------------------------------------------
// Pure-bf16 MFMA state_out: out = H @ sow + sob, gated by silu(z); emits
// pure bf16 gA rows for out_proj (chunk ^= token&7).  LDS 24 KB.
// ---------------------------------------------------------------------------
__global__ __launch_bounds__(256, 4)
void stateout_mfma(const __hip_bfloat16* __restrict__ Hhl,
                   const float* __restrict__ sow, const float* __restrict__ sob,
                   const float* __restrict__ zs, __hip_bfloat16* __restrict__ gA)
{
    __shared__ __hip_bfloat16 Wl[64 * 64];    // 8 KB
    __shared__ __hip_bfloat16 Hl[128 * 64];   // 16 KB
    const int tid  = threadIdx.x;
    const int lane = tid & 63, wave = tid >> 6;
    const int l15  = lane & 15, l4 = lane >> 4;
    const int e7   = l15 & 7;

    // convert sow (64x64 f32, (k,n)) -> Wl pure bf16, octet o at o^(n&7)
    {
        const int n = tid & 63;
        const int o0 = tid >> 6;   // 0..3
#pragma unroll
        for (int oo = 0; oo < 2; ++oo) {
            const int o = o0 + oo * 4;
            alignas(16) __hip_bfloat16 b[8];
#pragma unroll
            for (int j = 0; j < 8; ++j)
                b[j] = __float2bfloat16(sow[(o * 8 + j) * 64 + n]);
            *(short8*)&Wl[n * 64 + ((o ^ (n & 7)) * 8)] = *(const short8*)b;
        }
    }
    // stage H tile: 1024 chunks over 256 threads (4 rounds)
    const __hip_bfloat16* hsrc = Hhl + (size_t)blockIdx.x * 8192;
#pragma unroll
    for (int r = 0; r < 4; ++r) {
        const int blk = r * 4 + wave;
        gload_lds16(hsrc + blk * 512 + lane * 8, Hl + blk * 512);
    }
    __syncthreads();

    short8 ha[2][2];
#pragma unroll
    for (int mt2 = 0; mt2 < 2; ++mt2)
#pragma unroll
        for (int s = 0; s < 2; ++s)
            ha[mt2][s] = *(const short8*)&Hl[(wave * 32 + mt2 * 16 + l15) * 64 + (((s * 4 + l4) ^ e7) * 8)];

#pragma unroll
    for (int nt = 0; nt < 4; ++nt) {
        short8 wb[2];
#pragma unroll
        for (int s = 0; s < 2; ++s)
            wb[s] = *(const short8*)&Wl[(nt * 16 + l15) * 64 + (((s * 4 + l4) ^ e7) * 8)];
        f32x4 ac[2] = {(f32x4)0.f, (f32x4)0.f};
#pragma unroll
        for (int mt2 = 0; mt2 < 2; ++mt2) {
            ac[mt2] = __builtin_amdgcn_mfma_f32_16x16x32_bf16(ha[mt2][0], wb[0], ac[mt2], 0, 0, 0);
            ac[mt2] = __builtin_amdgcn_mfma_f32_16x16x32_bf16(ha[mt2][1], wb[1], ac[mt2], 0, 0, 0);
        }
        const int col = nt * 16 + l15;
        const float bj = sob[col];
#pragma unroll
        for (int mt2 = 0; mt2 < 2; ++mt2)
#pragma unroll
            for (int q = 0; q < 4; ++q) {
                const size_t th = (size_t)blockIdx.x * 128 + wave * 32 + mt2 * 16 + l4 * 4 + q;
                const float v = (ac[mt2][q] + bj) * zs[th * 64 + col];
                const size_t token = th >> 4;
                const int colg = (int)(th & 15) * 64 + col;   // 0..1023
                const int cg = colg >> 3, jg = colg & 7;      // octet, elem
                const int cs = (cg & 120) | ((cg & 7) ^ ((int)(token & 7)));
                gA[token * 1024 + cs * 8 + jg] = __float2bfloat16(v);
            }
    }
}

// ---------------------------------------------------------------------------
extern "C" void kernel_launch(void* const* d_in, const int* in_sizes, int n_in,
                              void* d_out, int out_size, void* d_ws, size_t ws_size,
                              hipStream_t stream)
{
    const float* x     = (const float*)d_in[0];
    const float* ipw   = (const float*)d_in[1];
    const float* cw    = (const float*)d_in[2];
    const float* cb    = (const float*)d_in[3];
    const float* bbw   = (const float*)d_in[4];
    const float* bbb   = (const float*)d_in[5];
    const float* f1w   = (const float*)d_in[6];
    const float* f1b   = (const float*)d_in[7];
    const float* f2w   = (const float*)d_in[8];
    const float* f2b   = (const float*)d_in[9];
    const float* tauw  = (const float*)d_in[10];
    const float* taub  = (const float*)d_in[11];
    const float* taub2 = (const float*)d_in[12];
    const float* decw  = (const float*)d_in[13];
    const float* decb  = (const float*)d_in[14];
    const float* sow   = (const float*)d_in[15];
    const float* sob   = (const float*)d_in[16];
    const float* opw   = (const float*)d_in[17];

    float* out = (float*)d_out;
    char*  ws  = (char*)d_ws;
    const size_t MB = 1024 * 1024;

    // Workspace map (198 MiB), no aliasing hazards:
    //  @0Mi   (32Mi): Abf (dead after GEMM-in) -> Xbf (dead after backbone)
    //  @32Mi  (32Mi): Hhl (pure bf16)
    //  @64Mi  (64Mi): xpath (f32, dead after conv) -> gA (32Mi)
    //  @128Mi (64Mi): BTin (4Mi, dead after GEMM-in) -> cd (packed uint 64Mi)
    //  @192Mi (6Mi) : WT5 (40KB, dead after backbone) -> Ach|Bch|hst;
    //                 BTout (2Mi) overwrites Ach after scan_chunks (hst @+4Mi safe)
    __hip_bfloat16* Abf   = (__hip_bfloat16*)(ws);
    __hip_bfloat16* Xbf   = (__hip_bfloat16*)(ws);
    __hip_bfloat16* Hhl   = (__hip_bfloat16*)(ws + 32 * MB);
    float*          xpath = (float*)(ws + 64 * MB);
    __hip_bfloat16* gA    = (__hip_bfloat16*)(ws + 64 * MB);
    __hip_bfloat16* BTin  = (__hip_bfloat16*)(ws + 128 * MB);
    unsigned*       cd    = (unsigned*)(ws + 128 * MB);
    __hip_bfloat16* WT5   = (__hip_bfloat16*)(ws + 192 * MB);
    float*          Ach   = (float*)(ws + 192 * MB);
    float*          Bch   = Ach + 524288;
    float*          hst   = Bch + 524288;
    __hip_bfloat16* BTout = (__hip_bfloat16*)(ws + 192 * MB);
    float*          zsilu = out;   // d_out as scratch until final GEMM

    // 1) conversions
    x_to_a_bf<<<8192, 256, 0, stream>>>(x, Abf);
    w_to_bt_bf<<<dim3(16, 32), 256, 0, stream>>>(ipw, BTin, 2048);
    w5_to_wt<<<10, 256, 0, stream>>>(bbw, f1w, f2w, tauw, decw, WT5);
    // 2) in_proj GEMM (pure bf16 MFMA) + silu(z)
    mfma_gemm256<8, 1><<<512, 512, 0, stream>>>(Abf, BTin, xpath, zsilu);
    // 3) conv + silu -> pure bf16 swizzled X (Abf dead)
    conv_silu_bf<<<8192, 256, 0, stream>>>(xpath, cw, cb, Xbf);
    // 4) pure-bf16 backbone -> packed cand|decay
    backbone_mfma<<<2048, 512, 0, stream>>>(Xbf, WT5, bbb, f1b, f2b,
                                            taub, taub2, decb, cd);
    // 5) chunked scan -> Hhl (pure bf16)
    scan_compose<<<2048, 256, 0, stream>>>(cd, Ach, Bch);
    scan_chunks<<<32, 256, 0, stream>>>(Ach, Bch, hst);
    scan_apply<<<2048, 256, 0, stream>>>(cd, hst, Hhl);
    // 6) out_proj weight conversion (Ach/Bch dead; hst untouched)
    w_to_bt_bf<<<dim3(16, 16), 256, 0, stream>>>(opw, BTout, 1024);
    // 7) state_out + gate (pure bf16 MFMA) -> gA
    stateout_mfma<<<2048, 256, 0, stream>>>(Hhl, sow, sob, zsilu, gA);
    // 8) out_proj GEMM (pure bf16)
    mfma_gemm256<4, 0><<<256, 512, 0, stream>>>(gA, BTout, out, nullptr);
}

// Round 13
// 315.624 us; speedup vs baseline: 2.0093x; 1.0165x over previous
//
#include <hip/hip_runtime.h>
#include <hip/hip_bf16.h>
#include <math.h>

// Problem constants
#define BN   8
#define SN   2048
#define HN   1024
#define NTOK 16384   // B*S
#define NHD  16
#define HDD  64
#define NSD  64

typedef __attribute__((ext_vector_type(8))) short short8;
typedef __attribute__((ext_vector_type(4))) float f32x4;

__device__ __forceinline__ float fsig(float x)  { return 1.f / (1.f + __expf(-x)); }
__device__ __forceinline__ float fsilu(float x) { return x / (1.f + __expf(-x)); }
__device__ __forceinline__ float ftanh(float x) {
    const float t = __expf(-2.f * fabsf(x));
    const float r = (1.f - t) / (1.f + t);
    return x >= 0.f ? r : -r;
}
__device__ __forceinline__ unsigned pack_cd(float cand, float dec) {
    __hip_bfloat16 cb_ = __float2bfloat16(cand);
    __hip_bfloat16 db_ = __float2bfloat16(dec);
    return (unsigned)*(unsigned short*)&cb_ | ((unsigned)*(unsigned short*)&db_ << 16);
}
__device__ __forceinline__ float bf2f(unsigned short u) {
    return __uint_as_float((unsigned)u << 16);
}
__device__ __forceinline__ void gload_lds16(const void* g, void* l) {
    __builtin_amdgcn_global_load_lds(
        (const __attribute__((address_space(1))) unsigned int*)g,
        (__attribute__((address_space(3))) unsigned int*)l, 16, 0, 0);
}

// ---------------------------------------------------------------------------
// x (16384x1024 f32) -> A (16384x1024 bf16), pre-swizzled in 4-octet groups:
// logical octet c of row r stored at (c&~3)|((c&3)^(r&3)).
// ---------------------------------------------------------------------------
__global__ __launch_bounds__(256)
void x_to_a_bf(const float* __restrict__ X, __hip_bfloat16* __restrict__ A)
{
    const int idx = blockIdx.x * 256 + threadIdx.x;   // 2M octets
    const int r = idx >> 7;
    const int c = idx & 127;                          // logical octet
    const float* src = &X[(size_t)r * 1024 + c * 8];
    alignas(16) __hip_bfloat16 b[8];
#pragma unroll
    for (int j = 0; j < 8; ++j) b[j] = __float2bfloat16(src[j]);
    const int cs = (c & ~3) | ((c & 3) ^ (r & 3));
    *(short8*)&A[(size_t)r * 1024 + cs * 8] = *(const short8*)b;
}

// ---------------------------------------------------------------------------
// W (1024 x N f32, (in,out)) -> BT (N x 1024 bf16), same 4-group pre-swizzle.
// ---------------------------------------------------------------------------
__global__ __launch_bounds__(256)
void w_to_bt_bf(const float* __restrict__ W, __hip_bfloat16* __restrict__ BT, int N)
{
    __shared__ float t[64][65];
    const int k0 = blockIdx.x * 64;
    const int n0 = blockIdx.y * 64;
    const int c  = threadIdx.x & 63, r4 = threadIdx.x >> 6;
#pragma unroll
    for (int rr = 0; rr < 64; rr += 4)
        t[rr + r4][c] = W[(size_t)(k0 + rr + r4) * N + n0 + c];
    __syncthreads();
#pragma unroll
    for (int oo = 0; oo < 2; ++oo) {
        const int o = r4 * 2 + oo;                 // octet within 64-k tile
        alignas(16) __hip_bfloat16 b[8];
#pragma unroll
        for (int j = 0; j < 8; ++j)
            b[j] = __float2bfloat16(t[o * 8 + j][c]);
        const int n = n0 + c;
        const int cglob = (k0 >> 3) + o;           // global octet index
        const int cs = (cglob & ~3) | ((cglob & 3) ^ (n & 3));
        *(short8*)&BT[(size_t)n * 1024 + cs * 8] = *(const short8*)b;
    }
}

// ---------------------------------------------------------------------------
// 5 backbone weight mats -> WT5 (backbone's own 8-group format, unchanged).
// ---------------------------------------------------------------------------
__global__ __launch_bounds__(256)
void w5_to_wt(const float* __restrict__ w0, const float* __restrict__ w1,
              const float* __restrict__ w2, const float* __restrict__ w3,
              const float* __restrict__ w4, __hip_bfloat16* __restrict__ WT5)
{
    const int idx = blockIdx.x * 256 + threadIdx.x;
    if (idx >= 2560) return;
    const int o = idx & 7, n = (idx >> 3) & 63, mat = idx >> 9;
    const float* W = mat == 0 ? w0 : mat == 1 ? w1 : mat == 2 ? w2 : mat == 3 ? w3 : w4;
    alignas(16) __hip_bfloat16 b[8];
#pragma unroll
    for (int j = 0; j < 8; ++j)
        b[j] = __float2bfloat16(W[(o * 8 + j) * 64 + n]);
    *(short8*)&WT5[(size_t)(mat * 64 + n) * 64 + ((o ^ (n & 7)) * 8)] = *(const short8*)b;
}

// ---------------------------------------------------------------------------
// Pure-bf16 MFMA GEMM, 128x256 tile, BK=32, 8 waves (2Mx4N), wave-tile 64x64.
// acc[4][4]=64 regs -> launch_bounds(512,4) -> 2 blocks/CU (48 KB LDS) so a
// second block hides each tile's barrier drain.  4-group swizzle throughout.
// MODE 0: f32 C to outf (stride NCT*256).
// MODE 1: cols<1024 -> bf16 xb; cols>=1024 -> silu -> bf16 zb.
// ---------------------------------------------------------------------------
template<int NCT, int MODE>
__global__ __launch_bounds__(512, 4)
void mfma_gemm(const __hip_bfloat16* __restrict__ A,
               const __hip_bfloat16* __restrict__ BT,
               float* __restrict__ outf,
               __hip_bfloat16* __restrict__ xb, __hip_bfloat16* __restrict__ zb)
{
    __shared__ __hip_bfloat16 lds[2][12288];   // [buf][A 128x32 | B 256x32]
    const int tid  = threadIdx.x;
    const int lane = tid & 63, wave = tid >> 6;
    const int wr   = wave >> 2, wc = wave & 3;     // 2 x 4 wave grid
    const int l15  = lane & 15, l4 = lane >> 4;

    // XCD-aware bijective swizzle (gridDim.x % 8 == 0 at both call sites)
    const int nwg = gridDim.x;
    const int cpx = nwg >> 3;
    const int swz = (blockIdx.x & 7) * cpx + (blockIdx.x >> 3);
    const int mt = swz / NCT, nt = swz % NCT;
    const int row0 = mt * 128, col0 = nt * 256;

    // staging map: 3 issues/tile; thread covers (s_r row, s_c chunk)
    const int s_c = tid & 3;
    const int s_r = tid >> 2;          // 0..127

    f32x4 acc[4][4];
#pragma unroll
    for (int m = 0; m < 4; ++m)
#pragma unroll
        for (int n = 0; n < 4; ++n) acc[m][n] = (f32x4)0.f;

    const int rdch = (0 ^ 0);  // placeholder (per-read below)

#define STAGE(TT, BUF)                                                         \
    {                                                                          \
        const int kk_ = (TT) << 5;                                             \
        gload_lds16(&A[(size_t)(row0 + s_r) * 1024 + kk_ + s_c * 8],           \
                    &lds[BUF][s_r * 32 + s_c * 8]);                            \
        _Pragma("unroll")                                                      \
        for (int h_ = 0; h_ < 2; ++h_) {                                       \
            const int r_ = h_ * 128 + s_r;                                     \
            gload_lds16(&BT[(size_t)(col0 + r_) * 1024 + kk_ + s_c * 8],       \
                        &lds[BUF][4096 + r_ * 32 + s_c * 8]);                  \
        }                                                                      \
    }

    // ---- prologue: stage K-tile 0 into buf 0 ----
    STAGE(0, 0)
    __syncthreads();

    for (int t = 0; t < 32; ++t) {
        const int cur = t & 1, nxt = cur ^ 1;
        if (t < 31) STAGE(t + 1, nxt)

        const int ch = (l4 ^ (l15 & 3)) * 8;
        short8 af[4], bf[4];
#pragma unroll
        for (int m = 0; m < 4; ++m)
            af[m] = *(const short8*)&lds[cur][(wr * 64 + m * 16 + l15) * 32 + ch];
#pragma unroll
        for (int n = 0; n < 4; ++n)
            bf[n] = *(const short8*)&lds[cur][4096 + (wc * 64 + n * 16 + l15) * 32 + ch];

        __builtin_amdgcn_s_setprio(1);
#pragma unroll
        for (int m = 0; m < 4; ++m)
#pragma unroll
            for (int n = 0; n < 4; ++n)
                acc[m][n] = __builtin_amdgcn_mfma_f32_16x16x32_bf16(af[m], bf[n], acc[m][n], 0, 0, 0);
        __builtin_amdgcn_s_setprio(0);

        __syncthreads();   // reads of cur done + prefetch into nxt landed
    }
#undef STAGE

    // epilogue: C/D layout col=lane&15, row=(lane>>4)*4+q
    const int orow = l4 * 4, ocol = l15;
#pragma unroll
    for (int m = 0; m < 4; ++m)
#pragma unroll
        for (int n = 0; n < 4; ++n) {
            const int c = col0 + wc * 64 + n * 16 + ocol;
#pragma unroll
            for (int q = 0; q < 4; ++q) {
                const int r = row0 + wr * 64 + m * 16 + orow + q;
                const float v = acc[m][n][q];
                if (MODE == 0) {
                    outf[(size_t)r * (NCT * 256) + c] = v;
                } else {
                    if (c < 1024) xb[(size_t)r * 1024 + c] = __float2bfloat16(v);
                    else          zb[(size_t)r * 1024 + (c - 1024)] = __float2bfloat16(fsilu(v));
                }
            }
        }
    (void)rdch;
}

// ---------------------------------------------------------------------------
// Depthwise causal conv (K=4) + bias + silu, bf16 input -> Xbf (8-group
// swizzled rows of 64 for the backbone, unchanged format).
// ---------------------------------------------------------------------------
__global__ __launch_bounds__(256)
void conv_silu_bf(const __hip_bfloat16* __restrict__ xp, const float* __restrict__ cw,
                  const float* __restrict__ cb, __hip_bfloat16* __restrict__ Xbf)
{
    const int idx = blockIdx.x * 256 + threadIdx.x;   // NTOK*128 octets
    const int g  = idx & 127;
    const int bt = idx >> 7;
    const int t  = bt & (SN - 1);
    const int c0 = g * 8;

    float acc[8];
#pragma unroll
    for (int j = 0; j < 8; ++j) acc[j] = cb[c0 + j];
    float4 cwv[8];
#pragma unroll
    for (int j = 0; j < 8; ++j) cwv[j] = *(const float4*)&cw[(c0 + j) * 4];
    const float* cwf = (const float*)cwv;

#pragma unroll
    for (int k = 0; k < 4; ++k) {
        if (t - 3 + k >= 0) {
            const short8 u = *(const short8*)&xp[(((size_t)(bt - 3 + k)) << 10) + c0];
#pragma unroll
            for (int j = 0; j < 8; ++j)
                acc[j] += cwf[j * 4 + k] * bf2f((unsigned short)u[j]);
        }
    }

    alignas(16) __hip_bfloat16 b[8];
#pragma unroll
    for (int j = 0; j < 8; ++j) b[j] = __float2bfloat16(fsilu(acc[j]));

    const int head = g >> 3;      // 0..15
    const int o    = g & 7;
    const size_t row = (size_t)bt * 16 + head;
    *(short8*)&Xbf[row * 64 + ((o ^ (head & 7)) * 8)] = *(const short8*)b;
}

// ---------------------------------------------------------------------------
// Pure-bf16 backbone (unchanged from round 12 — proven fast).
// ---------------------------------------------------------------------------
__global__ __launch_bounds__(512, 4)
void backbone_mfma(const __hip_bfloat16* __restrict__ Xbf,
                   const __hip_bfloat16* __restrict__ WT5,
                   const float* __restrict__ bbb,
                   const float* __restrict__ f1b, const float* __restrict__ f2b,
                   const float* __restrict__ taub, const float* __restrict__ taub2,
                   const float* __restrict__ decb,
                   unsigned* __restrict__ cd)
{
    __shared__ __hip_bfloat16 Wl[5 * 64 * 64];   // 40 KB
    __shared__ __hip_bfloat16 Bb[128 * 64];      // 16 KB
    const int tid  = threadIdx.x;
    const int lane = tid & 63, wave = tid >> 6;
    const int l15  = lane & 15, l4 = lane >> 4;
    const int e7   = l15 & 7;

#pragma unroll
    for (int r = 0; r < 5; ++r) {
        const int blk = r * 8 + wave;
        gload_lds16(WT5 + blk * 512 + lane * 8, Wl + blk * 512);
    }

    const __hip_bfloat16* xrow = Xbf + ((size_t)(blockIdx.x * 8 + wave) * 16) * 64;
    short8 xa[2];
#pragma unroll
    for (int s = 0; s < 2; ++s)
        xa[s] = *(const short8*)&xrow[l15 * 64 + (((s * 4 + l4) ^ e7) * 8)];

    __syncthreads();   // Wl staged (vmcnt drained)

#pragma unroll
    for (int nt = 0; nt < 4; ++nt) {
        short8 wb[2];
#pragma unroll
        for (int s = 0; s < 2; ++s)
            wb[s] = *(const short8*)&Wl[(nt * 16 + l15) * 64 + (((s * 4 + l4) ^ e7) * 8)];
        f32x4 ac = (f32x4)0.f;
        ac = __builtin_amdgcn_mfma_f32_16x16x32_bf16(xa[0], wb[0], ac, 0, 0, 0);
        ac = __builtin_amdgcn_mfma_f32_16x16x32_bf16(xa[1], wb[1], ac, 0, 0, 0);
        const int col = nt * 16 + l15;
        const float bc = bbb[col];
#pragma unroll
        for (int q = 0; q < 4; ++q) {
            const int r15 = l4 * 4 + q;
            Bb[(wave * 16 + r15) * 64 + ((col >> 3) ^ (r15 & 7)) * 8 + (col & 7)] =
                __float2bfloat16(fsilu(ac[q] + bc));
        }
    }
    // wave-private slab: no barrier needed

    short8 ba[2];
#pragma unroll
    for (int s = 0; s < 2; ++s)
        ba[s] = *(const short8*)&Bb[(wave * 16 + l15) * 64 + (((s * 4 + l4) ^ e7) * 8)];

#pragma unroll
    for (int nt = 0; nt < 4; ++nt) {
        f32x4 a2[4];
#pragma unroll
        for (int m = 0; m < 4; ++m) a2[m] = (f32x4)0.f;

#pragma unroll
        for (int mat = 0; mat < 4; ++mat) {
            short8 w2[2];
#pragma unroll
            for (int s = 0; s < 2; ++s)
                w2[s] = *(const short8*)&Wl[((mat + 1) * 64 + nt * 16 + l15) * 64 + (((s * 4 + l4) ^ e7) * 8)];
            a2[mat] = __builtin_amdgcn_mfma_f32_16x16x32_bf16(ba[0], w2[0], a2[mat], 0, 0, 0);
            a2[mat] = __builtin_amdgcn_mfma_f32_16x16x32_bf16(ba[1], w2[1], a2[mat], 0, 0, 0);
        }

        const int col = nt * 16 + l15;
        const float b1 = f1b[col], b2 = f2b[col];
        const float b3 = taub[col] + taub2[col], b4 = decb[col];
        const size_t Rbase = (size_t)blockIdx.x * 128 + wave * 16;
#pragma unroll
        for (int q = 0; q < 4; ++q) {
            const size_t R = Rbase + l4 * 4 + q;
            const float f1v = ftanh(a2[0][q] + b1);
            const float f2v = ftanh(a2[1][q] + b2);
            const float tv  = fsig (a2[2][q] + b3);
            const float dv  = fsig (a2[3][q] + b4);
            cd[R * 64 + col] = pack_cd(f1v * (1.f - tv) + f2v * tv, dv);
        }
    }
}

// ---------------------------------------------------------------------------
// Chunked scan passes 1+2 (packed cd input, unchanged).
// ---------------------------------------------------------------------------
__global__ __launch_bounds__(256)
void scan_compose(const unsigned* __restrict__ cd,
                  float* __restrict__ Ach, float* __restrict__ Bch)
{
    const int idx = blockIdx.x * 256 + threadIdx.x;
    const int p  = idx & 1023;
    const int rest = idx >> 10;
    const int ch = rest & 63, b = rest >> 6;
    float A = 1.f, Bv = 0.f;
    const size_t base = ((size_t)(b * SN + ch * 32) << 10) + p;
    for (int t = 0; t < 32; ++t) {
        const unsigned u = cd[base + ((size_t)t << 10)];
        const float c = __uint_as_float(u << 16);
        const float d = __uint_as_float(u & 0xffff0000u);
        A  *= d;
        Bv  = d * Bv + (1.f - d) * c;
    }
    Ach[(ch << 13) + (b << 10) + p] = A;
    Bch[(ch << 13) + (b << 10) + p] = Bv;
}

__global__ __launch_bounds__(256)
void scan_chunks(const float* __restrict__ Ach, const float* __restrict__ Bch,
                 float* __restrict__ hstart)
{
    const int q = blockIdx.x * 256 + threadIdx.x;
    float h = 0.f;
    for (int ch = 0; ch < 64; ++ch) {
        hstart[(ch << 13) + q] = h;
        h = Ach[(ch << 13) + q] * h + Bch[(ch << 13) + q];
    }
}

// ---------------------------------------------------------------------------
// scan_apply: final h per timestep as pure bf16 swizzled rows (unchanged).
// ---------------------------------------------------------------------------
__global__ __launch_bounds__(256)
void scan_apply(const unsigned* __restrict__ cd,
                const float* __restrict__ hstart, __hip_bfloat16* __restrict__ Hhl)
{
    const int idx = blockIdx.x * 256 + threadIdx.x;
    const int p  = idx & 1023;
    const int rest = idx >> 10;
    const int ch = rest & 63, b = rest >> 6;
    const int nh = p >> 6, ns = p & 63;
    const int hpos = ((ns >> 3) ^ (nh & 7)) * 8 + (ns & 7);
    float h = hstart[(ch << 13) + (b << 10) + p];
    const int t0 = b * SN + ch * 32;
    const size_t base = ((size_t)t0 << 10) + p;
    for (int t = 0; t < 32; ++t) {
        const unsigned u = cd[base + ((size_t)t << 10)];
        const float c = __uint_as_float(u << 16);
        const float d = __uint_as_float(u & 0xffff0000u);
        h = d * h + (1.f - d) * c;
        Hhl[((size_t)(t0 + t) * 16 + nh) * 64 + hpos] = __float2bfloat16(h);
    }
}

// ---------------------------------------------------------------------------
// Pure-bf16 MFMA state_out: out = H @ sow + sob, gated by silu(z) (bf16);
// emits bf16 gA rows in 4-group swizzle for out_proj.
// ---------------------------------------------------------------------------
__global__ __launch_bounds__(256, 4)
void stateout_mfma(const __hip_bfloat16* __restrict__ Hhl,
                   const float* __restrict__ sow, const float* __restrict__ sob,
                   const __hip_bfloat16* __restrict__ zs, __hip_bfloat16* __restrict__ gA)
{
    __shared__ __hip_bfloat16 Wl[64 * 64];    // 8 KB
    __shared__ __hip_bfloat16 Hl[128 * 64];   // 16 KB
    const int tid  = threadIdx.x;
    const int lane = tid & 63, wave = tid >> 6;
    const int l15  = lane & 15, l4 = lane >> 4;
    const int e7   = l15 & 7;

    {
        const int n = tid & 63;
        const int o0 = tid >> 6;   // 0..3
#pragma unroll
        for (int oo = 0; oo < 2; ++oo) {
            const int o = o0 + oo * 4;
            alignas(16) __hip_bfloat16 b[8];
#pragma unroll
            for (int j = 0; j < 8; ++j)
                b[j] = __float2bfloat16(sow[(o * 8 + j) * 64 + n]);
            *(short8*)&Wl[n * 64 + ((o ^ (n & 7)) * 8)] = *(const short8*)b;
        }
    }
    const __hip_bfloat16* hsrc = Hhl + (size_t)blockIdx.x * 8192;
#pragma unroll
    for (int r = 0; r < 4; ++r) {
        const int blk = r * 4 + wave;
        gload_lds16(hsrc + blk * 512 + lane * 8, Hl + blk * 512);
    }
    __syncthreads();

    short8 ha[2][2];
#pragma unroll
    for (int mt2 = 0; mt2 < 2; ++mt2)
#pragma unroll
        for (int s = 0; s < 2; ++s)
            ha[mt2][s] = *(const short8*)&Hl[(wave * 32 + mt2 * 16 + l15) * 64 + (((s * 4 + l4) ^ e7) * 8)];

#pragma unroll
    for (int nt = 0; nt < 4; ++nt) {
        short8 wb[2];
#pragma unroll
        for (int s = 0; s < 2; ++s)
            wb[s] = *(const short8*)&Wl[(nt * 16 + l15) * 64 + (((s * 4 + l4) ^ e7) * 8)];
        f32x4 ac[2] = {(f32x4)0.f, (f32x4)0.f};
#pragma unroll
        for (int mt2 = 0; mt2 < 2; ++mt2) {
            ac[mt2] = __builtin_amdgcn_mfma_f32_16x16x32_bf16(ha[mt2][0], wb[0], ac[mt2], 0, 0, 0);
            ac[mt2] = __builtin_amdgcn_mfma_f32_16x16x32_bf16(ha[mt2][1], wb[1], ac[mt2], 0, 0, 0);
        }
        const int col = nt * 16 + l15;
        const float bj = sob[col];
#pragma unroll
        for (int mt2 = 0; mt2 < 2; ++mt2)
#pragma unroll
            for (int q = 0; q < 4; ++q) {
                const size_t th = (size_t)blockIdx.x * 128 + wave * 32 + mt2 * 16 + l4 * 4 + q;
                const float z = bf2f(*(const unsigned short*)&zs[th * 64 + col]);
                const float v = (ac[mt2][q] + bj) * z;
                const size_t token = th >> 4;
                const int colg = (int)(th & 15) * 64 + col;   // 0..1023
                const int cg = colg >> 3, jg = colg & 7;      // octet, elem
                const int cs = (cg & ~3) | ((cg & 3) ^ ((int)(token & 3)));
                gA[token * 1024 + cs * 8 + jg] = __float2bfloat16(v);
            }
    }
}

// ---------------------------------------------------------------------------
extern "C" void kernel_launch(void* const* d_in, const int* in_sizes, int n_in,
                              void* d_out, int out_size, void* d_ws, size_t ws_size,
                              hipStream_t stream)
{
    const float* x     = (const float*)d_in[0];
    const float* ipw   = (const float*)d_in[1];
    const float* cw    = (const float*)d_in[2];
    const float* cb    = (const float*)d_in[3];
    const float* bbw   = (const float*)d_in[4];
    const float* bbb   = (const float*)d_in[5];
    const float* f1b_  = (const float*)d_in[7];
    const float* f1w   = (const float*)d_in[6];
    const float* f2w   = (const float*)d_in[8];
    const float* f2b   = (const float*)d_in[9];
    const float* tauw  = (const float*)d_in[10];
    const float* taub  = (const float*)d_in[11];
    const float* taub2 = (const float*)d_in[12];
    const float* decw  = (const float*)d_in[13];
    const float* decb  = (const float*)d_in[14];
    const float* sow   = (const float*)d_in[15];
    const float* sob   = (const float*)d_in[16];
    const float* opw   = (const float*)d_in[17];

    float* out = (float*)d_out;
    char*  ws  = (char*)d_ws;
    const size_t MB = 1024 * 1024;

    // Workspace map (198 MiB), no aliasing hazards:
    //  @0Mi   (32Mi): Abf (dead after GEMM-in) -> Xbf (dead after backbone)
    //  @32Mi  (32Mi): Hhl (pure bf16)
    //  @64Mi  (64Mi): xpath_bf (32Mi, dead after conv) -> gA (32Mi)
    //  @128Mi (64Mi): BTin (2Mi, dead after GEMM-in) -> cd (packed uint 64Mi)
    //  @192Mi (6Mi) : WT5 (40KB, dead after backbone) -> Ach|Bch|hst;
    //                 BTout (2Mi) overwrites Ach after scan_chunks (hst @+4Mi safe)
    __hip_bfloat16* Abf   = (__hip_bfloat16*)(ws);
    __hip_bfloat16* Xbf   = (__hip_bfloat16*)(ws);
    __hip_bfloat16* Hhl   = (__hip_bfloat16*)(ws + 32 * MB);
    __hip_bfloat16* xpath = (__hip_bfloat16*)(ws + 64 * MB);
    __hip_bfloat16* gA    = (__hip_bfloat16*)(ws + 64 * MB);
    __hip_bfloat16* BTin  = (__hip_bfloat16*)(ws + 128 * MB);
    unsigned*       cd    = (unsigned*)(ws + 128 * MB);
    __hip_bfloat16* WT5   = (__hip_bfloat16*)(ws + 192 * MB);
    float*          Ach   = (float*)(ws + 192 * MB);
    float*          Bch   = Ach + 524288;
    float*          hst   = Bch + 524288;
    __hip_bfloat16* BTout = (__hip_bfloat16*)(ws + 192 * MB);
    __hip_bfloat16* zsilu = (__hip_bfloat16*)out;   // d_out as scratch until final GEMM

    // 1) conversions
    x_to_a_bf<<<8192, 256, 0, stream>>>(x, Abf);
    w_to_bt_bf<<<dim3(16, 32), 256, 0, stream>>>(ipw, BTin, 2048);
    w5_to_wt<<<10, 256, 0, stream>>>(bbw, f1w, f2w, tauw, decw, WT5);
    // 2) in_proj GEMM (2 blocks/CU) -> bf16 x_path + bf16 silu(z)
    mfma_gemm<8, 1><<<1024, 512, 0, stream>>>(Abf, BTin, nullptr, xpath, zsilu);
    // 3) conv + silu (bf16 in) -> swizzled bf16 X (Abf dead)
    conv_silu_bf<<<8192, 256, 0, stream>>>(xpath, cw, cb, Xbf);
    // 4) pure-bf16 backbone -> packed cand|decay
    backbone_mfma<<<2048, 512, 0, stream>>>(Xbf, WT5, bbb, f1b_, f2b,
                                            taub, taub2, decb, cd);
    // 5) chunked scan -> Hhl (pure bf16)
    scan_compose<<<2048, 256, 0, stream>>>(cd, Ach, Bch);
    scan_chunks<<<32, 256, 0, stream>>>(Ach, Bch, hst);
    scan_apply<<<2048, 256, 0, stream>>>(cd, hst, Hhl);
    // 6) out_proj weight conversion (Ach/Bch dead; hst untouched)
    w_to_bt_bf<<<dim3(16, 16), 256, 0, stream>>>(opw, BTout, 1024);
    // 7) state_out + gate (bf16 z) -> gA (4-group swizzle)
    stateout_mfma<<<2048, 256, 0, stream>>>(Hhl, sow, sob, zsilu, gA);
    // 8) out_proj GEMM -> f32 out
    mfma_gemm<4, 0><<<512, 512, 0, stream>>>(gA, BTout, out, nullptr, nullptr);
}

// Round 15
// 314.262 us; speedup vs baseline: 2.0180x; 1.0043x over previous
//
#include <hip/hip_runtime.h>
#include <hip/hip_bf16.h>
#include <math.h>

// Problem constants
#define BN   8
#define SN   2048
#define HN   1024
#define NTOK 16384   // B*S
#define NHD  16
#define HDD  64
#define NSD  64

typedef __attribute__((ext_vector_type(8))) short short8;
typedef __attribute__((ext_vector_type(4))) float f32x4;

__device__ __forceinline__ float fsig(float x)  { return 1.f / (1.f + __expf(-x)); }
__device__ __forceinline__ float fsilu(float x) { return x / (1.f + __expf(-x)); }
__device__ __forceinline__ float ftanh(float x) {
    const float t = __expf(-2.f * fabsf(x));
    const float r = (1.f - t) / (1.f + t);
    return x >= 0.f ? r : -r;
}
__device__ __forceinline__ unsigned pack_cd(float cand, float dec) {
    __hip_bfloat16 cb_ = __float2bfloat16(cand);
    __hip_bfloat16 db_ = __float2bfloat16(dec);
    return (unsigned)*(unsigned short*)&cb_ | ((unsigned)*(unsigned short*)&db_ << 16);
}
__device__ __forceinline__ float bf2f(unsigned short u) {
    return __uint_as_float((unsigned)u << 16);
}
__device__ __forceinline__ void gload_lds16(const void* g, void* l) {
    __builtin_amdgcn_global_load_lds(
        (const __attribute__((address_space(1))) unsigned int*)g,
        (__attribute__((address_space(3))) unsigned int*)l, 16, 0, 0);
}

// ---------------------------------------------------------------------------
// x (16384x1024 f32) -> A (16384x1024 bf16), pre-swizzled in 4-octet groups:
// logical octet c of row r stored at (c&~3)|((c&3)^((r>>1)&3)).
// (>>1 because 64B rows: 2 rows span the 128B bank window -> 2-way = free)
// ---------------------------------------------------------------------------
__global__ __launch_bounds__(256)
void x_to_a_bf(const float* __restrict__ X, __hip_bfloat16* __restrict__ A)
{
    const int idx = blockIdx.x * 256 + threadIdx.x;   // 2M octets
    const int r = idx >> 7;
    const int c = idx & 127;                          // logical octet
    const float* src = &X[(size_t)r * 1024 + c * 8];
    alignas(16) __hip_bfloat16 b[8];
#pragma unroll
    for (int j = 0; j < 8; ++j) b[j] = __float2bfloat16(src[j]);
    const int cs = (c & ~3) | ((c & 3) ^ ((r >> 1) & 3));
    *(short8*)&A[(size_t)r * 1024 + cs * 8] = *(const short8*)b;
}

// ---------------------------------------------------------------------------
// W (1024 x N f32, (in,out)) -> BT (N x 1024 bf16), same 4-group pre-swizzle.
// ---------------------------------------------------------------------------
__global__ __launch_bounds__(256)
void w_to_bt_bf(const float* __restrict__ W, __hip_bfloat16* __restrict__ BT, int N)
{
    __shared__ float t[64][65];
    const int k0 = blockIdx.x * 64;
    const int n0 = blockIdx.y * 64;
    const int c  = threadIdx.x & 63, r4 = threadIdx.x >> 6;
#pragma unroll
    for (int rr = 0; rr < 64; rr += 4)
        t[rr + r4][c] = W[(size_t)(k0 + rr + r4) * N + n0 + c];
    __syncthreads();
#pragma unroll
    for (int oo = 0; oo < 2; ++oo) {
        const int o = r4 * 2 + oo;                 // octet within 64-k tile
        alignas(16) __hip_bfloat16 b[8];
#pragma unroll
        for (int j = 0; j < 8; ++j)
            b[j] = __float2bfloat16(t[o * 8 + j][c]);
        const int n = n0 + c;
        const int cglob = (k0 >> 3) + o;           // global octet index
        const int cs = (cglob & ~3) | ((cglob & 3) ^ ((n >> 1) & 3));
        *(short8*)&BT[(size_t)n * 1024 + cs * 8] = *(const short8*)b;
    }
}

// ---------------------------------------------------------------------------
// 5 backbone weight mats -> WT5 (backbone's own 8-group format, unchanged).
// ---------------------------------------------------------------------------
__global__ __launch_bounds__(256)
void w5_to_wt(const float* __restrict__ w0, const float* __restrict__ w1,
              const float* __restrict__ w2, const float* __restrict__ w3,
              const float* __restrict__ w4, __hip_bfloat16* __restrict__ WT5)
{
    const int idx = blockIdx.x * 256 + threadIdx.x;
    if (idx >= 2560) return;
    const int o = idx & 7, n = (idx >> 3) & 63, mat = idx >> 9;
    const float* W = mat == 0 ? w0 : mat == 1 ? w1 : mat == 2 ? w2 : mat == 3 ? w3 : w4;
    alignas(16) __hip_bfloat16 b[8];
#pragma unroll
    for (int j = 0; j < 8; ++j)
        b[j] = __float2bfloat16(W[(o * 8 + j) * 64 + n]);
    *(short8*)&WT5[(size_t)(mat * 64 + n) * 64 + ((o ^ (n & 7)) * 8)] = *(const short8*)b;
}

// ---------------------------------------------------------------------------
// Pure-bf16 MFMA GEMM, 128x256 tile, BK=32, 8 waves (2Mx4N), wave-tile 64x64.
// acc[4][4]=64 regs, launch_bounds(512,4) -> 2 blocks/CU (48 KB LDS).
// 4-group swizzle with (row>>1)&3 -> conflict-free ds_read_b128.
// MODE 0: f32 C to outf.  MODE 1: cols<1024 -> bf16 xb; else silu -> bf16 zb.
// ---------------------------------------------------------------------------
template<int NCT, int MODE>
__global__ __launch_bounds__(512, 4)
void mfma_gemm(const __hip_bfloat16* __restrict__ A,
               const __hip_bfloat16* __restrict__ BT,
               float* __restrict__ outf,
               __hip_bfloat16* __restrict__ xb, __hip_bfloat16* __restrict__ zb)
{
    __shared__ __hip_bfloat16 lds[2][12288];   // [buf][A 128x32 | B 256x32]
    const int tid  = threadIdx.x;
    const int lane = tid & 63, wave = tid >> 6;
    const int wr   = wave >> 2, wc = wave & 3;     // 2 x 4 wave grid
    const int l15  = lane & 15, l4 = lane >> 4;

    // XCD-aware bijective swizzle (gridDim.x % 8 == 0 at both call sites)
    const int nwg = gridDim.x;
    const int cpx = nwg >> 3;
    const int swz = (blockIdx.x & 7) * cpx + (blockIdx.x >> 3);
    const int mt = swz / NCT, nt = swz % NCT;
    const int row0 = mt * 128, col0 = nt * 256;

    const int s_c = tid & 3;
    const int s_r = tid >> 2;          // 0..127

    f32x4 acc[4][4];
#pragma unroll
    for (int m = 0; m < 4; ++m)
#pragma unroll
        for (int n = 0; n < 4; ++n) acc[m][n] = (f32x4)0.f;

#define STAGE(TT, BUF)                                                         \
    {                                                                          \
        const int kk_ = (TT) << 5;                                             \
        gload_lds16(&A[(size_t)(row0 + s_r) * 1024 + kk_ + s_c * 8],           \
                    &lds[BUF][s_r * 32 + s_c * 8]);                            \
        _Pragma("unroll")                                                      \
        for (int h_ = 0; h_ < 2; ++h_) {                                       \
            const int r_ = h_ * 128 + s_r;                                     \
            gload_lds16(&BT[(size_t)(col0 + r_) * 1024 + kk_ + s_c * 8],       \
                        &lds[BUF][4096 + r_ * 32 + s_c * 8]);                  \
        }                                                                      \
    }

    // ---- prologue: stage K-tile 0 into buf 0 ----
    STAGE(0, 0)
    __syncthreads();

    for (int t = 0; t < 32; ++t) {
        const int cur = t & 1, nxt = cur ^ 1;
        if (t < 31) STAGE(t + 1, nxt)

        const int ch = (l4 ^ ((l15 >> 1) & 3)) * 8;   // conflict-free swizzle
        short8 af[4], bf[4];
#pragma unroll
        for (int m = 0; m < 4; ++m)
            af[m] = *(const short8*)&lds[cur][(wr * 64 + m * 16 + l15) * 32 + ch];
#pragma unroll
        for (int n = 0; n < 4; ++n)
            bf[n] = *(const short8*)&lds[cur][4096 + (wc * 64 + n * 16 + l15) * 32 + ch];

        __builtin_amdgcn_s_setprio(1);
#pragma unroll
        for (int m = 0; m < 4; ++m)
#pragma unroll
            for (int n = 0; n < 4; ++n)
                acc[m][n] = __builtin_amdgcn_mfma_f32_16x16x32_bf16(af[m], bf[n], acc[m][n], 0, 0, 0);
        __builtin_amdgcn_s_setprio(0);

        __syncthreads();   // reads of cur done + prefetch into nxt landed
    }
#undef STAGE

    // epilogue: C/D layout col=lane&15, row=(lane>>4)*4+q
    const int orow = l4 * 4, ocol = l15;
#pragma unroll
    for (int m = 0; m < 4; ++m)
#pragma unroll
        for (int n = 0; n < 4; ++n) {
            const int c = col0 + wc * 64 + n * 16 + ocol;
#pragma unroll
            for (int q = 0; q < 4; ++q) {
                const int r = row0 + wr * 64 + m * 16 + orow + q;
                const float v = acc[m][n][q];
                if (MODE == 0) {
                    outf[(size_t)r * (NCT * 256) + c] = v;
                } else {
                    if (c < 1024) xb[(size_t)r * 1024 + c] = __float2bfloat16(v);
                    else          zb[(size_t)r * 1024 + (c - 1024)] = __float2bfloat16(fsilu(v));
                }
            }
        }
}

// ---------------------------------------------------------------------------
// Depthwise causal conv (K=4) + bias + silu, bf16 input -> Xbf (8-group
// swizzled rows of 64 for the backbone, unchanged format).
// ---------------------------------------------------------------------------
__global__ __launch_bounds__(256)
void conv_silu_bf(const __hip_bfloat16* __restrict__ xp, const float* __restrict__ cw,
                  const float* __restrict__ cb, __hip_bfloat16* __restrict__ Xbf)
{
    const int idx = blockIdx.x * 256 + threadIdx.x;   // NTOK*128 octets
    const int g  = idx & 127;
    const int bt = idx >> 7;
    const int t  = bt & (SN - 1);
    const int c0 = g * 8;

    float acc[8];
#pragma unroll
    for (int j = 0; j < 8; ++j) acc[j] = cb[c0 + j];
    float4 cwv[8];
#pragma unroll
    for (int j = 0; j < 8; ++j) cwv[j] = *(const float4*)&cw[(c0 + j) * 4];
    const float* cwf = (const float*)cwv;

#pragma unroll
    for (int k = 0; k < 4; ++k) {
        if (t - 3 + k >= 0) {
            const short8 u = *(const short8*)&xp[(((size_t)(bt - 3 + k)) << 10) + c0];
#pragma unroll
            for (int j = 0; j < 8; ++j)
                acc[j] += cwf[j * 4 + k] * bf2f((unsigned short)u[j]);
        }
    }

    alignas(16) __hip_bfloat16 b[8];
#pragma unroll
    for (int j = 0; j < 8; ++j) b[j] = __float2bfloat16(fsilu(acc[j]));

    const int head = g >> 3;      // 0..15
    const int o    = g & 7;
    const size_t row = (size_t)bt * 16 + head;
    *(short8*)&Xbf[row * 64 + ((o ^ (head & 7)) * 8)] = *(const short8*)b;
}

// ---------------------------------------------------------------------------
// Pure-bf16 backbone (unchanged — proven fast).
// ---------------------------------------------------------------------------
__global__ __launch_bounds__(512, 4)
void backbone_mfma(const __hip_bfloat16* __restrict__ Xbf,
                   const __hip_bfloat16* __restrict__ WT5,
                   const float* __restrict__ bbb,
                   const float* __restrict__ f1b, const float* __restrict__ f2b,
                   const float* __restrict__ taub, const float* __restrict__ taub2,
                   const float* __restrict__ decb,
                   unsigned* __restrict__ cd)
{
    __shared__ __hip_bfloat16 Wl[5 * 64 * 64];   // 40 KB
    __shared__ __hip_bfloat16 Bb[128 * 64];      // 16 KB
    const int tid  = threadIdx.x;
    const int lane = tid & 63, wave = tid >> 6;
    const int l15  = lane & 15, l4 = lane >> 4;
    const int e7   = l15 & 7;

#pragma unroll
    for (int r = 0; r < 5; ++r) {
        const int blk = r * 8 + wave;
        gload_lds16(WT5 + blk * 512 + lane * 8, Wl + blk * 512);
    }

    const __hip_bfloat16* xrow = Xbf + ((size_t)(blockIdx.x * 8 + wave) * 16) * 64;
    short8 xa[2];
#pragma unroll
    for (int s = 0; s < 2; ++s)
        xa[s] = *(const short8*)&xrow[l15 * 64 + (((s * 4 + l4) ^ e7) * 8)];

    __syncthreads();   // Wl staged (vmcnt drained)

#pragma unroll
    for (int nt = 0; nt < 4; ++nt) {
        short8 wb[2];
#pragma unroll
        for (int s = 0; s < 2; ++s)
            wb[s] = *(const short8*)&Wl[(nt * 16 + l15) * 64 + (((s * 4 + l4) ^ e7) * 8)];
        f32x4 ac = (f32x4)0.f;
        ac = __builtin_amdgcn_mfma_f32_16x16x32_bf16(xa[0], wb[0], ac, 0, 0, 0);
        ac = __builtin_amdgcn_mfma_f32_16x16x32_bf16(xa[1], wb[1], ac, 0, 0, 0);
        const int col = nt * 16 + l15;
        const float bc = bbb[col];
#pragma unroll
        for (int q = 0; q < 4; ++q) {
            const int r15 = l4 * 4 + q;
            Bb[(wave * 16 + r15) * 64 + ((col >> 3) ^ (r15 & 7)) * 8 + (col & 7)] =
                __float2bfloat16(fsilu(ac[q] + bc));
        }
    }
    // wave-private slab: no barrier needed

    short8 ba[2];
#pragma unroll
    for (int s = 0; s < 2; ++s)
        ba[s] = *(const short8*)&Bb[(wave * 16 + l15) * 64 + (((s * 4 + l4) ^ e7) * 8)];

#pragma unroll
    for (int nt = 0; nt < 4; ++nt) {
        f32x4 a2[4];
#pragma unroll
        for (int m = 0; m < 4; ++m) a2[m] = (f32x4)0.f;

#pragma unroll
        for (int mat = 0; mat < 4; ++mat) {
            short8 w2[2];
#pragma unroll
            for (int s = 0; s < 2; ++s)
                w2[s] = *(const short8*)&Wl[((mat + 1) * 64 + nt * 16 + l15) * 64 + (((s * 4 + l4) ^ e7) * 8)];
            a2[mat] = __builtin_amdgcn_mfma_f32_16x16x32_bf16(ba[0], w2[0], a2[mat], 0, 0, 0);
            a2[mat] = __builtin_amdgcn_mfma_f32_16x16x32_bf16(ba[1], w2[1], a2[mat], 0, 0, 0);
        }

        const int col = nt * 16 + l15;
        const float b1 = f1b[col], b2 = f2b[col];
        const float b3 = taub[col] + taub2[col], b4 = decb[col];
        const size_t Rbase = (size_t)blockIdx.x * 128 + wave * 16;
#pragma unroll
        for (int q = 0; q < 4; ++q) {
            const size_t R = Rbase + l4 * 4 + q;
            const float f1v = ftanh(a2[0][q] + b1);
            const float f2v = ftanh(a2[1][q] + b2);
            const float tv  = fsig (a2[2][q] + b3);
            const float dv  = fsig (a2[3][q] + b4);
            cd[R * 64 + col] = pack_cd(f1v * (1.f - tv) + f2v * tv, dv);
        }
    }
}

// ---------------------------------------------------------------------------
// Chunked scan passes 1+2 (packed cd input, unchanged).
// ---------------------------------------------------------------------------
__global__ __launch_bounds__(256)
void scan_compose(const unsigned* __restrict__ cd,
                  float* __restrict__ Ach, float* __restrict__ Bch)
{
    const int idx = blockIdx.x * 256 + threadIdx.x;
    const int p  = idx & 1023;
    const int rest = idx >> 10;
    const int ch = rest & 63, b = rest >> 6;
    float A = 1.f, Bv = 0.f;
    const size_t base = ((size_t)(b * SN + ch * 32) << 10) + p;
    for (int t = 0; t < 32; ++t) {
        const unsigned u = cd[base + ((size_t)t << 10)];
        const float c = __uint_as_float(u << 16);
        const float d = __uint_as_float(u & 0xffff0000u);
        A  *= d;
        Bv  = d * Bv + (1.f - d) * c;
    }
    Ach[(ch << 13) + (b << 10) + p] = A;
    Bch[(ch << 13) + (b << 10) + p] = Bv;
}

__global__ __launch_bounds__(256)
void scan_chunks(const float* __restrict__ Ach, const float* __restrict__ Bch,
                 float* __restrict__ hstart)
{
    const int q = blockIdx.x * 256 + threadIdx.x;
    float h = 0.f;
    for (int ch = 0; ch < 64; ++ch) {
        hstart[(ch << 13) + q] = h;
        h = Ach[(ch << 13) + q] * h + Bch[(ch << 13) + q];
    }
}

// ---------------------------------------------------------------------------
// scan_apply: final h per timestep as pure bf16 swizzled rows (unchanged).
// ---------------------------------------------------------------------------
__global__ __launch_bounds__(256)
void scan_apply(const unsigned* __restrict__ cd,
                const float* __restrict__ hstart, __hip_bfloat16* __restrict__ Hhl)
{
    const int idx = blockIdx.x * 256 + threadIdx.x;
    const int p  = idx & 1023;
    const int rest = idx >> 10;
    const int ch = rest & 63, b = rest >> 6;
    const int nh = p >> 6, ns = p & 63;
    const int hpos = ((ns >> 3) ^ (nh & 7)) * 8 + (ns & 7);
    float h = hstart[(ch << 13) + (b << 10) + p];
    const int t0 = b * SN + ch * 32;
    const size_t base = ((size_t)t0 << 10) + p;
    for (int t = 0; t < 32; ++t) {
        const unsigned u = cd[base + ((size_t)t << 10)];
        const float c = __uint_as_float(u << 16);
        const float d = __uint_as_float(u & 0xffff0000u);
        h = d * h + (1.f - d) * c;
        Hhl[((size_t)(t0 + t) * 16 + nh) * 64 + hpos] = __float2bfloat16(h);
    }
}

// ---------------------------------------------------------------------------
// Pure-bf16 MFMA state_out: out = H @ sow + sob, gated by silu(z) (bf16);
// emits bf16 gA rows in 4-group swizzle ((token>>1)&3) for out_proj.
// ---------------------------------------------------------------------------
__global__ __launch_bounds__(256, 4)
void stateout_mfma(const __hip_bfloat16* __restrict__ Hhl,
                   const float* __restrict__ sow, const float* __restrict__ sob,
                   const __hip_bfloat16* __restrict__ zs, __hip_bfloat16* __restrict__ gA)
{
    __shared__ __hip_bfloat16 Wl[64 * 64];    // 8 KB
    __shared__ __hip_bfloat16 Hl[128 * 64];   // 16 KB
    const int tid  = threadIdx.x;
    const int lane = tid & 63, wave = tid >> 6;
    const int l15  = lane & 15, l4 = lane >> 4;
    const int e7   = l15 & 7;

    {
        const int n = tid & 63;
        const int o0 = tid >> 6;   // 0..3
#pragma unroll
        for (int oo = 0; oo < 2; ++oo) {
            const int o = o0 + oo * 4;
            alignas(16) __hip_bfloat16 b[8];
#pragma unroll
            for (int j = 0; j < 8; ++j)
                b[j] = __float2bfloat16(sow[(o * 8 + j) * 64 + n]);
            *(short8*)&Wl[n * 64 + ((o ^ (n & 7)) * 8)] = *(const short8*)b;
        }
    }
    const __hip_bfloat16* hsrc = Hhl + (size_t)blockIdx.x * 8192;
#pragma unroll
    for (int r = 0; r < 4; ++r) {
        const int blk = r * 4 + wave;
        gload_lds16(hsrc + blk * 512 + lane * 8, Hl + blk * 512);
    }
    __syncthreads();

    short8 ha[2][2];
#pragma unroll
    for (int mt2 = 0; mt2 < 2; ++mt2)
#pragma unroll
        for (int s = 0; s < 2; ++s)
            ha[mt2][s] = *(const short8*)&Hl[(wave * 32 + mt2 * 16 + l15) * 64 + (((s * 4 + l4) ^ e7) * 8)];

#pragma unroll
    for (int nt = 0; nt < 4; ++nt) {
        short8 wb[2];
#pragma unroll
        for (int s = 0; s < 2; ++s)
            wb[s] = *(const short8*)&Wl[(nt * 16 + l15) * 64 + (((s * 4 + l4) ^ e7) * 8)];
        f32x4 ac[2] = {(f32x4)0.f, (f32x4)0.f};
#pragma unroll
        for (int mt2 = 0; mt2 < 2; ++mt2) {
            ac[mt2] = __builtin_amdgcn_mfma_f32_16x16x32_bf16(ha[mt2][0], wb[0], ac[mt2], 0, 0, 0);
            ac[mt2] = __builtin_amdgcn_mfma_f32_16x16x32_bf16(ha[mt2][1], wb[1], ac[mt2], 0, 0, 0);
        }
        const int col = nt * 16 + l15;
        const float bj = sob[col];
#pragma unroll
        for (int mt2 = 0; mt2 < 2; ++mt2)
#pragma unroll
            for (int q = 0; q < 4; ++q) {
                const size_t th = (size_t)blockIdx.x * 128 + wave * 32 + mt2 * 16 + l4 * 4 + q;
                const float z = bf2f(*(const unsigned short*)&zs[th * 64 + col]);
                const float v = (ac[mt2][q] + bj) * z;
                const size_t token = th >> 4;
                const int colg = (int)(th & 15) * 64 + col;   // 0..1023
                const int cg = colg >> 3, jg = colg & 7;      // octet, elem
                const int cs = (cg & ~3) | ((cg & 3) ^ ((int)((token >> 1) & 3)));
                gA[token * 1024 + cs * 8 + jg] = __float2bfloat16(v);
            }
    }
}

// ---------------------------------------------------------------------------
extern "C" void kernel_launch(void* const* d_in, const int* in_sizes, int n_in,
                              void* d_out, int out_size, void* d_ws, size_t ws_size,
                              hipStream_t stream)
{
    const float* x     = (const float*)d_in[0];
    const float* ipw   = (const float*)d_in[1];
    const float* cw    = (const float*)d_in[2];
    const float* cb    = (const float*)d_in[3];
    const float* bbw   = (const float*)d_in[4];
    const float* bbb   = (const float*)d_in[5];
    const float* f1w   = (const float*)d_in[6];
    const float* f1b   = (const float*)d_in[7];
    const float* f2w   = (const float*)d_in[8];
    const float* f2b   = (const float*)d_in[9];
    const float* tauw  = (const float*)d_in[10];
    const float* taub  = (const float*)d_in[11];
    const float* taub2 = (const float*)d_in[12];
    const float* decw  = (const float*)d_in[13];
    const float* decb  = (const float*)d_in[14];
    const float* sow   = (const float*)d_in[15];
    const float* sob   = (const float*)d_in[16];
    const float* opw   = (const float*)d_in[17];

    float* out = (float*)d_out;
    char*  ws  = (char*)d_ws;
    const size_t MB = 1024 * 1024;

    // Workspace map (198 MiB), no aliasing hazards:
    //  @0Mi   (32Mi): Abf (dead after GEMM-in) -> Xbf (dead after backbone)
    //  @32Mi  (32Mi): Hhl (pure bf16)
    //  @64Mi  (64Mi): xpath_bf (32Mi, dead after conv) -> gA (32Mi)
    //  @128Mi (64Mi): BTin (2Mi, dead after GEMM-in) -> cd (packed uint 64Mi)
    //  @192Mi (6Mi) : WT5 (40KB, dead after backbone) -> Ach|Bch|hst;
    //                 BTout (2Mi) overwrites Ach after scan_chunks (hst @+4Mi safe)
    __hip_bfloat16* Abf   = (__hip_bfloat16*)(ws);
    __hip_bfloat16* Xbf   = (__hip_bfloat16*)(ws);
    __hip_bfloat16* Hhl   = (__hip_bfloat16*)(ws + 32 * MB);
    __hip_bfloat16* xpath = (__hip_bfloat16*)(ws + 64 * MB);
    __hip_bfloat16* gA    = (__hip_bfloat16*)(ws + 64 * MB);
    __hip_bfloat16* BTin  = (__hip_bfloat16*)(ws + 128 * MB);
    unsigned*       cd    = (unsigned*)(ws + 128 * MB);
    __hip_bfloat16* WT5   = (__hip_bfloat16*)(ws + 192 * MB);
    float*          Ach   = (float*)(ws + 192 * MB);
    float*          Bch   = Ach + 524288;
    float*          hst   = Bch + 524288;
    __hip_bfloat16* BTout = (__hip_bfloat16*)(ws + 192 * MB);
    __hip_bfloat16* zsilu = (__hip_bfloat16*)out;   // d_out as scratch until final GEMM

    // 1) conversions
    x_to_a_bf<<<8192, 256, 0, stream>>>(x, Abf);
    w_to_bt_bf<<<dim3(16, 32), 256, 0, stream>>>(ipw, BTin, 2048);
    w5_to_wt<<<10, 256, 0, stream>>>(bbw, f1w, f2w, tauw, decw, WT5);
    // 2) in_proj GEMM (2 blocks/CU, conflict-free) -> bf16 x_path + bf16 silu(z)
    mfma_gemm<8, 1><<<1024, 512, 0, stream>>>(Abf, BTin, nullptr, xpath, zsilu);
    // 3) conv + silu (bf16 in) -> swizzled bf16 X (Abf dead)
    conv_silu_bf<<<8192, 256, 0, stream>>>(xpath, cw, cb, Xbf);
    // 4) pure-bf16 backbone -> packed cand|decay
    backbone_mfma<<<2048, 512, 0, stream>>>(Xbf, WT5, bbb, f1b, f2b,
                                            taub, taub2, decb, cd);
    // 5) chunked scan -> Hhl (pure bf16)
    scan_compose<<<2048, 256, 0, stream>>>(cd, Ach, Bch);
    scan_chunks<<<32, 256, 0, stream>>>(Ach, Bch, hst);
    scan_apply<<<2048, 256, 0, stream>>>(cd, hst, Hhl);
    // 6) out_proj weight conversion (Ach/Bch dead; hst untouched)
    w_to_bt_bf<<<dim3(16, 16), 256, 0, stream>>>(opw, BTout, 1024);
    // 7) state_out + gate (bf16 z) -> gA (4-group swizzle)
    stateout_mfma<<<2048, 256, 0, stream>>>(Hhl, sow, sob, zsilu, gA);
    // 8) out_proj GEMM -> f32 out
    mfma_gemm<4, 0><<<512, 512, 0, stream>>>(gA, BTout, out, nullptr, nullptr);
}